// Round 20
// baseline (355.001 us; speedup 1.0000x reference)
//
#include <hip/hip_runtime.h>
#include <hip/hip_fp16.h>
#include <math.h>

constexpr int NN  = 50000;   // nodes
constexpr int EE  = 800000;  // edges
constexpr int INF_ = 256;    // input feat
constexpr int HF  = 128;     // hidden
constexpr int CC  = 50;      // classes
constexpr long NH = (long)NN * HF;
constexpr int NSL = 32;          // edge slices (preprocessing)
constexpr int ESL = EE / NSL;    // 25000 edges per slice
constexpr int CHK = 12500;       // nodes per chunk (4 chunks), 50KB LDS
#define EPSV 1e-5f

enum { EPI_RELU = 0, EPI_NONE = 1, EPI_ATTN = 4 };
enum { OUT_F32 = 0, OUT_F16 = 1, OUT_F16S = 2 };

typedef __attribute__((ext_vector_type(4))) float f32x4;
typedef __attribute__((ext_vector_type(8))) _Float16 f16x8;

__device__ __forceinline__ void nt_store_h(__half v, __half* p) {
  __builtin_nontemporal_store(__half_as_ushort(v), (ushort*)p);
}

// ---------------- graph preprocessing (atomic-free: LDS histograms) ----------------

__global__ __launch_bounds__(256) void count_partial2_kernel(
    const int4* __restrict__ dst4, const int4* __restrict__ src4,
    unsigned* __restrict__ pd, unsigned* __restrict__ ps) {
  __shared__ unsigned cnt[CHK];
  int bb = blockIdx.x;
  const int which = bb >> 7;
  bb &= 127;
  const int4* keys4 = which ? src4 : dst4;
  unsigned* partials = which ? ps : pd;
  const int chunk = bb & 3;
  const int sl = bb >> 2;
  for (int i = threadIdx.x; i < CHK; i += 256) cnt[i] = 0;
  __syncthreads();
  const int base4 = sl * (ESL / 4);
  const int lo = chunk * CHK;
  for (int i = threadIdx.x; i < ESL / 4; i += 256) {
    int4 k = keys4[base4 + i];
    int a;
    a = k.x - lo; if ((unsigned)a < (unsigned)CHK) atomicAdd(&cnt[a], 1u);
    a = k.y - lo; if ((unsigned)a < (unsigned)CHK) atomicAdd(&cnt[a], 1u);
    a = k.z - lo; if ((unsigned)a < (unsigned)CHK) atomicAdd(&cnt[a], 1u);
    a = k.w - lo; if ((unsigned)a < (unsigned)CHK) atomicAdd(&cnt[a], 1u);
  }
  __syncthreads();
  unsigned* p = partials + (long)sl * NN + lo;
  for (int i = threadIdx.x; i < CHK; i += 256) p[i] = cnt[i];
}

__global__ __launch_bounds__(256) void deg_scan_kernel(
    const unsigned* __restrict__ pd, const unsigned* __restrict__ ps,
    int* __restrict__ row_ptr, int* __restrict__ bsum,
    float* __restrict__ inv_mean, float* __restrict__ inv_in,
    float* __restrict__ inv_out) {
  __shared__ int sh[256];
  int n = blockIdx.x * 256 + threadIdx.x;
  unsigned di = 0, dz = 0;
  if (n < NN) {
    #pragma unroll 8
    for (int sl = 0; sl < NSL; ++sl) {
      di += pd[(long)sl * NN + n];
      dz += ps[(long)sl * NN + n];
    }
    float fdi = fmaxf((float)di, 1.f), fdz = fmaxf((float)dz, 1.f);
    inv_mean[n] = 1.f / fdi;
    inv_in[n]  = rsqrtf(fdi);
    inv_out[n] = rsqrtf(fdz);
  }
  int v = (n < NN) ? (int)di : 0;
  sh[threadIdx.x] = v;
  __syncthreads();
  #pragma unroll
  for (int off = 1; off < 256; off <<= 1) {
    int tv = (threadIdx.x >= off) ? sh[threadIdx.x - off] : 0;
    __syncthreads();
    sh[threadIdx.x] += tv;
    __syncthreads();
  }
  if (n < NN) row_ptr[n] = sh[threadIdx.x] - v;
  if (threadIdx.x == 255) bsum[blockIdx.x] = sh[255];
}

__global__ __launch_bounds__(256) void scan_block_kernel(const int* __restrict__ counts,
                                                         int* excl, int* bsum, int n) {
  __shared__ int sh[256];
  int i = blockIdx.x * 256 + threadIdx.x;
  int v = (i < n) ? counts[i] : 0;
  sh[threadIdx.x] = v;
  __syncthreads();
  #pragma unroll
  for (int off = 1; off < 256; off <<= 1) {
    int tv = (threadIdx.x >= off) ? sh[threadIdx.x - off] : 0;
    __syncthreads();
    sh[threadIdx.x] += tv;
    __syncthreads();
  }
  if (i < n) excl[i] = sh[threadIdx.x] - v;
  if (threadIdx.x == 255 && bsum) bsum[blockIdx.x] = sh[255];
}

__global__ void cursor_init_kernel(const int* __restrict__ row_ptr, const int* __restrict__ bsum,
                                   const unsigned* __restrict__ pd,
                                   unsigned* __restrict__ cur0,
                                   const float* __restrict__ inv_mean,
                                   const float* __restrict__ inv_in,
                                   int4* __restrict__ nodeinfo) {
  int n = blockIdx.x * 256 + threadIdx.x;
  if (n >= NN) return;
  unsigned start = (unsigned)(row_ptr[n] + bsum[n >> 8]);
  unsigned run = start;
  #pragma unroll 8
  for (int sl = 0; sl < NSL; ++sl) {
    cur0[(long)sl * NN + n] = run;
    run += pd[(long)sl * NN + n];
  }
  nodeinfo[n] = make_int4((int)start, (int)run,
                          __float_as_int(inv_mean[n]), __float_as_int(inv_in[n]));
}

__global__ __launch_bounds__(256) void fill_partial_kernel(
    const int4* __restrict__ dst4, const int4* __restrict__ src4,
    const unsigned* __restrict__ cur0, int* __restrict__ col) {
  __shared__ unsigned cur[CHK];
  const int chunk = blockIdx.x & 3;
  const int sl = blockIdx.x >> 2;
  const int lo = chunk * CHK;
  const unsigned* c0 = cur0 + (long)sl * NN + lo;
  for (int i = threadIdx.x; i < CHK; i += 256) cur[i] = c0[i];
  __syncthreads();
  const int base4 = sl * (ESL / 4);
  for (int i = threadIdx.x; i < ESL / 4; i += 256) {
    int4 d = dst4[base4 + i];
    int4 s = src4[base4 + i];
    int a;
    a = d.x - lo; if ((unsigned)a < (unsigned)CHK) __builtin_nontemporal_store(s.x, &col[atomicAdd(&cur[a], 1u)]);
    a = d.y - lo; if ((unsigned)a < (unsigned)CHK) __builtin_nontemporal_store(s.y, &col[atomicAdd(&cur[a], 1u)]);
    a = d.z - lo; if ((unsigned)a < (unsigned)CHK) __builtin_nontemporal_store(s.z, &col[atomicAdd(&cur[a], 1u)]);
    a = d.w - lo; if ((unsigned)a < (unsigned)CHK) __builtin_nontemporal_store(s.w, &col[atomicAdd(&cur[a], 1u)]);
  }
}

// ---------------- SpMM: 4 slices x 32 feats (L2-resident), 2 nodes per wave ----------------
// MODE 0: mean-agg. MODE 1: GCN layer (×inv_in, bias-folded BN, relu). MODE 2: +residual.
// Output via non-temporal stores (consumed cross-XCD -> keep lines clean).

template<int MODE>
__global__ __launch_bounds__(256) void spmm32p_kernel(
    const int4* __restrict__ nodeinfo, const int* __restrict__ cols,
    const __half* __restrict__ xs,
    const float* __restrict__ bnsc, const float* __restrict__ bnsh,
    const __half* __restrict__ resp,
    __half* __restrict__ outh) {
  const int t = threadIdx.x;
  const int lane = t & 63;
  const int wv = t >> 6;
  const int b = blockIdx.x;
  const int xcd = b & 7;
  const int slice = xcd >> 1;
  const int sub = xcd & 1;
  const int npair = lane >> 5;
  const int node = (b >> 3) * 16 + sub * 8 + wv * 2 + npair;  // NN = 3125*16
  const int e8 = (lane >> 2) & 7;
  const int q4 = lane & 3;
  const __half* xb = xs + (long)slice * NN * 32 + q4 * 8;
  int4 ni = nodeinfo[node];
  const int e0 = ni.x, end = ni.y;
  const float d = __int_as_float(MODE == 0 ? ni.z : ni.w);
  const int deg = end - e0;
  int dmax = deg > 0 ? deg : 0;
  {
    int od = __shfl_xor(dmax, 32, 64);
    dmax = dmax > od ? dmax : od;
  }
  const int kmax = (dmax + 7) >> 3;
  const int ecl = (end - 1) > 0 ? (end - 1) : 0;
  const __half2 z2 = __float2half2_rn(0.f);
  __half2 A0 = z2, A1 = z2, A2 = z2, A3 = z2;
  __half2 B0 = z2, B1 = z2, B2 = z2, B3 = z2;
  int k = 0;
  for (; k + 2 <= kmax; k += 2) {
    int ee0 = e0 + k * 8 + e8;
    int ee1 = ee0 + 8;
    bool m0 = ee0 < end, m1 = ee1 < end;
    int s0 = cols[m0 ? ee0 : ecl];
    int s1 = cols[m1 ? ee1 : ecl];
    f32x4 v0 = *(const f32x4*)(xb + (unsigned)s0 * 32u);
    f32x4 v1 = *(const f32x4*)(xb + (unsigned)s1 * 32u);
    const __half2* h0 = (const __half2*)&v0;
    const __half2* h1 = (const __half2*)&v1;
    A0 = __hadd2(A0, m0 ? h0[0] : z2); A1 = __hadd2(A1, m0 ? h0[1] : z2);
    A2 = __hadd2(A2, m0 ? h0[2] : z2); A3 = __hadd2(A3, m0 ? h0[3] : z2);
    B0 = __hadd2(B0, m1 ? h1[0] : z2); B1 = __hadd2(B1, m1 ? h1[1] : z2);
    B2 = __hadd2(B2, m1 ? h1[2] : z2); B3 = __hadd2(B3, m1 ? h1[3] : z2);
  }
  if (k < kmax) {
    int ee = e0 + k * 8 + e8;
    bool m = ee < end;
    int s = cols[m ? ee : ecl];
    f32x4 v = *(const f32x4*)(xb + (unsigned)s * 32u);
    const __half2* h = (const __half2*)&v;
    A0 = __hadd2(A0, m ? h[0] : z2); A1 = __hadd2(A1, m ? h[1] : z2);
    A2 = __hadd2(A2, m ? h[2] : z2); A3 = __hadd2(A3, m ? h[3] : z2);
  }
  A0 = __hadd2(A0, B0); A1 = __hadd2(A1, B1);
  A2 = __hadd2(A2, B2); A3 = __hadd2(A3, B3);
  float2 p0 = __half22float2(A0), p1 = __half22float2(A1);
  float2 p2 = __half22float2(A2), p3 = __half22float2(A3);
  float f0 = p0.x, f1 = p0.y, f2 = p1.x, f3 = p1.y;
  float f4 = p2.x, f5 = p2.y, f6 = p3.x, f7 = p3.y;
  {
    bool hi = (lane & 4) != 0;
    float t0 = hi ? f0 : f4, t1 = hi ? f1 : f5, t2 = hi ? f2 : f6, t3 = hi ? f3 : f7;
    t0 = __shfl_xor(t0, 4, 64); t1 = __shfl_xor(t1, 4, 64);
    t2 = __shfl_xor(t2, 4, 64); t3 = __shfl_xor(t3, 4, 64);
    f0 = (hi ? f4 : f0) + t0; f1 = (hi ? f5 : f1) + t1;
    f2 = (hi ? f6 : f2) + t2; f3 = (hi ? f7 : f3) + t3;
  }
  {
    bool hi = (lane & 8) != 0;
    float t0 = hi ? f0 : f2, t1 = hi ? f1 : f3;
    t0 = __shfl_xor(t0, 8, 64); t1 = __shfl_xor(t1, 8, 64);
    f0 = (hi ? f2 : f0) + t0; f1 = (hi ? f3 : f1) + t1;
  }
  float fin;
  {
    bool hi = (lane & 16) != 0;
    float t0 = hi ? f0 : f1;
    t0 = __shfl_xor(t0, 16, 64);
    fin = (hi ? f1 : f0) + t0;
  }
  int foff = q4 * 8 + ((lane >> 2) & 1) * 4 + ((lane >> 3) & 1) * 2 + ((lane >> 4) & 1);
  long oidx = ((long)slice * NN + node) * 32 + foff;
  float v = fin * d;
  if (MODE >= 1) {
    int f = slice * 32 + foff;
    v = fmaxf(v * bnsc[f] + bnsh[f], 0.f);
    if (MODE == 2) v += __half2float(resp[oidx]);
  }
  nt_store_h(__float2half(v), &outh[oidx]);
}

// ---------------- fused weight prepack + BN fold ----------------

constexpr int SZ256 = 8 * 8 * 512;   // K=256, NTP=8
constexpr int SZ128 = 4 * 8 * 512;   // K=128, NTP=8
constexpr int SZOUT = 4 * 4 * 512;   // K=128, NTP=4
constexpr int PK_TOTAL = 3 * SZ256 + 3 * SZ128 + SZOUT;
constexpr int PK_ALL = PK_TOTAL + 3 * HF;   // + BN fold

__global__ __launch_bounds__(256) void prepack_all_kernel(
    const float* __restrict__ w_in, const float* __restrict__ agg_w,
    const float* __restrict__ at1, const float* __restrict__ gc_w,
    const float* __restrict__ out_w, ushort* __restrict__ outbase,
    const float* __restrict__ gc_b, const float* __restrict__ bn_gamma,
    const float* __restrict__ bn_beta, const float* __restrict__ bn_mean,
    const float* __restrict__ bn_var,
    float* __restrict__ bnsc, float* __restrict__ bnsh) {
  int idx = blockIdx.x * 256 + threadIdx.x;
  if (idx >= PK_ALL) return;
  if (idx >= PK_TOTAL) {
    int i = idx - PK_TOTAL;                 // l*HF + f
    float sc = bn_gamma[i] * rsqrtf(bn_var[i] + EPSV);
    bnsc[i] = sc;
    bnsh[i] = (gc_b[i] - bn_mean[i]) * sc + bn_beta[i];
    return;
  }
  const float* W; int N, ldw, NTpad, local; ushort* outp;
  if (idx < 3 * SZ256) {
    int s = idx / SZ256; local = idx - s * SZ256;
    W = (s == 0) ? w_in : ((s == 1) ? agg_w : at1);
    N = HF; ldw = HF; NTpad = 8;
    outp = outbase + s * SZ256;
  } else if (idx < 3 * SZ256 + 3 * SZ128) {
    int r = idx - 3 * SZ256; int s = r / SZ128; local = r - s * SZ128;
    W = gc_w + (long)s * HF * HF; N = HF; ldw = HF; NTpad = 8;
    outp = outbase + 3 * SZ256 + s * SZ128;
  } else {
    local = idx - 3 * SZ256 - 3 * SZ128;
    W = out_w; N = CC; ldw = CC; NTpad = 4;
    outp = outbase + 3 * SZ256 + 3 * SZ128;
  }
  int j    = local & 7;
  int lane = (local >> 3) & 63;
  int rest = local >> 9;
  int nt = rest % NTpad;
  int kc = rest / NTpad;
  int k = kc * 32 + (lane >> 4) * 8 + j;
  int n = nt * 16 + (lane & 15);
  float w = (n < N) ? W[(long)k * ldw + n] : 0.f;
  outp[local] = __half_as_ushort(__float2half(w));
}

// ---------------- fp16 MFMA GEMM: out = epi( [A1|A2] @ W + bias ) ----------------
// fp16 outputs via non-temporal stores (consumed cross-XCD -> keep lines clean).

template<int KC, int NT, int NTP, int EPI, int ASRC, int OUTM, int COLSPLIT>
__global__ __launch_bounds__(256) void mgemm_kernel(
    const void* __restrict__ A1, int lda1,
    const void* __restrict__ A2,
    const ushort* __restrict__ Bf,
    const float* __restrict__ bias,
    const float* __restrict__ g, const float* __restrict__ be,
    float* __restrict__ outf, __half* __restrict__ outh, int ldc, int Ncols,
    __half* __restrict__ x16, const float* __restrict__ rowscale) {
  const int t = threadIdx.x;
  const int lane = t & 63;
  const int wid = t >> 6;
  const int rowbase = COLSPLIT ? (blockIdx.x * 32 + (wid >> 1) * 16)
                               : (blockIdx.x * 64 + wid * 16);
  const int colbase = COLSPLIT ? ((wid & 1) * NT * 16) : 0;
  const int arow = rowbase + (lane & 15);
  const int kgrp = (lane >> 4) * 8;
  const bool rowok = arow < NN;

  f32x4 acc[NT];
  #pragma unroll
  for (int n = 0; n < NT; ++n) acc[n] = (f32x4){0.f, 0.f, 0.f, 0.f};

  const f32x4 z4 = {0.f, 0.f, 0.f, 0.f};
  f32x4 fra[ASRC == 0 ? KC : 1], frb[ASRC == 0 ? KC : 1];
  uint4 areg[ASRC == 1 ? KC : 1];
  if (ASRC == 0) {
    #pragma unroll
    for (int kc = 0; kc < KC; ++kc) {
      const float* p = (const float*)A1 + (long)arow * lda1 + kc * 32 + kgrp;
      fra[kc] = rowok ? *(const f32x4*)p : z4;
      frb[kc] = rowok ? *(const f32x4*)(p + 4) : z4;
    }
  } else {
    #pragma unroll
    for (int kc = 0; kc < KC; ++kc) {
      const bool second = (KC == 8) && (kc >= 4);
      const ushort* At = (const ushort*)(second ? A2 : A1);
      int k0 = (second ? (kc - 4) : kc) * 32 + kgrp;
      const ushort* p = At + ((long)(k0 >> 5) * NN + arow) * 32 + (k0 & 31);
      areg[kc] = rowok ? *(const uint4*)p : make_uint4(0, 0, 0, 0);
    }
  }

  #pragma unroll
  for (int kc = 0; kc < KC; ++kc) {
    f16x8 av;
    if (ASRC == 0) {
      #pragma unroll
      for (int j = 0; j < 4; ++j) {
        av[j]     = (_Float16)fra[kc][j];
        av[j + 4] = (_Float16)frb[kc][j];
      }
    } else {
      union { uint4 u; f16x8 v; } cv;
      cv.u = areg[kc];
      av = cv.v;
    }
    const ushort* bp = Bf + ((long)kc * NTP * 64 + lane) * 8 + (long)colbase * 32;
    #pragma unroll
    for (int nt = 0; nt < NT; ++nt) {
      union { uint4 u; f16x8 v; } bv;
      bv.u = *(const uint4*)(bp + (long)nt * 512);
      acc[nt] = __builtin_amdgcn_mfma_f32_16x16x32_f16(av, bv.v, acc[nt], 0, 0, 0);
    }
  }

  const int colg = lane & 15;
  const int rsub = (lane >> 4) * 4;

  if (EPI == EPI_ATTN) {
    float part0 = 0.f, part1 = 0.f, part2 = 0.f, part3 = 0.f;
    #pragma unroll
    for (int nt = 0; nt < NT; ++nt) {
      int c = nt * 16 + colg;
      float w2v = g[c];
      float bb = bias[c];
      part0 = fmaf(fmaxf(acc[nt][0] + bb, 0.f), w2v, part0);
      part1 = fmaf(fmaxf(acc[nt][1] + bb, 0.f), w2v, part1);
      part2 = fmaf(fmaxf(acc[nt][2] + bb, 0.f), w2v, part2);
      part3 = fmaf(fmaxf(acc[nt][3] + bb, 0.f), w2v, part3);
    }
    #pragma unroll
    for (int m = 1; m <= 8; m <<= 1) {
      part0 += __shfl_xor(part0, m, 64);
      part1 += __shfl_xor(part1, m, 64);
      part2 += __shfl_xor(part2, m, 64);
      part3 += __shfl_xor(part3, m, 64);
    }
    const float b2v = be[0];
    float s0 = 1.f / (1.f + __expf(-(part0 + b2v)));
    float s1 = 1.f / (1.f + __expf(-(part1 + b2v)));
    float s2 = 1.f / (1.f + __expf(-(part2 + b2v)));
    float s3 = 1.f / (1.f + __expf(-(part3 + b2v)));
    const __half* h0t = (const __half*)A1;
    const __half* aggt = (const __half*)A2;
    #pragma unroll
    for (int nt = 0; nt < NT; ++nt) {
      int c = nt * 16 + colg;
      #pragma unroll
      for (int i = 0; i < 4; ++i) {
        int r = rowbase + rsub + i;
        if (r >= NN) continue;
        long sidx = ((long)(c >> 5) * NN + r) * 32 + (c & 31);
        float sv = (i == 0) ? s0 : ((i == 1) ? s1 : ((i == 2) ? s2 : s3));
        float h = __half2float(h0t[sidx]) + __half2float(aggt[sidx]) * sv;
        nt_store_h(__float2half(h), &x16[sidx]);
      }
    }
    return;
  }

  #pragma unroll
  for (int nt = 0; nt < NT; ++nt) {
    int c = colbase + nt * 16 + colg;
    if (c >= Ncols) continue;
    float bb = bias ? bias[c] : 0.f;
    #pragma unroll
    for (int i = 0; i < 4; ++i) {
      int r = rowbase + rsub + i;
      if (r >= NN) continue;
      long sidx = ((long)(c >> 5) * NN + r) * 32 + (c & 31);
      float v = acc[nt][i] + bb;
      if (EPI == EPI_RELU) v = fmaxf(v, 0.f);
      if (OUTM == OUT_F32) {
        outf[(long)r * ldc + c] = v;
      } else if (OUTM == OUT_F16) {
        nt_store_h(__float2half(v), &outh[sidx]);
      } else {                            // OUT_F16S: z * inv_out[r]
        nt_store_h(__float2half(v * rowscale[r]), &outh[sidx]);
      }
    }
  }
}

// ---------------- launch ----------------

extern "C" void kernel_launch(void* const* d_in, const int* in_sizes, int n_in,
                              void* d_out, int out_size, void* d_ws, size_t ws_size,
                              hipStream_t stream) {
  const float* features = (const float*)d_in[0];
  const int*   src      = (const int*)d_in[1];
  const int*   dst      = (const int*)d_in[2];
  const float* w_in     = (const float*)d_in[3];
  const float* b_in     = (const float*)d_in[4];
  const float* gc_w     = (const float*)d_in[5];
  const float* gc_b     = (const float*)d_in[6];
  const float* bn_gamma = (const float*)d_in[7];
  const float* bn_beta  = (const float*)d_in[8];
  const float* bn_mean  = (const float*)d_in[9];
  const float* bn_var   = (const float*)d_in[10];
  const float* attn_w1  = (const float*)d_in[11];
  const float* attn_b1  = (const float*)d_in[12];
  const float* attn_w2  = (const float*)d_in[13];
  const float* attn_b2  = (const float*)d_in[14];
  const float* agg_w    = (const float*)d_in[15];
  const float* agg_b    = (const float*)d_in[16];
  const float* out_w    = (const float*)d_in[17];
  const float* out_b    = (const float*)d_in[18];
  float* out = (float*)d_out;

  float* fbase = (float*)d_ws;
  float* inv_mean = fbase;
  float* inv_in   = inv_mean + NN;
  float* inv_out  = inv_in + NN;
  int* row_ptr = (int*)(inv_out + NN);   // NN+16
  int* bsum    = row_ptr + NN + 16;      // 256
  int* col     = bsum + 256;             // EE
  int4* nodeinfo = (int4*)(col + EE);    // NN

  // packed fp16 weights (contiguous: win, agg, at1, gc0..2, ow) + BN fold arrays
  ushort* pk = (ushort*)(nodeinfo + NN);
  ushort* win_f = pk;
  ushort* agg_f = pk + SZ256;
  ushort* at1_f = pk + 2 * SZ256;
  ushort* gcf0  = pk + 3 * SZ256;
  ushort* gcf1  = gcf0 + SZ128;
  ushort* gcf2  = gcf1 + SZ128;
  ushort* ow_f  = gcf2 + SZ128;
  float* bnsc = (float*)(ow_f + SZOUT);  // 3*HF
  float* bnsh = bnsc + 3 * HF;           // 3*HF

  // fp16 activation pools, sliced [4][NN][32]
  __half* T0 = (__half*)(bnsh + 3 * HF); // h0
  __half* T1 = T0 + NH;                  // neigh / z (per layer)
  __half* T2 = T1 + NH;                  // agg -> rst0 -> rst2
  __half* X16 = T2 + NH;                 // h_att -> rst1

  // preprocessing scratch aliased into T0/T1 (dead before their first writes)
  unsigned* pd   = (unsigned*)T0;              // NSL*NN
  unsigned* ps   = pd + (long)NSL * NN;
  unsigned* cur0 = ps + (long)NSL * NN;

  dim3 b256(256);
  const int gN = (NN + 255) / 256;
  const int gblocks = (NN + 63) / 64;     // 782 (NT=8 blocks)
  const int gsplit  = (NN + 31) / 32;     // 1563 (col-split blocks)
  const int gspmm = (NN / 16) * 8;        // 25000
  const int gpre = NSL * 4;

  // graph preprocessing (no global atomics)
  count_partial2_kernel<<<2 * gpre, b256, 0, stream>>>(
      (const int4*)dst, (const int4*)src, pd, ps);
  deg_scan_kernel<<<gN, b256, 0, stream>>>(pd, ps, row_ptr, bsum, inv_mean, inv_in, inv_out);
  scan_block_kernel<<<1, b256, 0, stream>>>(bsum, bsum, nullptr, gN);
  cursor_init_kernel<<<gN, b256, 0, stream>>>(row_ptr, bsum, pd, cur0, inv_mean, inv_in, nodeinfo);
  fill_partial_kernel<<<gpre, b256, 0, stream>>>((const int4*)dst, (const int4*)src, cur0, col);

  // weight prepack + BN fold in one launch
  prepack_all_kernel<<<(PK_ALL + 255) / 256, b256, 0, stream>>>(
      w_in, agg_w, attn_w1, gc_w, out_w, pk,
      gc_b, bn_gamma, bn_beta, bn_mean, bn_var, bnsc, bnsh);

  // #1: h0 = relu(features @ w_in + b_in) -> T0  (col-split)
  mgemm_kernel<8, 4, 8, EPI_RELU, 0, OUT_F16, 1><<<gsplit, b256, 0, stream>>>(
      features, INF_, nullptr, win_f, b_in,
      nullptr, nullptr, nullptr, T0, HF, HF, nullptr, nullptr);
  // spmm1: neigh = mean-agg(h0) -> T1
  spmm32p_kernel<0><<<gspmm, b256, 0, stream>>>(
      nodeinfo, col, T0, nullptr, nullptr, nullptr, T1);
  // #2: agg = relu([h0|neigh] @ agg_w + agg_b) -> T2  (col-split)
  mgemm_kernel<8, 4, 8, EPI_RELU, 1, OUT_F16, 1><<<gsplit, b256, 0, stream>>>(
      T0, 0, T1, agg_f, agg_b,
      nullptr, nullptr, nullptr, T2, HF, HF, nullptr, nullptr);
  // #3 (fused attn): h_att = h0 + agg*sigmoid(relu([h0|agg]@w1+b1)@w2+b2) -> X16 (raw)
  mgemm_kernel<8, 8, 8, EPI_ATTN, 1, OUT_F16, 0><<<gblocks, b256, 0, stream>>>(
      T0, 0, T2, at1_f, attn_b1,
      attn_w2, attn_b2, nullptr, nullptr, HF, HF, X16, nullptr);

  // layer 0: z = (h_att @ gc0) * inv_out -> T1 ; spmm: rst0 = relu(BN(inv_in*sum)) -> T2
  mgemm_kernel<4, 4, 8, EPI_NONE, 1, OUT_F16S, 1><<<gsplit, b256, 0, stream>>>(
      X16, 0, nullptr, gcf0, nullptr,
      nullptr, nullptr, nullptr, T1, HF, HF, nullptr, inv_out);
  spmm32p_kernel<1><<<gspmm, b256, 0, stream>>>(
      nodeinfo, col, T1, bnsc, bnsh, nullptr, T2);
  // layer 1: z = (rst0 @ gc1) * inv_out -> T1 ; spmm: rst1 = relu(BN(..)) + rst0 -> X16
  mgemm_kernel<4, 4, 8, EPI_NONE, 1, OUT_F16S, 1><<<gsplit, b256, 0, stream>>>(
      T2, 0, nullptr, gcf1, nullptr,
      nullptr, nullptr, nullptr, T1, HF, HF, nullptr, inv_out);
  spmm32p_kernel<2><<<gspmm, b256, 0, stream>>>(
      nodeinfo, col, T1, bnsc + HF, bnsh + HF, T2, X16);
  // layer 2: z = (rst1 @ gc2) * inv_out -> T1 ; spmm: rst2 = relu(BN(..)) + rst1 -> T2
  mgemm_kernel<4, 4, 8, EPI_NONE, 1, OUT_F16S, 1><<<gsplit, b256, 0, stream>>>(
      X16, 0, nullptr, gcf2, nullptr,
      nullptr, nullptr, nullptr, T1, HF, HF, nullptr, inv_out);
  spmm32p_kernel<2><<<gspmm, b256, 0, stream>>>(
      nodeinfo, col, T1, bnsc + 2 * HF, bnsh + 2 * HF, X16, T2);

  // out = rst2 @ out_w + out_b -> d_out (fp32; NT=4 covers 64 >= 50 cols)
  mgemm_kernel<4, 4, 4, EPI_NONE, 1, OUT_F32, 0><<<gblocks, b256, 0, stream>>>(
      T2, 0, nullptr, ow_f, out_b,
      nullptr, nullptr, out, nullptr, CC, CC, nullptr, nullptr);
}

// Round 21
// 319.814 us; speedup vs baseline: 1.1100x; 1.1100x over previous
//
#include <hip/hip_runtime.h>
#include <hip/hip_fp16.h>
#include <math.h>

constexpr int NN  = 50000;   // nodes
constexpr int EE  = 800000;  // edges
constexpr int INF_ = 256;    // input feat
constexpr int HF  = 128;     // hidden
constexpr int CC  = 50;      // classes
constexpr long NH = (long)NN * HF;
constexpr int NSL = 32;          // edge slices (preprocessing)
constexpr int ESL = EE / NSL;    // 25000 edges per slice
constexpr int CHK = 12500;       // nodes per chunk (4 chunks), 50KB LDS
#define EPSV 1e-5f

enum { EPI_RELU = 0, EPI_NONE = 1, EPI_BN = 2, EPI_BN_RES = 3, EPI_ATTN = 4 };
enum { H16_NONE = 0, H16_SCALED = 2 };

typedef __attribute__((ext_vector_type(4))) float f32x4;
typedef __attribute__((ext_vector_type(8))) _Float16 f16x8;

// ---------------- graph preprocessing (atomic-free: LDS histograms) ----------------

__global__ __launch_bounds__(256) void count_partial2_kernel(
    const int4* __restrict__ dst4, const int4* __restrict__ src4,
    unsigned* __restrict__ pd, unsigned* __restrict__ ps) {
  __shared__ unsigned cnt[CHK];
  int bb = blockIdx.x;
  const int which = bb >> 7;
  bb &= 127;
  const int4* keys4 = which ? src4 : dst4;
  unsigned* partials = which ? ps : pd;
  const int chunk = bb & 3;
  const int sl = bb >> 2;
  for (int i = threadIdx.x; i < CHK; i += 256) cnt[i] = 0;
  __syncthreads();
  const int base4 = sl * (ESL / 4);
  const int lo = chunk * CHK;
  for (int i = threadIdx.x; i < ESL / 4; i += 256) {
    int4 k = keys4[base4 + i];
    int a;
    a = k.x - lo; if ((unsigned)a < (unsigned)CHK) atomicAdd(&cnt[a], 1u);
    a = k.y - lo; if ((unsigned)a < (unsigned)CHK) atomicAdd(&cnt[a], 1u);
    a = k.z - lo; if ((unsigned)a < (unsigned)CHK) atomicAdd(&cnt[a], 1u);
    a = k.w - lo; if ((unsigned)a < (unsigned)CHK) atomicAdd(&cnt[a], 1u);
  }
  __syncthreads();
  unsigned* p = partials + (long)sl * NN + lo;
  for (int i = threadIdx.x; i < CHK; i += 256) p[i] = cnt[i];
}

__global__ __launch_bounds__(256) void deg_scan_kernel(
    const unsigned* __restrict__ pd, const unsigned* __restrict__ ps,
    int* __restrict__ row_ptr, int* __restrict__ bsum,
    float* __restrict__ inv_mean, float* __restrict__ inv_in,
    float* __restrict__ inv_out) {
  __shared__ int sh[256];
  int n = blockIdx.x * 256 + threadIdx.x;
  unsigned di = 0, dz = 0;
  if (n < NN) {
    #pragma unroll 8
    for (int sl = 0; sl < NSL; ++sl) {
      di += pd[(long)sl * NN + n];
      dz += ps[(long)sl * NN + n];
    }
    float fdi = fmaxf((float)di, 1.f), fdz = fmaxf((float)dz, 1.f);
    inv_mean[n] = 1.f / fdi;
    inv_in[n]  = rsqrtf(fdi);
    inv_out[n] = rsqrtf(fdz);
  }
  int v = (n < NN) ? (int)di : 0;
  sh[threadIdx.x] = v;
  __syncthreads();
  #pragma unroll
  for (int off = 1; off < 256; off <<= 1) {
    int tv = (threadIdx.x >= off) ? sh[threadIdx.x - off] : 0;
    __syncthreads();
    sh[threadIdx.x] += tv;
    __syncthreads();
  }
  if (n < NN) row_ptr[n] = sh[threadIdx.x] - v;
  if (threadIdx.x == 255) bsum[blockIdx.x] = sh[255];
}

__global__ __launch_bounds__(256) void scan_block_kernel(const int* __restrict__ counts,
                                                         int* excl, int* bsum, int n) {
  __shared__ int sh[256];
  int i = blockIdx.x * 256 + threadIdx.x;
  int v = (i < n) ? counts[i] : 0;
  sh[threadIdx.x] = v;
  __syncthreads();
  #pragma unroll
  for (int off = 1; off < 256; off <<= 1) {
    int tv = (threadIdx.x >= off) ? sh[threadIdx.x - off] : 0;
    __syncthreads();
    sh[threadIdx.x] += tv;
    __syncthreads();
  }
  if (i < n) excl[i] = sh[threadIdx.x] - v;
  if (threadIdx.x == 255 && bsum) bsum[blockIdx.x] = sh[255];
}

__global__ void cursor_init_kernel(const int* __restrict__ row_ptr, const int* __restrict__ bsum,
                                   const unsigned* __restrict__ pd,
                                   unsigned* __restrict__ cur0,
                                   const float* __restrict__ inv_mean,
                                   const float* __restrict__ inv_in,
                                   int4* __restrict__ nodeinfo) {
  int n = blockIdx.x * 256 + threadIdx.x;
  if (n >= NN) return;
  unsigned start = (unsigned)(row_ptr[n] + bsum[n >> 8]);
  unsigned run = start;
  #pragma unroll 8
  for (int sl = 0; sl < NSL; ++sl) {
    cur0[(long)sl * NN + n] = run;
    run += pd[(long)sl * NN + n];
  }
  nodeinfo[n] = make_int4((int)start, (int)run,
                          __float_as_int(inv_mean[n]), __float_as_int(inv_in[n]));
}

__global__ __launch_bounds__(256) void fill_partial_kernel(
    const int4* __restrict__ dst4, const int4* __restrict__ src4,
    const unsigned* __restrict__ cur0, int* __restrict__ col) {
  __shared__ unsigned cur[CHK];
  const int chunk = blockIdx.x & 3;
  const int sl = blockIdx.x >> 2;
  const int lo = chunk * CHK;
  const unsigned* c0 = cur0 + (long)sl * NN + lo;
  for (int i = threadIdx.x; i < CHK; i += 256) cur[i] = c0[i];
  __syncthreads();
  const int base4 = sl * (ESL / 4);
  for (int i = threadIdx.x; i < ESL / 4; i += 256) {
    int4 d = dst4[base4 + i];
    int4 s = src4[base4 + i];
    int a;
    a = d.x - lo; if ((unsigned)a < (unsigned)CHK) col[atomicAdd(&cur[a], 1u)] = s.x;
    a = d.y - lo; if ((unsigned)a < (unsigned)CHK) col[atomicAdd(&cur[a], 1u)] = s.y;
    a = d.z - lo; if ((unsigned)a < (unsigned)CHK) col[atomicAdd(&cur[a], 1u)] = s.z;
    a = d.w - lo; if ((unsigned)a < (unsigned)CHK) col[atomicAdd(&cur[a], 1u)] = s.w;
  }
}

// ---------------- SpMM: 4 slices x 32 feats (L2-resident), 2 nodes per wave ----------------

__global__ __launch_bounds__(256) void spmm32p_kernel(
    const int4* __restrict__ nodeinfo, const int* __restrict__ cols,
    const __half* __restrict__ xs, int useW,
    __half* __restrict__ outh) {
  const int t = threadIdx.x;
  const int lane = t & 63;
  const int wv = t >> 6;
  const int b = blockIdx.x;
  const int xcd = b & 7;
  const int slice = xcd >> 1;
  const int sub = xcd & 1;
  const int npair = lane >> 5;
  const int node = (b >> 3) * 16 + sub * 8 + wv * 2 + npair;  // NN = 3125*16
  const int e8 = (lane >> 2) & 7;
  const int q4 = lane & 3;
  const __half* xb = xs + (long)slice * NN * 32 + q4 * 8;
  int4 ni = nodeinfo[node];
  const int e0 = ni.x, end = ni.y;
  const float d = __int_as_float(useW ? ni.w : ni.z);
  const int deg = end - e0;
  int dmax = deg > 0 ? deg : 0;
  {
    int od = __shfl_xor(dmax, 32, 64);
    dmax = dmax > od ? dmax : od;
  }
  const int kmax = (dmax + 7) >> 3;
  const int ecl = (end - 1) > 0 ? (end - 1) : 0;
  const __half2 z2 = __float2half2_rn(0.f);
  __half2 A0 = z2, A1 = z2, A2 = z2, A3 = z2;
  __half2 B0 = z2, B1 = z2, B2 = z2, B3 = z2;
  int k = 0;
  for (; k + 2 <= kmax; k += 2) {
    int ee0 = e0 + k * 8 + e8;
    int ee1 = ee0 + 8;
    bool m0 = ee0 < end, m1 = ee1 < end;
    int s0 = cols[m0 ? ee0 : ecl];
    int s1 = cols[m1 ? ee1 : ecl];
    f32x4 v0 = *(const f32x4*)(xb + (unsigned)s0 * 32u);
    f32x4 v1 = *(const f32x4*)(xb + (unsigned)s1 * 32u);
    const __half2* h0 = (const __half2*)&v0;
    const __half2* h1 = (const __half2*)&v1;
    A0 = __hadd2(A0, m0 ? h0[0] : z2); A1 = __hadd2(A1, m0 ? h0[1] : z2);
    A2 = __hadd2(A2, m0 ? h0[2] : z2); A3 = __hadd2(A3, m0 ? h0[3] : z2);
    B0 = __hadd2(B0, m1 ? h1[0] : z2); B1 = __hadd2(B1, m1 ? h1[1] : z2);
    B2 = __hadd2(B2, m1 ? h1[2] : z2); B3 = __hadd2(B3, m1 ? h1[3] : z2);
  }
  if (k < kmax) {
    int ee = e0 + k * 8 + e8;
    bool m = ee < end;
    int s = cols[m ? ee : ecl];
    f32x4 v = *(const f32x4*)(xb + (unsigned)s * 32u);
    const __half2* h = (const __half2*)&v;
    A0 = __hadd2(A0, m ? h[0] : z2); A1 = __hadd2(A1, m ? h[1] : z2);
    A2 = __hadd2(A2, m ? h[2] : z2); A3 = __hadd2(A3, m ? h[3] : z2);
  }
  A0 = __hadd2(A0, B0); A1 = __hadd2(A1, B1);
  A2 = __hadd2(A2, B2); A3 = __hadd2(A3, B3);
  float2 p0 = __half22float2(A0), p1 = __half22float2(A1);
  float2 p2 = __half22float2(A2), p3 = __half22float2(A3);
  float f0 = p0.x, f1 = p0.y, f2 = p1.x, f3 = p1.y;
  float f4 = p2.x, f5 = p2.y, f6 = p3.x, f7 = p3.y;
  {
    bool hi = (lane & 4) != 0;
    float t0 = hi ? f0 : f4, t1 = hi ? f1 : f5, t2 = hi ? f2 : f6, t3 = hi ? f3 : f7;
    t0 = __shfl_xor(t0, 4, 64); t1 = __shfl_xor(t1, 4, 64);
    t2 = __shfl_xor(t2, 4, 64); t3 = __shfl_xor(t3, 4, 64);
    f0 = (hi ? f4 : f0) + t0; f1 = (hi ? f5 : f1) + t1;
    f2 = (hi ? f6 : f2) + t2; f3 = (hi ? f7 : f3) + t3;
  }
  {
    bool hi = (lane & 8) != 0;
    float t0 = hi ? f0 : f2, t1 = hi ? f1 : f3;
    t0 = __shfl_xor(t0, 8, 64); t1 = __shfl_xor(t1, 8, 64);
    f0 = (hi ? f2 : f0) + t0; f1 = (hi ? f3 : f1) + t1;
  }
  float fin;
  {
    bool hi = (lane & 16) != 0;
    float t0 = hi ? f0 : f1;
    t0 = __shfl_xor(t0, 16, 64);
    fin = (hi ? f1 : f0) + t0;
  }
  int foff = q4 * 8 + ((lane >> 2) & 1) * 4 + ((lane >> 3) & 1) * 2 + ((lane >> 4) & 1);
  outh[((long)slice * NN + node) * 32 + foff] = __float2half(fin * d);
}

// ---------------- fused weight prepack: all fp32 W -> fp16 MFMA fragments ----------------

constexpr int SZ256 = 8 * 8 * 512;   // K=256, NTP=8
constexpr int SZ128 = 4 * 8 * 512;   // K=128, NTP=8
constexpr int SZOUT = 4 * 4 * 512;   // K=128, NTP=4
constexpr int PK_TOTAL = 3 * SZ256 + 3 * SZ128 + SZOUT;

__global__ __launch_bounds__(256) void prepack_all_kernel(
    const float* __restrict__ w_in, const float* __restrict__ agg_w,
    const float* __restrict__ at1, const float* __restrict__ gc_w,
    const float* __restrict__ out_w, ushort* __restrict__ outbase) {
  int idx = blockIdx.x * 256 + threadIdx.x;
  if (idx >= PK_TOTAL) return;
  const float* W; int N, ldw, NTpad, local; ushort* outp;
  if (idx < 3 * SZ256) {
    int s = idx / SZ256; local = idx - s * SZ256;
    W = (s == 0) ? w_in : ((s == 1) ? agg_w : at1);
    N = HF; ldw = HF; NTpad = 8;
    outp = outbase + s * SZ256;
  } else if (idx < 3 * SZ256 + 3 * SZ128) {
    int r = idx - 3 * SZ256; int s = r / SZ128; local = r - s * SZ128;
    W = gc_w + (long)s * HF * HF; N = HF; ldw = HF; NTpad = 8;
    outp = outbase + 3 * SZ256 + s * SZ128;
  } else {
    local = idx - 3 * SZ256 - 3 * SZ128;
    W = out_w; N = CC; ldw = CC; NTpad = 4;
    outp = outbase + 3 * SZ256 + 3 * SZ128;
  }
  int j    = local & 7;
  int lane = (local >> 3) & 63;
  int rest = local >> 9;
  int nt = rest % NTpad;
  int kc = rest / NTpad;
  int k = kc * 32 + (lane >> 4) * 8 + j;
  int n = nt * 16 + (lane & 15);
  float w = (n < N) ? W[(long)k * ldw + n] : 0.f;
  outp[local] = __half_as_ushort(__float2half(w));
}

// ---------------- fp16 MFMA GEMM: out = epi( [A1|A2] @ W + bias ) ----------------
// BHOIST=1 (KC=4 only): ALL A and B fragments loaded before the MFMA loop ->
// one latency exposure per wave (forces ~110 VGPR, breaks the serial chain).

template<int KC, int NT, int NTP, int EPI, int H16, int ASRC, int OUTM, int COLSPLIT, int BHOIST>
__global__ __launch_bounds__(256) void mgemm_kernel(
    const void* __restrict__ A1, int lda1,
    const void* __restrict__ A2,
    const ushort* __restrict__ Bf,
    const float* __restrict__ bias,
    const float* __restrict__ g, const float* __restrict__ be,
    const float* __restrict__ mu, const float* __restrict__ va,
    const __half* __restrict__ resp,
    float* __restrict__ outf, __half* __restrict__ outh, int ldc, int Ncols,
    __half* __restrict__ x16, const float* __restrict__ rowscale) {
  const int t = threadIdx.x;
  const int lane = t & 63;
  const int wid = t >> 6;
  const int rowbase = COLSPLIT ? (blockIdx.x * 32 + (wid >> 1) * 16)
                               : (blockIdx.x * 64 + wid * 16);
  const int colbase = COLSPLIT ? ((wid & 1) * NT * 16) : 0;
  const int arow = rowbase + (lane & 15);
  const int kgrp = (lane >> 4) * 8;
  const bool rowok = arow < NN;

  f32x4 acc[NT];
  #pragma unroll
  for (int n = 0; n < NT; ++n) acc[n] = (f32x4){0.f, 0.f, 0.f, 0.f};

  const f32x4 z4 = {0.f, 0.f, 0.f, 0.f};
  f32x4 fra[ASRC == 0 ? KC : 1], frb[ASRC == 0 ? KC : 1];
  uint4 areg[ASRC == 1 ? KC : 1];
  if (ASRC == 0) {
    #pragma unroll
    for (int kc = 0; kc < KC; ++kc) {
      const float* p = (const float*)A1 + (long)arow * lda1 + kc * 32 + kgrp;
      fra[kc] = rowok ? *(const f32x4*)p : z4;
      frb[kc] = rowok ? *(const f32x4*)(p + 4) : z4;
    }
  } else {
    #pragma unroll
    for (int kc = 0; kc < KC; ++kc) {
      const bool second = (KC == 8) && (kc >= 4);
      const ushort* At = (const ushort*)(second ? A2 : A1);
      int k0 = (second ? (kc - 4) : kc) * 32 + kgrp;
      const ushort* p = At + ((long)(k0 >> 5) * NN + arow) * 32 + (k0 & 31);
      areg[kc] = rowok ? *(const uint4*)p : make_uint4(0, 0, 0, 0);
    }
  }

  if (BHOIST) {
    uint4 breg[KC * NT];
    #pragma unroll
    for (int kc = 0; kc < KC; ++kc) {
      const ushort* bp = Bf + ((long)kc * NTP * 64 + lane) * 8 + (long)colbase * 32;
      #pragma unroll
      for (int nt = 0; nt < NT; ++nt)
        breg[kc * NT + nt] = *(const uint4*)(bp + (long)nt * 512);
    }
    #pragma unroll
    for (int kc = 0; kc < KC; ++kc) {
      union { uint4 u; f16x8 v; } cv;
      cv.u = areg[kc];
      #pragma unroll
      for (int nt = 0; nt < NT; ++nt) {
        union { uint4 u; f16x8 v; } bv;
        bv.u = breg[kc * NT + nt];
        acc[nt] = __builtin_amdgcn_mfma_f32_16x16x32_f16(cv.v, bv.v, acc[nt], 0, 0, 0);
      }
    }
  } else {
    #pragma unroll
    for (int kc = 0; kc < KC; ++kc) {
      f16x8 av;
      if (ASRC == 0) {
        #pragma unroll
        for (int j = 0; j < 4; ++j) {
          av[j]     = (_Float16)fra[kc][j];
          av[j + 4] = (_Float16)frb[kc][j];
        }
      } else {
        union { uint4 u; f16x8 v; } cv;
        cv.u = areg[kc];
        av = cv.v;
      }
      const ushort* bp = Bf + ((long)kc * NTP * 64 + lane) * 8 + (long)colbase * 32;
      #pragma unroll
      for (int nt = 0; nt < NT; ++nt) {
        union { uint4 u; f16x8 v; } bv;
        bv.u = *(const uint4*)(bp + (long)nt * 512);
        acc[nt] = __builtin_amdgcn_mfma_f32_16x16x32_f16(av, bv.v, acc[nt], 0, 0, 0);
      }
    }
  }

  const int colg = lane & 15;
  const int rsub = (lane >> 4) * 4;

  if (EPI == EPI_ATTN) {
    float part0 = 0.f, part1 = 0.f, part2 = 0.f, part3 = 0.f;
    #pragma unroll
    for (int nt = 0; nt < NT; ++nt) {
      int c = nt * 16 + colg;
      float w2v = g[c];
      float bb = bias[c];
      part0 = fmaf(fmaxf(acc[nt][0] + bb, 0.f), w2v, part0);
      part1 = fmaf(fmaxf(acc[nt][1] + bb, 0.f), w2v, part1);
      part2 = fmaf(fmaxf(acc[nt][2] + bb, 0.f), w2v, part2);
      part3 = fmaf(fmaxf(acc[nt][3] + bb, 0.f), w2v, part3);
    }
    #pragma unroll
    for (int m = 1; m <= 8; m <<= 1) {
      part0 += __shfl_xor(part0, m, 64);
      part1 += __shfl_xor(part1, m, 64);
      part2 += __shfl_xor(part2, m, 64);
      part3 += __shfl_xor(part3, m, 64);
    }
    const float b2v = be[0];
    float s0 = 1.f / (1.f + __expf(-(part0 + b2v)));
    float s1 = 1.f / (1.f + __expf(-(part1 + b2v)));
    float s2 = 1.f / (1.f + __expf(-(part2 + b2v)));
    float s3 = 1.f / (1.f + __expf(-(part3 + b2v)));
    const __half* h0t = (const __half*)A1;
    const __half* aggt = (const __half*)A2;
    #pragma unroll
    for (int nt = 0; nt < NT; ++nt) {
      int c = nt * 16 + colg;
      #pragma unroll
      for (int i = 0; i < 4; ++i) {
        int r = rowbase + rsub + i;
        if (r >= NN) continue;
        long sidx = ((long)(c >> 5) * NN + r) * 32 + (c & 31);
        float sv = (i == 0) ? s0 : ((i == 1) ? s1 : ((i == 2) ? s2 : s3));
        float h = __half2float(h0t[sidx]) + __half2float(aggt[sidx]) * sv;
        x16[sidx] = __float2half(h * rowscale[r]);
      }
    }
    return;
  }

  #pragma unroll
  for (int nt = 0; nt < NT; ++nt) {
    int c = colbase + nt * 16 + colg;
    if (c >= Ncols) continue;
    float bb = bias ? bias[c] : 0.f;
    float scale = 1.f, shift = 0.f;
    if (EPI == EPI_BN || EPI == EPI_BN_RES) {
      scale = g[c] * rsqrtf(va[c] + EPSV);
      shift = be[c] - mu[c] * scale;
    }
    #pragma unroll
    for (int i = 0; i < 4; ++i) {
      int r = rowbase + rsub + i;
      if (r >= NN) continue;
      long sidx = ((long)(c >> 5) * NN + r) * 32 + (c & 31);
      float v = acc[nt][i] + bb;
      if (EPI == EPI_RELU) {
        v = fmaxf(v, 0.f);
      } else if (EPI == EPI_BN || EPI == EPI_BN_RES) {
        v = fmaxf(v * scale + shift, 0.f);
        if (EPI == EPI_BN_RES) v += __half2float(resp[sidx]);
      }
      if (OUTM == 0) {
        outf[(long)r * ldc + c] = v;
      } else {
        outh[sidx] = __float2half(v);
        if (H16 == H16_SCALED) x16[sidx] = __float2half(v * rowscale[r]);
      }
    }
  }
}

// ---------------- launch ----------------

extern "C" void kernel_launch(void* const* d_in, const int* in_sizes, int n_in,
                              void* d_out, int out_size, void* d_ws, size_t ws_size,
                              hipStream_t stream) {
  const float* features = (const float*)d_in[0];
  const int*   src      = (const int*)d_in[1];
  const int*   dst      = (const int*)d_in[2];
  const float* w_in     = (const float*)d_in[3];
  const float* b_in     = (const float*)d_in[4];
  const float* gc_w     = (const float*)d_in[5];
  const float* gc_b     = (const float*)d_in[6];
  const float* bn_gamma = (const float*)d_in[7];
  const float* bn_beta  = (const float*)d_in[8];
  const float* bn_mean  = (const float*)d_in[9];
  const float* bn_var   = (const float*)d_in[10];
  const float* attn_w1  = (const float*)d_in[11];
  const float* attn_b1  = (const float*)d_in[12];
  const float* attn_w2  = (const float*)d_in[13];
  const float* attn_b2  = (const float*)d_in[14];
  const float* agg_w    = (const float*)d_in[15];
  const float* agg_b    = (const float*)d_in[16];
  const float* out_w    = (const float*)d_in[17];
  const float* out_b    = (const float*)d_in[18];
  float* out = (float*)d_out;

  float* fbase = (float*)d_ws;
  float* inv_mean = fbase;
  float* inv_in   = inv_mean + NN;
  float* inv_out  = inv_in + NN;
  int* row_ptr = (int*)(inv_out + NN);   // NN+16
  int* bsum    = row_ptr + NN + 16;      // 256
  int* col     = bsum + 256;             // EE
  int4* nodeinfo = (int4*)(col + EE);    // NN

  // packed fp16 weights (contiguous: win, agg, at1, gc0..2, ow)
  ushort* pk = (ushort*)(nodeinfo + NN);
  ushort* win_f = pk;
  ushort* agg_f = pk + SZ256;
  ushort* at1_f = pk + 2 * SZ256;
  ushort* gcf0  = pk + 3 * SZ256;
  ushort* gcf1  = gcf0 + SZ128;
  ushort* gcf2  = gcf1 + SZ128;
  ushort* ow_f  = gcf2 + SZ128;

  // fp16 activation pools, sliced [4][NN][32]
  __half* T0 = (__half*)(ow_f + SZOUT);  // h0 -> rst1
  __half* T1 = T0 + NH;                  // neigh / spmm rst
  __half* T2 = T1 + NH;                  // agg -> rst0 -> rst2
  __half* X16 = T2 + NH;                 // scaled gather table

  // preprocessing scratch aliased into T0/T1 (dead before their first writes)
  unsigned* pd   = (unsigned*)T0;              // NSL*NN
  unsigned* ps   = pd + (long)NSL * NN;
  unsigned* cur0 = ps + (long)NSL * NN;

  dim3 b256(256);
  const int gN = (NN + 255) / 256;
  const int gblocks = (NN + 63) / 64;     // 782 (NT=8 blocks)
  const int gsplit  = (NN + 31) / 32;     // 1563 (col-split blocks)
  const int gspmm = (NN / 16) * 8;        // 25000
  const int gpre = NSL * 4;

  // graph preprocessing (no global atomics)
  count_partial2_kernel<<<2 * gpre, b256, 0, stream>>>(
      (const int4*)dst, (const int4*)src, pd, ps);
  deg_scan_kernel<<<gN, b256, 0, stream>>>(pd, ps, row_ptr, bsum, inv_mean, inv_in, inv_out);
  scan_block_kernel<<<1, b256, 0, stream>>>(bsum, bsum, nullptr, gN);
  cursor_init_kernel<<<gN, b256, 0, stream>>>(row_ptr, bsum, pd, cur0, inv_mean, inv_in, nodeinfo);
  fill_partial_kernel<<<gpre, b256, 0, stream>>>((const int4*)dst, (const int4*)src, cur0, col);

  // all weight prepack in one launch
  prepack_all_kernel<<<(PK_TOTAL + 255) / 256, b256, 0, stream>>>(
      w_in, agg_w, attn_w1, gc_w, out_w, pk);

  // #1: h0 = relu(features @ w_in + b_in) -> T0  (col-split)
  mgemm_kernel<8, 4, 8, EPI_RELU, H16_NONE, 0, 1, 1, 0><<<gsplit, b256, 0, stream>>>(
      features, INF_, nullptr, win_f, b_in,
      nullptr, nullptr, nullptr, nullptr, nullptr,
      nullptr, T0, HF, HF, nullptr, nullptr);
  // spmm1: neigh = mean-agg(h0) -> T1
  spmm32p_kernel<<<gspmm, b256, 0, stream>>>(nodeinfo, col, T0, 0, T1);
  // #2: agg = relu([h0|neigh] @ agg_w + agg_b) -> T2  (col-split)
  mgemm_kernel<8, 4, 8, EPI_RELU, H16_NONE, 1, 1, 1, 0><<<gsplit, b256, 0, stream>>>(
      T0, 0, T1, agg_f, agg_b,
      nullptr, nullptr, nullptr, nullptr, nullptr,
      nullptr, T2, HF, HF, nullptr, nullptr);
  // #3 (fused attn): needs full row per wave -> NT=8, no col-split
  mgemm_kernel<8, 8, 8, EPI_ATTN, H16_NONE, 1, 1, 0, 0><<<gblocks, b256, 0, stream>>>(
      T0, 0, T2, at1_f, attn_b1,
      attn_w2, attn_b2, nullptr, nullptr, nullptr,
      nullptr, nullptr, HF, HF, X16, inv_out);

  // layer 0: spmm(X16) -> T1 ; rst0 = relu(BN(T1@gc0+b0)) -> T2 (+X16)  (col-split, B-hoist)
  spmm32p_kernel<<<gspmm, b256, 0, stream>>>(nodeinfo, col, X16, 1, T1);
  mgemm_kernel<4, 4, 8, EPI_BN, H16_SCALED, 1, 1, 1, 1><<<gsplit, b256, 0, stream>>>(
      T1, 0, nullptr, gcf0, gc_b,
      bn_gamma, bn_beta, bn_mean, bn_var, nullptr,
      nullptr, T2, HF, HF, X16, inv_out);
  // layer 1
  spmm32p_kernel<<<gspmm, b256, 0, stream>>>(nodeinfo, col, X16, 1, T1);
  mgemm_kernel<4, 4, 8, EPI_BN_RES, H16_SCALED, 1, 1, 1, 1><<<gsplit, b256, 0, stream>>>(
      T1, 0, nullptr, gcf1, gc_b + HF,
      bn_gamma + HF, bn_beta + HF, bn_mean + HF, bn_var + HF, T2,
      nullptr, T0, HF, HF, X16, inv_out);
  // layer 2
  spmm32p_kernel<<<gspmm, b256, 0, stream>>>(nodeinfo, col, X16, 1, T1);
  mgemm_kernel<4, 4, 8, EPI_BN_RES, H16_NONE, 1, 1, 1, 1><<<gsplit, b256, 0, stream>>>(
      T1, 0, nullptr, gcf2, gc_b + 2 * HF,
      bn_gamma + 2 * HF, bn_beta + 2 * HF, bn_mean + 2 * HF, bn_var + 2 * HF, T0,
      nullptr, T2, HF, HF, nullptr, nullptr);

  // out = rst2 @ out_w + out_b -> d_out (fp32; NT=4 covers 64 >= 50 cols; B-hoist)
  mgemm_kernel<4, 4, 4, EPI_NONE, H16_NONE, 1, 0, 0, 1><<<gblocks, b256, 0, stream>>>(
      T2, 0, nullptr, ow_f, out_b,
      nullptr, nullptr, nullptr, nullptr, nullptr,
      out, nullptr, CC, CC, nullptr, nullptr);
}

// Round 22
// 310.461 us; speedup vs baseline: 1.1435x; 1.0301x over previous
//
#include <hip/hip_runtime.h>
#include <hip/hip_fp16.h>
#include <math.h>

constexpr int NN  = 50000;   // nodes
constexpr int EE  = 800000;  // edges
constexpr int INF_ = 256;    // input feat
constexpr int HF  = 128;     // hidden
constexpr int CC  = 50;      // classes
constexpr long NH = (long)NN * HF;
constexpr int NSL = 32;          // edge slices (preprocessing)
constexpr int ESL = EE / NSL;    // 25000 edges per slice
constexpr int CHK = 12500;       // nodes per chunk (4 chunks), 50KB LDS
#define EPSV 1e-5f

enum { EPI_RELU = 0, EPI_NONE = 1, EPI_BN = 2, EPI_BN_RES = 3, EPI_ATTN = 4 };
enum { H16_NONE = 0, H16_SCALED = 2 };

typedef __attribute__((ext_vector_type(4))) float f32x4;
typedef __attribute__((ext_vector_type(8))) _Float16 f16x8;

constexpr int SZ256 = 8 * 8 * 512;   // K=256, NTP=8
constexpr int SZ128 = 4 * 8 * 512;   // K=128, NTP=8
constexpr int SZOUT = 4 * 4 * 512;   // K=128, NTP=4
constexpr int PK_TOTAL = 3 * SZ256 + 3 * SZ128 + SZOUT;
constexpr int PKB = (PK_TOTAL + 255) / 256;   // prepack blocks (608)

// ---------------- FUSE1: edge histograms (256 blocks) + weight prepack (PKB blocks) ----------------

__global__ __launch_bounds__(256) void fuse1_kernel(
    const int4* __restrict__ dst4, const int4* __restrict__ src4,
    unsigned* __restrict__ pd, unsigned* __restrict__ ps,
    const float* __restrict__ w_in, const float* __restrict__ agg_w,
    const float* __restrict__ at1, const float* __restrict__ gc_w,
    const float* __restrict__ out_w, ushort* __restrict__ outbase) {
  __shared__ unsigned cnt[CHK];
  if (blockIdx.x < 256) {
    int bb = blockIdx.x;
    const int which = bb >> 7;
    bb &= 127;
    const int4* keys4 = which ? src4 : dst4;
    unsigned* partials = which ? ps : pd;
    const int chunk = bb & 3;
    const int sl = bb >> 2;
    for (int i = threadIdx.x; i < CHK; i += 256) cnt[i] = 0;
    __syncthreads();
    const int base4 = sl * (ESL / 4);
    const int lo = chunk * CHK;
    for (int i = threadIdx.x; i < ESL / 4; i += 256) {
      int4 k = keys4[base4 + i];
      int a;
      a = k.x - lo; if ((unsigned)a < (unsigned)CHK) atomicAdd(&cnt[a], 1u);
      a = k.y - lo; if ((unsigned)a < (unsigned)CHK) atomicAdd(&cnt[a], 1u);
      a = k.z - lo; if ((unsigned)a < (unsigned)CHK) atomicAdd(&cnt[a], 1u);
      a = k.w - lo; if ((unsigned)a < (unsigned)CHK) atomicAdd(&cnt[a], 1u);
    }
    __syncthreads();
    unsigned* p = partials + (long)sl * NN + lo;
    for (int i = threadIdx.x; i < CHK; i += 256) p[i] = cnt[i];
    return;
  }
  // prepack branch
  int idx = (blockIdx.x - 256) * 256 + threadIdx.x;
  if (idx >= PK_TOTAL) return;
  const float* W; int N, ldw, NTpad, local; ushort* outp;
  if (idx < 3 * SZ256) {
    int s = idx / SZ256; local = idx - s * SZ256;
    W = (s == 0) ? w_in : ((s == 1) ? agg_w : at1);
    N = HF; ldw = HF; NTpad = 8;
    outp = outbase + s * SZ256;
  } else if (idx < 3 * SZ256 + 3 * SZ128) {
    int r = idx - 3 * SZ256; int s = r / SZ128; local = r - s * SZ128;
    W = gc_w + (long)s * HF * HF; N = HF; ldw = HF; NTpad = 8;
    outp = outbase + 3 * SZ256 + s * SZ128;
  } else {
    local = idx - 3 * SZ256 - 3 * SZ128;
    W = out_w; N = CC; ldw = CC; NTpad = 4;
    outp = outbase + 3 * SZ256 + 3 * SZ128;
  }
  int j    = local & 7;
  int lane = (local >> 3) & 63;
  int rest = local >> 9;
  int nt = rest % NTpad;
  int kc = rest / NTpad;
  int k = kc * 32 + (lane >> 4) * 8 + j;
  int n = nt * 16 + (lane & 15);
  float w = (n < N) ? W[(long)k * ldw + n] : 0.f;
  outp[local] = __half_as_ushort(__float2half(w));
}

// ---------------- FUSE2: GEMM#1 (gsplit blocks) + degree reduce/scan (gN blocks) ----------------
// GEMM#1: h0 = relu(features @ w_in + b_in), fp32 A, KC=8, NT=4, col-split.

constexpr int GSPLIT = (NN + 31) / 32;   // 1563
constexpr int GN = (NN + 255) / 256;     // 196

__global__ __launch_bounds__(256) void fuse2_kernel(
    const float* __restrict__ features, const ushort* __restrict__ Bf,
    const float* __restrict__ bias, __half* __restrict__ outh,
    const unsigned* __restrict__ pd, const unsigned* __restrict__ ps,
    int* __restrict__ row_ptr, int* __restrict__ bsum,
    float* __restrict__ inv_mean, float* __restrict__ inv_in,
    float* __restrict__ inv_out) {
  __shared__ int sh[256];
  if (blockIdx.x >= GSPLIT) {
    // deg_scan branch
    int n = (blockIdx.x - GSPLIT) * 256 + threadIdx.x;
    unsigned di = 0, dz = 0;
    if (n < NN) {
      #pragma unroll 8
      for (int sl = 0; sl < NSL; ++sl) {
        di += pd[(long)sl * NN + n];
        dz += ps[(long)sl * NN + n];
      }
      float fdi = fmaxf((float)di, 1.f), fdz = fmaxf((float)dz, 1.f);
      inv_mean[n] = 1.f / fdi;
      inv_in[n]  = rsqrtf(fdi);
      inv_out[n] = rsqrtf(fdz);
    }
    int v = (n < NN) ? (int)di : 0;
    sh[threadIdx.x] = v;
    __syncthreads();
    #pragma unroll
    for (int off = 1; off < 256; off <<= 1) {
      int tv = (threadIdx.x >= off) ? sh[threadIdx.x - off] : 0;
      __syncthreads();
      sh[threadIdx.x] += tv;
      __syncthreads();
    }
    if (n < NN) row_ptr[n] = sh[threadIdx.x] - v;
    if (threadIdx.x == 255) bsum[blockIdx.x - GSPLIT] = sh[255];
    return;
  }
  // GEMM#1 branch (KC=8, NT=4, NTP=8, fp32 A, col-split)
  const int t = threadIdx.x;
  const int lane = t & 63;
  const int wid = t >> 6;
  const int rowbase = blockIdx.x * 32 + (wid >> 1) * 16;
  const int colbase = (wid & 1) * 64;
  const int arow = rowbase + (lane & 15);
  const int kgrp = (lane >> 4) * 8;
  const bool rowok = arow < NN;

  f32x4 acc[4];
  #pragma unroll
  for (int n = 0; n < 4; ++n) acc[n] = (f32x4){0.f, 0.f, 0.f, 0.f};
  const f32x4 z4 = {0.f, 0.f, 0.f, 0.f};
  f32x4 fra[8], frb[8];
  #pragma unroll
  for (int kc = 0; kc < 8; ++kc) {
    const float* p = features + (long)arow * INF_ + kc * 32 + kgrp;
    fra[kc] = rowok ? *(const f32x4*)p : z4;
    frb[kc] = rowok ? *(const f32x4*)(p + 4) : z4;
  }
  #pragma unroll
  for (int kc = 0; kc < 8; ++kc) {
    f16x8 av;
    #pragma unroll
    for (int j = 0; j < 4; ++j) {
      av[j]     = (_Float16)fra[kc][j];
      av[j + 4] = (_Float16)frb[kc][j];
    }
    const ushort* bp = Bf + ((long)kc * 8 * 64 + lane) * 8 + (long)colbase * 32;
    #pragma unroll
    for (int nt = 0; nt < 4; ++nt) {
      union { uint4 u; f16x8 v; } bv;
      bv.u = *(const uint4*)(bp + (long)nt * 512);
      acc[nt] = __builtin_amdgcn_mfma_f32_16x16x32_f16(av, bv.v, acc[nt], 0, 0, 0);
    }
  }
  const int colg = lane & 15;
  const int rsub = (lane >> 4) * 4;
  #pragma unroll
  for (int nt = 0; nt < 4; ++nt) {
    int c = colbase + nt * 16 + colg;
    float bb = bias[c];
    #pragma unroll
    for (int i = 0; i < 4; ++i) {
      int r = rowbase + rsub + i;
      if (r >= NN) continue;
      long sidx = ((long)(c >> 5) * NN + r) * 32 + (c & 31);
      outh[sidx] = __float2half(fmaxf(acc[nt][i] + bb, 0.f));
    }
  }
}

// ---------------- cursor_init (absorbs the bsum scan) ----------------

__global__ __launch_bounds__(256) void cursor_init2_kernel(
    const int* __restrict__ row_ptr, const int* __restrict__ bsum,
    const unsigned* __restrict__ pd, unsigned* __restrict__ cur0,
    const float* __restrict__ inv_mean, const float* __restrict__ inv_in,
    int4* __restrict__ nodeinfo) {
  __shared__ int sh[256];
  // block-prefix over bsum[0..blockIdx.x)
  int part = 0;
  for (int j = threadIdx.x; j < (int)blockIdx.x; j += 256) part += bsum[j];
  sh[threadIdx.x] = part;
  __syncthreads();
  #pragma unroll
  for (int off = 128; off >= 1; off >>= 1) {
    if (threadIdx.x < off) sh[threadIdx.x] += sh[threadIdx.x + off];
    __syncthreads();
  }
  const int boff = sh[0];
  int n = blockIdx.x * 256 + threadIdx.x;
  if (n >= NN) return;
  unsigned start = (unsigned)(row_ptr[n] + boff);
  unsigned run = start;
  #pragma unroll 8
  for (int sl = 0; sl < NSL; ++sl) {
    cur0[(long)sl * NN + n] = run;
    run += pd[(long)sl * NN + n];
  }
  nodeinfo[n] = make_int4((int)start, (int)run,
                          __float_as_int(inv_mean[n]), __float_as_int(inv_in[n]));
}

__global__ __launch_bounds__(256) void fill_partial_kernel(
    const int4* __restrict__ dst4, const int4* __restrict__ src4,
    const unsigned* __restrict__ cur0, int* __restrict__ col) {
  __shared__ unsigned cur[CHK];
  const int chunk = blockIdx.x & 3;
  const int sl = blockIdx.x >> 2;
  const int lo = chunk * CHK;
  const unsigned* c0 = cur0 + (long)sl * NN + lo;
  for (int i = threadIdx.x; i < CHK; i += 256) cur[i] = c0[i];
  __syncthreads();
  const int base4 = sl * (ESL / 4);
  for (int i = threadIdx.x; i < ESL / 4; i += 256) {
    int4 d = dst4[base4 + i];
    int4 s = src4[base4 + i];
    int a;
    a = d.x - lo; if ((unsigned)a < (unsigned)CHK) col[atomicAdd(&cur[a], 1u)] = s.x;
    a = d.y - lo; if ((unsigned)a < (unsigned)CHK) col[atomicAdd(&cur[a], 1u)] = s.y;
    a = d.z - lo; if ((unsigned)a < (unsigned)CHK) col[atomicAdd(&cur[a], 1u)] = s.z;
    a = d.w - lo; if ((unsigned)a < (unsigned)CHK) col[atomicAdd(&cur[a], 1u)] = s.w;
  }
}

// ---------------- SpMM: 4 slices x 32 feats (L2-resident), 2 nodes per wave ----------------

__global__ __launch_bounds__(256) void spmm32p_kernel(
    const int4* __restrict__ nodeinfo, const int* __restrict__ cols,
    const __half* __restrict__ xs, int useW,
    __half* __restrict__ outh) {
  const int t = threadIdx.x;
  const int lane = t & 63;
  const int wv = t >> 6;
  const int b = blockIdx.x;
  const int xcd = b & 7;
  const int slice = xcd >> 1;
  const int sub = xcd & 1;
  const int npair = lane >> 5;
  const int node = (b >> 3) * 16 + sub * 8 + wv * 2 + npair;  // NN = 3125*16
  const int e8 = (lane >> 2) & 7;
  const int q4 = lane & 3;
  const __half* xb = xs + (long)slice * NN * 32 + q4 * 8;
  int4 ni = nodeinfo[node];
  const int e0 = ni.x, end = ni.y;
  const float d = __int_as_float(useW ? ni.w : ni.z);
  const int deg = end - e0;
  int dmax = deg > 0 ? deg : 0;
  {
    int od = __shfl_xor(dmax, 32, 64);
    dmax = dmax > od ? dmax : od;
  }
  const int kmax = (dmax + 7) >> 3;
  const int ecl = (end - 1) > 0 ? (end - 1) : 0;
  const __half2 z2 = __float2half2_rn(0.f);
  __half2 A0 = z2, A1 = z2, A2 = z2, A3 = z2;
  __half2 B0 = z2, B1 = z2, B2 = z2, B3 = z2;
  int k = 0;
  for (; k + 2 <= kmax; k += 2) {
    int ee0 = e0 + k * 8 + e8;
    int ee1 = ee0 + 8;
    bool m0 = ee0 < end, m1 = ee1 < end;
    int s0 = cols[m0 ? ee0 : ecl];
    int s1 = cols[m1 ? ee1 : ecl];
    f32x4 v0 = *(const f32x4*)(xb + (unsigned)s0 * 32u);
    f32x4 v1 = *(const f32x4*)(xb + (unsigned)s1 * 32u);
    const __half2* h0 = (const __half2*)&v0;
    const __half2* h1 = (const __half2*)&v1;
    A0 = __hadd2(A0, m0 ? h0[0] : z2); A1 = __hadd2(A1, m0 ? h0[1] : z2);
    A2 = __hadd2(A2, m0 ? h0[2] : z2); A3 = __hadd2(A3, m0 ? h0[3] : z2);
    B0 = __hadd2(B0, m1 ? h1[0] : z2); B1 = __hadd2(B1, m1 ? h1[1] : z2);
    B2 = __hadd2(B2, m1 ? h1[2] : z2); B3 = __hadd2(B3, m1 ? h1[3] : z2);
  }
  if (k < kmax) {
    int ee = e0 + k * 8 + e8;
    bool m = ee < end;
    int s = cols[m ? ee : ecl];
    f32x4 v = *(const f32x4*)(xb + (unsigned)s * 32u);
    const __half2* h = (const __half2*)&v;
    A0 = __hadd2(A0, m ? h[0] : z2); A1 = __hadd2(A1, m ? h[1] : z2);
    A2 = __hadd2(A2, m ? h[2] : z2); A3 = __hadd2(A3, m ? h[3] : z2);
  }
  A0 = __hadd2(A0, B0); A1 = __hadd2(A1, B1);
  A2 = __hadd2(A2, B2); A3 = __hadd2(A3, B3);
  float2 p0 = __half22float2(A0), p1 = __half22float2(A1);
  float2 p2 = __half22float2(A2), p3 = __half22float2(A3);
  float f0 = p0.x, f1 = p0.y, f2 = p1.x, f3 = p1.y;
  float f4 = p2.x, f5 = p2.y, f6 = p3.x, f7 = p3.y;
  {
    bool hi = (lane & 4) != 0;
    float t0 = hi ? f0 : f4, t1 = hi ? f1 : f5, t2 = hi ? f2 : f6, t3 = hi ? f3 : f7;
    t0 = __shfl_xor(t0, 4, 64); t1 = __shfl_xor(t1, 4, 64);
    t2 = __shfl_xor(t2, 4, 64); t3 = __shfl_xor(t3, 4, 64);
    f0 = (hi ? f4 : f0) + t0; f1 = (hi ? f5 : f1) + t1;
    f2 = (hi ? f6 : f2) + t2; f3 = (hi ? f7 : f3) + t3;
  }
  {
    bool hi = (lane & 8) != 0;
    float t0 = hi ? f0 : f2, t1 = hi ? f1 : f3;
    t0 = __shfl_xor(t0, 8, 64); t1 = __shfl_xor(t1, 8, 64);
    f0 = (hi ? f2 : f0) + t0; f1 = (hi ? f3 : f1) + t1;
  }
  float fin;
  {
    bool hi = (lane & 16) != 0;
    float t0 = hi ? f0 : f1;
    t0 = __shfl_xor(t0, 16, 64);
    fin = (hi ? f1 : f0) + t0;
  }
  int foff = q4 * 8 + ((lane >> 2) & 1) * 4 + ((lane >> 3) & 1) * 2 + ((lane >> 4) & 1);
  outh[((long)slice * NN + node) * 32 + foff] = __float2half(fin * d);
}

// ---------------- fp16 MFMA GEMM: out = epi( [A1|A2] @ W + bias ) ----------------

template<int KC, int NT, int NTP, int EPI, int H16, int ASRC, int OUTM, int COLSPLIT, int BHOIST>
__global__ __launch_bounds__(256) void mgemm_kernel(
    const void* __restrict__ A1, int lda1,
    const void* __restrict__ A2,
    const ushort* __restrict__ Bf,
    const float* __restrict__ bias,
    const float* __restrict__ g, const float* __restrict__ be,
    const float* __restrict__ mu, const float* __restrict__ va,
    const __half* __restrict__ resp,
    float* __restrict__ outf, __half* __restrict__ outh, int ldc, int Ncols,
    __half* __restrict__ x16, const float* __restrict__ rowscale) {
  const int t = threadIdx.x;
  const int lane = t & 63;
  const int wid = t >> 6;
  const int rowbase = COLSPLIT ? (blockIdx.x * 32 + (wid >> 1) * 16)
                               : (blockIdx.x * 64 + wid * 16);
  const int colbase = COLSPLIT ? ((wid & 1) * NT * 16) : 0;
  const int arow = rowbase + (lane & 15);
  const int kgrp = (lane >> 4) * 8;
  const bool rowok = arow < NN;

  f32x4 acc[NT];
  #pragma unroll
  for (int n = 0; n < NT; ++n) acc[n] = (f32x4){0.f, 0.f, 0.f, 0.f};

  const f32x4 z4 = {0.f, 0.f, 0.f, 0.f};
  f32x4 fra[ASRC == 0 ? KC : 1], frb[ASRC == 0 ? KC : 1];
  uint4 areg[ASRC == 1 ? KC : 1];
  if (ASRC == 0) {
    #pragma unroll
    for (int kc = 0; kc < KC; ++kc) {
      const float* p = (const float*)A1 + (long)arow * lda1 + kc * 32 + kgrp;
      fra[kc] = rowok ? *(const f32x4*)p : z4;
      frb[kc] = rowok ? *(const f32x4*)(p + 4) : z4;
    }
  } else {
    #pragma unroll
    for (int kc = 0; kc < KC; ++kc) {
      const bool second = (KC == 8) && (kc >= 4);
      const ushort* At = (const ushort*)(second ? A2 : A1);
      int k0 = (second ? (kc - 4) : kc) * 32 + kgrp;
      const ushort* p = At + ((long)(k0 >> 5) * NN + arow) * 32 + (k0 & 31);
      areg[kc] = rowok ? *(const uint4*)p : make_uint4(0, 0, 0, 0);
    }
  }

  if (BHOIST) {
    uint4 breg[KC * NT];
    #pragma unroll
    for (int kc = 0; kc < KC; ++kc) {
      const ushort* bp = Bf + ((long)kc * NTP * 64 + lane) * 8 + (long)colbase * 32;
      #pragma unroll
      for (int nt = 0; nt < NT; ++nt)
        breg[kc * NT + nt] = *(const uint4*)(bp + (long)nt * 512);
    }
    #pragma unroll
    for (int kc = 0; kc < KC; ++kc) {
      union { uint4 u; f16x8 v; } cv;
      cv.u = areg[kc];
      #pragma unroll
      for (int nt = 0; nt < NT; ++nt) {
        union { uint4 u; f16x8 v; } bv;
        bv.u = breg[kc * NT + nt];
        acc[nt] = __builtin_amdgcn_mfma_f32_16x16x32_f16(cv.v, bv.v, acc[nt], 0, 0, 0);
      }
    }
  } else {
    #pragma unroll
    for (int kc = 0; kc < KC; ++kc) {
      f16x8 av;
      if (ASRC == 0) {
        #pragma unroll
        for (int j = 0; j < 4; ++j) {
          av[j]     = (_Float16)fra[kc][j];
          av[j + 4] = (_Float16)frb[kc][j];
        }
      } else {
        union { uint4 u; f16x8 v; } cv;
        cv.u = areg[kc];
        av = cv.v;
      }
      const ushort* bp = Bf + ((long)kc * NTP * 64 + lane) * 8 + (long)colbase * 32;
      #pragma unroll
      for (int nt = 0; nt < NT; ++nt) {
        union { uint4 u; f16x8 v; } bv;
        bv.u = *(const uint4*)(bp + (long)nt * 512);
        acc[nt] = __builtin_amdgcn_mfma_f32_16x16x32_f16(av, bv.v, acc[nt], 0, 0, 0);
      }
    }
  }

  const int colg = lane & 15;
  const int rsub = (lane >> 4) * 4;

  if (EPI == EPI_ATTN) {
    float part0 = 0.f, part1 = 0.f, part2 = 0.f, part3 = 0.f;
    #pragma unroll
    for (int nt = 0; nt < NT; ++nt) {
      int c = nt * 16 + colg;
      float w2v = g[c];
      float bb = bias[c];
      part0 = fmaf(fmaxf(acc[nt][0] + bb, 0.f), w2v, part0);
      part1 = fmaf(fmaxf(acc[nt][1] + bb, 0.f), w2v, part1);
      part2 = fmaf(fmaxf(acc[nt][2] + bb, 0.f), w2v, part2);
      part3 = fmaf(fmaxf(acc[nt][3] + bb, 0.f), w2v, part3);
    }
    #pragma unroll
    for (int m = 1; m <= 8; m <<= 1) {
      part0 += __shfl_xor(part0, m, 64);
      part1 += __shfl_xor(part1, m, 64);
      part2 += __shfl_xor(part2, m, 64);
      part3 += __shfl_xor(part3, m, 64);
    }
    const float b2v = be[0];
    float s0 = 1.f / (1.f + __expf(-(part0 + b2v)));
    float s1 = 1.f / (1.f + __expf(-(part1 + b2v)));
    float s2 = 1.f / (1.f + __expf(-(part2 + b2v)));
    float s3 = 1.f / (1.f + __expf(-(part3 + b2v)));
    const __half* h0t = (const __half*)A1;
    const __half* aggt = (const __half*)A2;
    #pragma unroll
    for (int nt = 0; nt < NT; ++nt) {
      int c = nt * 16 + colg;
      #pragma unroll
      for (int i = 0; i < 4; ++i) {
        int r = rowbase + rsub + i;
        if (r >= NN) continue;
        long sidx = ((long)(c >> 5) * NN + r) * 32 + (c & 31);
        float sv = (i == 0) ? s0 : ((i == 1) ? s1 : ((i == 2) ? s2 : s3));
        float h = __half2float(h0t[sidx]) + __half2float(aggt[sidx]) * sv;
        x16[sidx] = __float2half(h * rowscale[r]);
      }
    }
    return;
  }

  #pragma unroll
  for (int nt = 0; nt < NT; ++nt) {
    int c = colbase + nt * 16 + colg;
    if (c >= Ncols) continue;
    float bb = bias ? bias[c] : 0.f;
    float scale = 1.f, shift = 0.f;
    if (EPI == EPI_BN || EPI == EPI_BN_RES) {
      scale = g[c] * rsqrtf(va[c] + EPSV);
      shift = be[c] - mu[c] * scale;
    }
    #pragma unroll
    for (int i = 0; i < 4; ++i) {
      int r = rowbase + rsub + i;
      if (r >= NN) continue;
      long sidx = ((long)(c >> 5) * NN + r) * 32 + (c & 31);
      float v = acc[nt][i] + bb;
      if (EPI == EPI_RELU) {
        v = fmaxf(v, 0.f);
      } else if (EPI == EPI_BN || EPI == EPI_BN_RES) {
        v = fmaxf(v * scale + shift, 0.f);
        if (EPI == EPI_BN_RES) v += __half2float(resp[sidx]);
      }
      if (OUTM == 0) {
        outf[(long)r * ldc + c] = v;
      } else {
        outh[sidx] = __float2half(v);
        if (H16 == H16_SCALED) x16[sidx] = __float2half(v * rowscale[r]);
      }
    }
  }
}

// ---------------- launch ----------------

extern "C" void kernel_launch(void* const* d_in, const int* in_sizes, int n_in,
                              void* d_out, int out_size, void* d_ws, size_t ws_size,
                              hipStream_t stream) {
  const float* features = (const float*)d_in[0];
  const int*   src      = (const int*)d_in[1];
  const int*   dst      = (const int*)d_in[2];
  const float* w_in     = (const float*)d_in[3];
  const float* b_in     = (const float*)d_in[4];
  const float* gc_w     = (const float*)d_in[5];
  const float* gc_b     = (const float*)d_in[6];
  const float* bn_gamma = (const float*)d_in[7];
  const float* bn_beta  = (const float*)d_in[8];
  const float* bn_mean  = (const float*)d_in[9];
  const float* bn_var   = (const float*)d_in[10];
  const float* attn_w1  = (const float*)d_in[11];
  const float* attn_b1  = (const float*)d_in[12];
  const float* attn_w2  = (const float*)d_in[13];
  const float* attn_b2  = (const float*)d_in[14];
  const float* agg_w    = (const float*)d_in[15];
  const float* agg_b    = (const float*)d_in[16];
  const float* out_w    = (const float*)d_in[17];
  const float* out_b    = (const float*)d_in[18];
  float* out = (float*)d_out;

  float* fbase = (float*)d_ws;
  float* inv_mean = fbase;
  float* inv_in   = inv_mean + NN;
  float* inv_out  = inv_in + NN;
  int* row_ptr = (int*)(inv_out + NN);   // NN+16
  int* bsum    = row_ptr + NN + 16;      // 256
  int* col     = bsum + 256;             // EE
  int4* nodeinfo = (int4*)(col + EE);    // NN

  // packed fp16 weights (contiguous: win, agg, at1, gc0..2, ow)
  ushort* pk = (ushort*)(nodeinfo + NN);
  ushort* win_f = pk;
  ushort* agg_f = pk + SZ256;
  ushort* at1_f = pk + 2 * SZ256;
  ushort* gcf0  = pk + 3 * SZ256;
  ushort* gcf1  = gcf0 + SZ128;
  ushort* gcf2  = gcf1 + SZ128;
  ushort* ow_f  = gcf2 + SZ128;

  // fp16 activation pools, sliced [4][NN][32]
  __half* T0 = (__half*)(ow_f + SZOUT);  // h0 -> rst1
  __half* T1 = T0 + NH;                  // neigh / spmm rst
  __half* T2 = T1 + NH;                  // agg -> rst0 -> rst2
  __half* X16 = T2 + NH;                 // scaled gather table

  // preprocessing scratch aliased into T1/T2 (dead until spmm1/GEMM#2; T0 is NOT
  // used because FUSE2 writes h0 into T0 while deg_scan still reads pd/ps)
  unsigned* pd   = (unsigned*)T1;              // NSL*NN (12.8MB = T1)
  unsigned* ps   = pd + (long)NSL * NN;        // spills into T2's first half?  no:
  // NSL*NN*4B = 6.4MB each; T1 holds 12.8MB -> pd+ps fit exactly in T1.
  unsigned* cur0 = (unsigned*)T2;              // 6.4MB in T2 (T2 first written by GEMM#2)

  dim3 b256(256);
  const int gblocks = (NN + 63) / 64;     // 782 (NT=8 blocks)
  const int gsplit  = GSPLIT;             // 1563
  const int gspmm = (NN / 16) * 8;        // 25000
  const int gpre = NSL * 4;

  // FUSE1: edge histograms + weight prepack (independent)
  fuse1_kernel<<<256 + PKB, b256, 0, stream>>>(
      (const int4*)dst, (const int4*)src, pd, ps,
      w_in, agg_w, attn_w1, gc_w, out_w, pk);

  // FUSE2: GEMM#1 (h0 -> T0) + degree reduce/scan (independent of each other)
  fuse2_kernel<<<GSPLIT + GN, b256, 0, stream>>>(
      features, win_f, b_in, T0,
      pd, ps, row_ptr, bsum, inv_mean, inv_in, inv_out);

  // cursor init (absorbs bsum scan) -> cur0 + nodeinfo
  cursor_init2_kernel<<<GN, b256, 0, stream>>>(
      row_ptr, bsum, pd, cur0, inv_mean, inv_in, nodeinfo);
  // CSR fill
  fill_partial_kernel<<<gpre, b256, 0, stream>>>((const int4*)dst, (const int4*)src, cur0, col);

  // spmm1: neigh = mean-agg(h0) -> T1 (pd/ps dead now)
  spmm32p_kernel<<<gspmm, b256, 0, stream>>>(nodeinfo, col, T0, 0, T1);
  // #2: agg = relu([h0|neigh] @ agg_w + agg_b) -> T2 (cur0 dead now)
  mgemm_kernel<8, 4, 8, EPI_RELU, H16_NONE, 1, 1, 1, 0><<<gsplit, b256, 0, stream>>>(
      T0, 0, T1, agg_f, agg_b,
      nullptr, nullptr, nullptr, nullptr, nullptr,
      nullptr, T2, HF, HF, nullptr, nullptr);
  // #3 (fused attn): needs full row per wave -> NT=8, no col-split
  mgemm_kernel<8, 8, 8, EPI_ATTN, H16_NONE, 1, 1, 0, 0><<<gblocks, b256, 0, stream>>>(
      T0, 0, T2, at1_f, attn_b1,
      attn_w2, attn_b2, nullptr, nullptr, nullptr,
      nullptr, nullptr, HF, HF, X16, inv_out);

  // layer 0: spmm(X16) -> T1 ; rst0 = relu(BN(T1@gc0+b0)) -> T2 (+X16)
  spmm32p_kernel<<<gspmm, b256, 0, stream>>>(nodeinfo, col, X16, 1, T1);
  mgemm_kernel<4, 4, 8, EPI_BN, H16_SCALED, 1, 1, 1, 1><<<gsplit, b256, 0, stream>>>(
      T1, 0, nullptr, gcf0, gc_b,
      bn_gamma, bn_beta, bn_mean, bn_var, nullptr,
      nullptr, T2, HF, HF, X16, inv_out);
  // layer 1
  spmm32p_kernel<<<gspmm, b256, 0, stream>>>(nodeinfo, col, X16, 1, T1);
  mgemm_kernel<4, 4, 8, EPI_BN_RES, H16_SCALED, 1, 1, 1, 1><<<gsplit, b256, 0, stream>>>(
      T1, 0, nullptr, gcf1, gc_b + HF,
      bn_gamma + HF, bn_beta + HF, bn_mean + HF, bn_var + HF, T2,
      nullptr, T0, HF, HF, X16, inv_out);
  // layer 2
  spmm32p_kernel<<<gspmm, b256, 0, stream>>>(nodeinfo, col, X16, 1, T1);
  mgemm_kernel<4, 4, 8, EPI_BN_RES, H16_NONE, 1, 1, 1, 1><<<gsplit, b256, 0, stream>>>(
      T1, 0, nullptr, gcf2, gc_b + 2 * HF,
      bn_gamma + 2 * HF, bn_beta + 2 * HF, bn_mean + 2 * HF, bn_var + 2 * HF, T0,
      nullptr, T2, HF, HF, nullptr, nullptr);

  // out = rst2 @ out_w + out_b -> d_out (fp32; NT=4 covers 64 >= 50 cols; B-hoist)
  mgemm_kernel<4, 4, 4, EPI_NONE, H16_NONE, 1, 0, 0, 1><<<gblocks, b256, 0, stream>>>(
      T2, 0, nullptr, ow_f, out_b,
      nullptr, nullptr, nullptr, nullptr, nullptr,
      out, nullptr, CC, CC, nullptr, nullptr);
}

// Round 23
// 300.620 us; speedup vs baseline: 1.1809x; 1.0327x over previous
//
#include <hip/hip_runtime.h>
#include <hip/hip_fp16.h>
#include <math.h>

constexpr int NN  = 50000;   // nodes
constexpr int EE  = 800000;  // edges
constexpr int INF_ = 256;    // input feat
constexpr int HF  = 128;     // hidden
constexpr int CC  = 50;      // classes
constexpr long NH = (long)NN * HF;
constexpr int NSL = 32;          // edge slices (preprocessing)
constexpr int ESL = EE / NSL;    // 25000 edges per slice
constexpr int CHK = 12500;       // nodes per chunk (4 chunks), 50KB LDS
#define EPSV 1e-5f

enum { EPI_RELU = 0, EPI_NONE = 1, EPI_BN = 2, EPI_BN_RES = 3, EPI_ATTN = 4 };
enum { H16_NONE = 0, H16_SCALED = 2 };

typedef __attribute__((ext_vector_type(4))) float f32x4;
typedef __attribute__((ext_vector_type(8))) _Float16 f16x8;

constexpr int SZ256 = 8 * 8 * 512;   // K=256, NTP=8
constexpr int SZ128 = 4 * 8 * 512;   // K=128, NTP=8
constexpr int SZOUT = 4 * 4 * 512;   // K=128, NTP=4
constexpr int PK_TOTAL = 3 * SZ256 + 3 * SZ128 + SZOUT;
constexpr int PKB = (PK_TOTAL + 255) / 256;   // prepack blocks (608)

// ---------------- FUSE1: edge histograms (256 blocks) + weight prepack (PKB blocks) ----------------

__global__ __launch_bounds__(256) void fuse1_kernel(
    const int4* __restrict__ dst4, const int4* __restrict__ src4,
    unsigned* __restrict__ pd, unsigned* __restrict__ ps,
    const float* __restrict__ w_in, const float* __restrict__ agg_w,
    const float* __restrict__ at1, const float* __restrict__ gc_w,
    const float* __restrict__ out_w, ushort* __restrict__ outbase) {
  __shared__ unsigned cnt[CHK];
  if (blockIdx.x < 256) {
    int bb = blockIdx.x;
    const int which = bb >> 7;
    bb &= 127;
    const int4* keys4 = which ? src4 : dst4;
    unsigned* partials = which ? ps : pd;
    const int chunk = bb & 3;
    const int sl = bb >> 2;
    for (int i = threadIdx.x; i < CHK; i += 256) cnt[i] = 0;
    __syncthreads();
    const int base4 = sl * (ESL / 4);
    const int lo = chunk * CHK;
    for (int i = threadIdx.x; i < ESL / 4; i += 256) {
      int4 k = keys4[base4 + i];
      int a;
      a = k.x - lo; if ((unsigned)a < (unsigned)CHK) atomicAdd(&cnt[a], 1u);
      a = k.y - lo; if ((unsigned)a < (unsigned)CHK) atomicAdd(&cnt[a], 1u);
      a = k.z - lo; if ((unsigned)a < (unsigned)CHK) atomicAdd(&cnt[a], 1u);
      a = k.w - lo; if ((unsigned)a < (unsigned)CHK) atomicAdd(&cnt[a], 1u);
    }
    __syncthreads();
    unsigned* p = partials + (long)sl * NN + lo;
    for (int i = threadIdx.x; i < CHK; i += 256) p[i] = cnt[i];
    return;
  }
  // prepack branch
  int idx = (blockIdx.x - 256) * 256 + threadIdx.x;
  if (idx >= PK_TOTAL) return;
  const float* W; int N, ldw, NTpad, local; ushort* outp;
  if (idx < 3 * SZ256) {
    int s = idx / SZ256; local = idx - s * SZ256;
    W = (s == 0) ? w_in : ((s == 1) ? agg_w : at1);
    N = HF; ldw = HF; NTpad = 8;
    outp = outbase + s * SZ256;
  } else if (idx < 3 * SZ256 + 3 * SZ128) {
    int r = idx - 3 * SZ256; int s = r / SZ128; local = r - s * SZ128;
    W = gc_w + (long)s * HF * HF; N = HF; ldw = HF; NTpad = 8;
    outp = outbase + 3 * SZ256 + s * SZ128;
  } else {
    local = idx - 3 * SZ256 - 3 * SZ128;
    W = out_w; N = CC; ldw = CC; NTpad = 4;
    outp = outbase + 3 * SZ256 + 3 * SZ128;
  }
  int j    = local & 7;
  int lane = (local >> 3) & 63;
  int rest = local >> 9;
  int nt = rest % NTpad;
  int kc = rest / NTpad;
  int k = kc * 32 + (lane >> 4) * 8 + j;
  int n = nt * 16 + (lane & 15);
  float w = (n < N) ? W[(long)k * ldw + n] : 0.f;
  outp[local] = __half_as_ushort(__float2half(w));
}

// ---------------- FUSE2: GEMM#1 (gsplit blocks) + degree reduce/scan (gN blocks) ----------------

constexpr int GSPLIT = (NN + 31) / 32;   // 1563
constexpr int GN = (NN + 255) / 256;     // 196

__global__ __launch_bounds__(256) void fuse2_kernel(
    const float* __restrict__ features, const ushort* __restrict__ Bf,
    const float* __restrict__ bias, __half* __restrict__ outh,
    const unsigned* __restrict__ pd, const unsigned* __restrict__ ps,
    int* __restrict__ row_ptr, int* __restrict__ bsum,
    float* __restrict__ inv_mean, float* __restrict__ inv_in,
    float* __restrict__ inv_out) {
  __shared__ int sh[256];
  if (blockIdx.x >= GSPLIT) {
    int n = (blockIdx.x - GSPLIT) * 256 + threadIdx.x;
    unsigned di = 0, dz = 0;
    if (n < NN) {
      #pragma unroll 8
      for (int sl = 0; sl < NSL; ++sl) {
        di += pd[(long)sl * NN + n];
        dz += ps[(long)sl * NN + n];
      }
      float fdi = fmaxf((float)di, 1.f), fdz = fmaxf((float)dz, 1.f);
      inv_mean[n] = 1.f / fdi;
      inv_in[n]  = rsqrtf(fdi);
      inv_out[n] = rsqrtf(fdz);
    }
    int v = (n < NN) ? (int)di : 0;
    sh[threadIdx.x] = v;
    __syncthreads();
    #pragma unroll
    for (int off = 1; off < 256; off <<= 1) {
      int tv = (threadIdx.x >= off) ? sh[threadIdx.x - off] : 0;
      __syncthreads();
      sh[threadIdx.x] += tv;
      __syncthreads();
    }
    if (n < NN) row_ptr[n] = sh[threadIdx.x] - v;
    if (threadIdx.x == 255) bsum[blockIdx.x - GSPLIT] = sh[255];
    return;
  }
  // GEMM#1 branch (KC=8, NT=4, NTP=8, fp32 A, col-split)
  const int t = threadIdx.x;
  const int lane = t & 63;
  const int wid = t >> 6;
  const int rowbase = blockIdx.x * 32 + (wid >> 1) * 16;
  const int colbase = (wid & 1) * 64;
  const int arow = rowbase + (lane & 15);
  const int kgrp = (lane >> 4) * 8;
  const bool rowok = arow < NN;

  f32x4 acc[4];
  #pragma unroll
  for (int n = 0; n < 4; ++n) acc[n] = (f32x4){0.f, 0.f, 0.f, 0.f};
  const f32x4 z4 = {0.f, 0.f, 0.f, 0.f};
  f32x4 fra[8], frb[8];
  #pragma unroll
  for (int kc = 0; kc < 8; ++kc) {
    const float* p = features + (long)arow * INF_ + kc * 32 + kgrp;
    fra[kc] = rowok ? *(const f32x4*)p : z4;
    frb[kc] = rowok ? *(const f32x4*)(p + 4) : z4;
  }
  #pragma unroll
  for (int kc = 0; kc < 8; ++kc) {
    f16x8 av;
    #pragma unroll
    for (int j = 0; j < 4; ++j) {
      av[j]     = (_Float16)fra[kc][j];
      av[j + 4] = (_Float16)frb[kc][j];
    }
    const ushort* bp = Bf + ((long)kc * 8 * 64 + lane) * 8 + (long)colbase * 32;
    #pragma unroll
    for (int nt = 0; nt < 4; ++nt) {
      union { uint4 u; f16x8 v; } bv;
      bv.u = *(const uint4*)(bp + (long)nt * 512);
      acc[nt] = __builtin_amdgcn_mfma_f32_16x16x32_f16(av, bv.v, acc[nt], 0, 0, 0);
    }
  }
  const int colg = lane & 15;
  const int rsub = (lane >> 4) * 4;
  #pragma unroll
  for (int nt = 0; nt < 4; ++nt) {
    int c = colbase + nt * 16 + colg;
    float bb = bias[c];
    #pragma unroll
    for (int i = 0; i < 4; ++i) {
      int r = rowbase + rsub + i;
      if (r >= NN) continue;
      long sidx = ((long)(c >> 5) * NN + r) * 32 + (c & 31);
      outh[sidx] = __float2half(fmaxf(acc[nt][i] + bb, 0.f));
    }
  }
}

// ---------------- cursor_init (absorbs the bsum scan) ----------------

__global__ __launch_bounds__(256) void cursor_init2_kernel(
    const int* __restrict__ row_ptr, const int* __restrict__ bsum,
    const unsigned* __restrict__ pd, unsigned* __restrict__ cur0,
    const float* __restrict__ inv_mean, const float* __restrict__ inv_in,
    int4* __restrict__ nodeinfo) {
  __shared__ int sh[256];
  int part = 0;
  for (int j = threadIdx.x; j < (int)blockIdx.x; j += 256) part += bsum[j];
  sh[threadIdx.x] = part;
  __syncthreads();
  #pragma unroll
  for (int off = 128; off >= 1; off >>= 1) {
    if (threadIdx.x < off) sh[threadIdx.x] += sh[threadIdx.x + off];
    __syncthreads();
  }
  const int boff = sh[0];
  int n = blockIdx.x * 256 + threadIdx.x;
  if (n >= NN) return;
  unsigned start = (unsigned)(row_ptr[n] + boff);
  unsigned run = start;
  #pragma unroll 8
  for (int sl = 0; sl < NSL; ++sl) {
    cur0[(long)sl * NN + n] = run;
    run += pd[(long)sl * NN + n];
  }
  nodeinfo[n] = make_int4((int)start, (int)run,
                          __float_as_int(inv_mean[n]), __float_as_int(inv_in[n]));
}

__global__ __launch_bounds__(256) void fill_partial_kernel(
    const int4* __restrict__ dst4, const int4* __restrict__ src4,
    const unsigned* __restrict__ cur0, int* __restrict__ col) {
  __shared__ unsigned cur[CHK];
  const int chunk = blockIdx.x & 3;
  const int sl = blockIdx.x >> 2;
  const int lo = chunk * CHK;
  const unsigned* c0 = cur0 + (long)sl * NN + lo;
  for (int i = threadIdx.x; i < CHK; i += 256) cur[i] = c0[i];
  __syncthreads();
  const int base4 = sl * (ESL / 4);
  for (int i = threadIdx.x; i < ESL / 4; i += 256) {
    int4 d = dst4[base4 + i];
    int4 s = src4[base4 + i];
    int a;
    a = d.x - lo; if ((unsigned)a < (unsigned)CHK) col[atomicAdd(&cur[a], 1u)] = s.x;
    a = d.y - lo; if ((unsigned)a < (unsigned)CHK) col[atomicAdd(&cur[a], 1u)] = s.y;
    a = d.z - lo; if ((unsigned)a < (unsigned)CHK) col[atomicAdd(&cur[a], 1u)] = s.z;
    a = d.w - lo; if ((unsigned)a < (unsigned)CHK) col[atomicAdd(&cur[a], 1u)] = s.w;
  }
}

// ---------------- SpMM: 4 slices x 32 feats (L2-resident), 2 nodes per wave ----------------

__global__ __launch_bounds__(256) void spmm32p_kernel(
    const int4* __restrict__ nodeinfo, const int* __restrict__ cols,
    const __half* __restrict__ xs, int useW,
    __half* __restrict__ outh) {
  const int t = threadIdx.x;
  const int lane = t & 63;
  const int wv = t >> 6;
  const int b = blockIdx.x;
  const int xcd = b & 7;
  const int slice = xcd >> 1;
  const int sub = xcd & 1;
  const int npair = lane >> 5;
  const int node = (b >> 3) * 16 + sub * 8 + wv * 2 + npair;  // NN = 3125*16
  const int e8 = (lane >> 2) & 7;
  const int q4 = lane & 3;
  const __half* xb = xs + (long)slice * NN * 32 + q4 * 8;
  int4 ni = nodeinfo[node];
  const int e0 = ni.x, end = ni.y;
  const float d = __int_as_float(useW ? ni.w : ni.z);
  const int deg = end - e0;
  int dmax = deg > 0 ? deg : 0;
  {
    int od = __shfl_xor(dmax, 32, 64);
    dmax = dmax > od ? dmax : od;
  }
  const int kmax = (dmax + 7) >> 3;
  const int ecl = (end - 1) > 0 ? (end - 1) : 0;
  const __half2 z2 = __float2half2_rn(0.f);
  __half2 A0 = z2, A1 = z2, A2 = z2, A3 = z2;
  __half2 B0 = z2, B1 = z2, B2 = z2, B3 = z2;
  int k = 0;
  for (; k + 2 <= kmax; k += 2) {
    int ee0 = e0 + k * 8 + e8;
    int ee1 = ee0 + 8;
    bool m0 = ee0 < end, m1 = ee1 < end;
    int s0 = cols[m0 ? ee0 : ecl];
    int s1 = cols[m1 ? ee1 : ecl];
    f32x4 v0 = *(const f32x4*)(xb + (unsigned)s0 * 32u);
    f32x4 v1 = *(const f32x4*)(xb + (unsigned)s1 * 32u);
    const __half2* h0 = (const __half2*)&v0;
    const __half2* h1 = (const __half2*)&v1;
    A0 = __hadd2(A0, m0 ? h0[0] : z2); A1 = __hadd2(A1, m0 ? h0[1] : z2);
    A2 = __hadd2(A2, m0 ? h0[2] : z2); A3 = __hadd2(A3, m0 ? h0[3] : z2);
    B0 = __hadd2(B0, m1 ? h1[0] : z2); B1 = __hadd2(B1, m1 ? h1[1] : z2);
    B2 = __hadd2(B2, m1 ? h1[2] : z2); B3 = __hadd2(B3, m1 ? h1[3] : z2);
  }
  if (k < kmax) {
    int ee = e0 + k * 8 + e8;
    bool m = ee < end;
    int s = cols[m ? ee : ecl];
    f32x4 v = *(const f32x4*)(xb + (unsigned)s * 32u);
    const __half2* h = (const __half2*)&v;
    A0 = __hadd2(A0, m ? h[0] : z2); A1 = __hadd2(A1, m ? h[1] : z2);
    A2 = __hadd2(A2, m ? h[2] : z2); A3 = __hadd2(A3, m ? h[3] : z2);
  }
  A0 = __hadd2(A0, B0); A1 = __hadd2(A1, B1);
  A2 = __hadd2(A2, B2); A3 = __hadd2(A3, B3);
  float2 p0 = __half22float2(A0), p1 = __half22float2(A1);
  float2 p2 = __half22float2(A2), p3 = __half22float2(A3);
  float f0 = p0.x, f1 = p0.y, f2 = p1.x, f3 = p1.y;
  float f4 = p2.x, f5 = p2.y, f6 = p3.x, f7 = p3.y;
  {
    bool hi = (lane & 4) != 0;
    float t0 = hi ? f0 : f4, t1 = hi ? f1 : f5, t2 = hi ? f2 : f6, t3 = hi ? f3 : f7;
    t0 = __shfl_xor(t0, 4, 64); t1 = __shfl_xor(t1, 4, 64);
    t2 = __shfl_xor(t2, 4, 64); t3 = __shfl_xor(t3, 4, 64);
    f0 = (hi ? f4 : f0) + t0; f1 = (hi ? f5 : f1) + t1;
    f2 = (hi ? f6 : f2) + t2; f3 = (hi ? f7 : f3) + t3;
  }
  {
    bool hi = (lane & 8) != 0;
    float t0 = hi ? f0 : f2, t1 = hi ? f1 : f3;
    t0 = __shfl_xor(t0, 8, 64); t1 = __shfl_xor(t1, 8, 64);
    f0 = (hi ? f2 : f0) + t0; f1 = (hi ? f3 : f1) + t1;
  }
  float fin;
  {
    bool hi = (lane & 16) != 0;
    float t0 = hi ? f0 : f1;
    t0 = __shfl_xor(t0, 16, 64);
    fin = (hi ? f1 : f0) + t0;
  }
  int foff = q4 * 8 + ((lane >> 2) & 1) * 4 + ((lane >> 3) & 1) * 2 + ((lane >> 4) & 1);
  outh[((long)slice * NN + node) * 32 + foff] = __float2half(fin * d);
}

// ---------------- fp16 MFMA GEMM: out = epi( [A1|A2] @ W + bias ) ----------------

template<int KC, int NT, int NTP, int EPI, int H16, int ASRC, int OUTM, int COLSPLIT, int BHOIST>
__global__ __launch_bounds__(256) void mgemm_kernel(
    const void* __restrict__ A1, int lda1,
    const void* __restrict__ A2,
    const ushort* __restrict__ Bf,
    const float* __restrict__ bias,
    const float* __restrict__ g, const float* __restrict__ be,
    const float* __restrict__ mu, const float* __restrict__ va,
    const __half* __restrict__ resp,
    float* __restrict__ outf, __half* __restrict__ outh, int ldc, int Ncols,
    __half* __restrict__ x16, const float* __restrict__ rowscale) {
  const int t = threadIdx.x;
  const int lane = t & 63;
  const int wid = t >> 6;
  const int rowbase = COLSPLIT ? (blockIdx.x * 32 + (wid >> 1) * 16)
                               : (blockIdx.x * 64 + wid * 16);
  const int colbase = COLSPLIT ? ((wid & 1) * NT * 16) : 0;
  const int arow = rowbase + (lane & 15);
  const int kgrp = (lane >> 4) * 8;
  const bool rowok = arow < NN;

  f32x4 acc[NT];
  #pragma unroll
  for (int n = 0; n < NT; ++n) acc[n] = (f32x4){0.f, 0.f, 0.f, 0.f};

  const f32x4 z4 = {0.f, 0.f, 0.f, 0.f};
  f32x4 fra[ASRC == 0 ? KC : 1], frb[ASRC == 0 ? KC : 1];
  uint4 areg[ASRC == 1 ? KC : 1];
  if (ASRC == 0) {
    #pragma unroll
    for (int kc = 0; kc < KC; ++kc) {
      const float* p = (const float*)A1 + (long)arow * lda1 + kc * 32 + kgrp;
      fra[kc] = rowok ? *(const f32x4*)p : z4;
      frb[kc] = rowok ? *(const f32x4*)(p + 4) : z4;
    }
  } else {
    #pragma unroll
    for (int kc = 0; kc < KC; ++kc) {
      const bool second = (KC == 8) && (kc >= 4);
      const ushort* At = (const ushort*)(second ? A2 : A1);
      int k0 = (second ? (kc - 4) : kc) * 32 + kgrp;
      const ushort* p = At + ((long)(k0 >> 5) * NN + arow) * 32 + (k0 & 31);
      areg[kc] = rowok ? *(const uint4*)p : make_uint4(0, 0, 0, 0);
    }
  }

  if (BHOIST) {
    uint4 breg[KC * NT];
    #pragma unroll
    for (int kc = 0; kc < KC; ++kc) {
      const ushort* bp = Bf + ((long)kc * NTP * 64 + lane) * 8 + (long)colbase * 32;
      #pragma unroll
      for (int nt = 0; nt < NT; ++nt)
        breg[kc * NT + nt] = *(const uint4*)(bp + (long)nt * 512);
    }
    #pragma unroll
    for (int kc = 0; kc < KC; ++kc) {
      union { uint4 u; f16x8 v; } cv;
      cv.u = areg[kc];
      #pragma unroll
      for (int nt = 0; nt < NT; ++nt) {
        union { uint4 u; f16x8 v; } bv;
        bv.u = breg[kc * NT + nt];
        acc[nt] = __builtin_amdgcn_mfma_f32_16x16x32_f16(cv.v, bv.v, acc[nt], 0, 0, 0);
      }
    }
  } else {
    #pragma unroll
    for (int kc = 0; kc < KC; ++kc) {
      f16x8 av;
      if (ASRC == 0) {
        #pragma unroll
        for (int j = 0; j < 4; ++j) {
          av[j]     = (_Float16)fra[kc][j];
          av[j + 4] = (_Float16)frb[kc][j];
        }
      } else {
        union { uint4 u; f16x8 v; } cv;
        cv.u = areg[kc];
        av = cv.v;
      }
      const ushort* bp = Bf + ((long)kc * NTP * 64 + lane) * 8 + (long)colbase * 32;
      #pragma unroll
      for (int nt = 0; nt < NT; ++nt) {
        union { uint4 u; f16x8 v; } bv;
        bv.u = *(const uint4*)(bp + (long)nt * 512);
        acc[nt] = __builtin_amdgcn_mfma_f32_16x16x32_f16(av, bv.v, acc[nt], 0, 0, 0);
      }
    }
  }

  const int colg = lane & 15;
  const int rsub = (lane >> 4) * 4;

  if (EPI == EPI_ATTN) {
    float part0 = 0.f, part1 = 0.f, part2 = 0.f, part3 = 0.f;
    #pragma unroll
    for (int nt = 0; nt < NT; ++nt) {
      int c = nt * 16 + colg;
      float w2v = g[c];
      float bb = bias[c];
      part0 = fmaf(fmaxf(acc[nt][0] + bb, 0.f), w2v, part0);
      part1 = fmaf(fmaxf(acc[nt][1] + bb, 0.f), w2v, part1);
      part2 = fmaf(fmaxf(acc[nt][2] + bb, 0.f), w2v, part2);
      part3 = fmaf(fmaxf(acc[nt][3] + bb, 0.f), w2v, part3);
    }
    #pragma unroll
    for (int m = 1; m <= 8; m <<= 1) {
      part0 += __shfl_xor(part0, m, 64);
      part1 += __shfl_xor(part1, m, 64);
      part2 += __shfl_xor(part2, m, 64);
      part3 += __shfl_xor(part3, m, 64);
    }
    const float b2v = be[0];
    float s0 = 1.f / (1.f + __expf(-(part0 + b2v)));
    float s1 = 1.f / (1.f + __expf(-(part1 + b2v)));
    float s2 = 1.f / (1.f + __expf(-(part2 + b2v)));
    float s3 = 1.f / (1.f + __expf(-(part3 + b2v)));
    const __half* h0t = (const __half*)A1;
    const __half* aggt = (const __half*)A2;
    #pragma unroll
    for (int nt = 0; nt < NT; ++nt) {
      int c = nt * 16 + colg;
      #pragma unroll
      for (int i = 0; i < 4; ++i) {
        int r = rowbase + rsub + i;
        if (r >= NN) continue;
        long sidx = ((long)(c >> 5) * NN + r) * 32 + (c & 31);
        float sv = (i == 0) ? s0 : ((i == 1) ? s1 : ((i == 2) ? s2 : s3));
        float h = __half2float(h0t[sidx]) + __half2float(aggt[sidx]) * sv;
        x16[sidx] = __float2half(h * rowscale[r]);
      }
    }
    return;
  }

  #pragma unroll
  for (int nt = 0; nt < NT; ++nt) {
    int c = colbase + nt * 16 + colg;
    if (c >= Ncols) continue;
    float bb = bias ? bias[c] : 0.f;
    float scale = 1.f, shift = 0.f;
    if (EPI == EPI_BN || EPI == EPI_BN_RES) {
      scale = g[c] * rsqrtf(va[c] + EPSV);
      shift = be[c] - mu[c] * scale;
    }
    #pragma unroll
    for (int i = 0; i < 4; ++i) {
      int r = rowbase + rsub + i;
      if (r >= NN) continue;
      long sidx = ((long)(c >> 5) * NN + r) * 32 + (c & 31);
      float v = acc[nt][i] + bb;
      if (EPI == EPI_RELU) {
        v = fmaxf(v, 0.f);
      } else if (EPI == EPI_BN || EPI == EPI_BN_RES) {
        v = fmaxf(v * scale + shift, 0.f);
        if (EPI == EPI_BN_RES) v += __half2float(resp[sidx]);
      }
      if (OUTM == 0) {
        outf[(long)r * ldc + c] = v;
      } else {
        outh[sidx] = __float2half(v);
        if (H16 == H16_SCALED) x16[sidx] = __float2half(v * rowscale[r]);
      }
    }
  }
}

// ---------------- fused layer-2 GEMM + out GEMM (rst2 lives only in LDS) ----------------
// Block = 16 rows, 4 waves. Phase 1: rst2 tile 16x128 (wave = 16r x 32c quarter,
// BN+relu+residual) -> LDS. Phase 2: out tile 16x50 from LDS (wave = one 16-col slice).

__global__ __launch_bounds__(256) void l2out_kernel(
    const __half* __restrict__ A1,      // T1 (z, sliced)
    const ushort* __restrict__ Bf,      // gcf2
    const float* __restrict__ bias,     // gc_b + 2*HF
    const float* __restrict__ g, const float* __restrict__ be,
    const float* __restrict__ mu, const float* __restrict__ va,
    const __half* __restrict__ resp,    // T0 (rst1)
    const ushort* __restrict__ OwF,     // ow_f
    const float* __restrict__ out_b,
    float* __restrict__ outf) {
  __shared__ __half sh[16][HF + 8];     // +8 halves pad -> 2-way max on f16x8 reads
  const int t = threadIdx.x;
  const int lane = t & 63;
  const int wid = t >> 6;
  const int rowbase = blockIdx.x * 16;  // NN = 3125*16, exact
  const int colbase = wid * 32;         // NT=2 quarter
  const int arow = rowbase + (lane & 15);
  const int kgrp = (lane >> 4) * 8;

  f32x4 acc[2];
  acc[0] = (f32x4){0.f, 0.f, 0.f, 0.f};
  acc[1] = (f32x4){0.f, 0.f, 0.f, 0.f};
  uint4 areg[4];
  #pragma unroll
  for (int kc = 0; kc < 4; ++kc) {
    int k0 = kc * 32 + kgrp;
    areg[kc] = *(const uint4*)(A1 + ((long)(k0 >> 5) * NN + arow) * 32 + (k0 & 31));
  }
  #pragma unroll
  for (int kc = 0; kc < 4; ++kc) {
    union { uint4 u; f16x8 v; } cv;
    cv.u = areg[kc];
    const ushort* bp = Bf + ((long)kc * 8 * 64 + lane) * 8 + (long)colbase * 32;
    #pragma unroll
    for (int nt = 0; nt < 2; ++nt) {
      union { uint4 u; f16x8 v; } bv;
      bv.u = *(const uint4*)(bp + (long)nt * 512);
      acc[nt] = __builtin_amdgcn_mfma_f32_16x16x32_f16(cv.v, bv.v, acc[nt], 0, 0, 0);
    }
  }
  const int colg = lane & 15;
  const int rsub = (lane >> 4) * 4;
  #pragma unroll
  for (int nt = 0; nt < 2; ++nt) {
    int c = colbase + nt * 16 + colg;
    float bb = bias[c];
    float scale = g[c] * rsqrtf(va[c] + EPSV);
    float shift = be[c] - mu[c] * scale;
    #pragma unroll
    for (int i = 0; i < 4; ++i) {
      int r = rowbase + rsub + i;
      long sidx = ((long)(c >> 5) * NN + r) * 32 + (c & 31);
      float v = fmaxf((acc[nt][i] + bb) * scale + shift, 0.f) + __half2float(resp[sidx]);
      sh[rsub + i][c] = __float2half(v);
    }
  }
  __syncthreads();
  // phase 2: out = sh[16][128] @ ow_f (+out_b); wave wid -> cols wid*16..+15
  f32x4 acc2 = (f32x4){0.f, 0.f, 0.f, 0.f};
  #pragma unroll
  for (int kc = 0; kc < 4; ++kc) {
    union { uint4 u; f16x8 v; } av;
    av.v = *(const f16x8*)&sh[lane & 15][kc * 32 + kgrp];
    union { uint4 u; f16x8 v; } bv;
    bv.u = *(const uint4*)(OwF + ((long)kc * 4 * 64 + lane) * 8 + (long)wid * 512);
    acc2 = __builtin_amdgcn_mfma_f32_16x16x32_f16(av.v, bv.v, acc2, 0, 0, 0);
  }
  int c = wid * 16 + colg;
  if (c < CC) {
    float bb = out_b[c];
    #pragma unroll
    for (int i = 0; i < 4; ++i) {
      int r = rowbase + rsub + i;
      outf[(long)r * CC + c] = acc2[i] + bb;
    }
  }
}

// ---------------- launch ----------------

extern "C" void kernel_launch(void* const* d_in, const int* in_sizes, int n_in,
                              void* d_out, int out_size, void* d_ws, size_t ws_size,
                              hipStream_t stream) {
  const float* features = (const float*)d_in[0];
  const int*   src      = (const int*)d_in[1];
  const int*   dst      = (const int*)d_in[2];
  const float* w_in     = (const float*)d_in[3];
  const float* b_in     = (const float*)d_in[4];
  const float* gc_w     = (const float*)d_in[5];
  const float* gc_b     = (const float*)d_in[6];
  const float* bn_gamma = (const float*)d_in[7];
  const float* bn_beta  = (const float*)d_in[8];
  const float* bn_mean  = (const float*)d_in[9];
  const float* bn_var   = (const float*)d_in[10];
  const float* attn_w1  = (const float*)d_in[11];
  const float* attn_b1  = (const float*)d_in[12];
  const float* attn_w2  = (const float*)d_in[13];
  const float* attn_b2  = (const float*)d_in[14];
  const float* agg_w    = (const float*)d_in[15];
  const float* agg_b    = (const float*)d_in[16];
  const float* out_w    = (const float*)d_in[17];
  const float* out_b    = (const float*)d_in[18];
  float* out = (float*)d_out;

  float* fbase = (float*)d_ws;
  float* inv_mean = fbase;
  float* inv_in   = inv_mean + NN;
  float* inv_out  = inv_in + NN;
  int* row_ptr = (int*)(inv_out + NN);   // NN+16
  int* bsum    = row_ptr + NN + 16;      // 256
  int* col     = bsum + 256;             // EE
  int4* nodeinfo = (int4*)(col + EE);    // NN

  // packed fp16 weights (contiguous: win, agg, at1, gc0..2, ow)
  ushort* pk = (ushort*)(nodeinfo + NN);
  ushort* win_f = pk;
  ushort* agg_f = pk + SZ256;
  ushort* at1_f = pk + 2 * SZ256;
  ushort* gcf0  = pk + 3 * SZ256;
  ushort* gcf1  = gcf0 + SZ128;
  ushort* gcf2  = gcf1 + SZ128;
  ushort* ow_f  = gcf2 + SZ128;

  // fp16 activation pools, sliced [4][NN][32]
  __half* T0 = (__half*)(ow_f + SZOUT);  // h0 -> rst1
  __half* T1 = T0 + NH;                  // neigh / spmm rst
  __half* T2 = T1 + NH;                  // agg -> rst0
  __half* X16 = T2 + NH;                 // h_att -> (layer gather table)

  // preprocessing scratch aliased into T1/T2 (dead until spmm1/GEMM#2)
  unsigned* pd   = (unsigned*)T1;              // 6.4MB
  unsigned* ps   = pd + (long)NSL * NN;        // 6.4MB (pd+ps = T1's 12.8MB exactly)
  unsigned* cur0 = (unsigned*)T2;              // 6.4MB (T2 first written by GEMM#2)

  dim3 b256(256);
  const int gblocks = (NN + 63) / 64;     // 782
  const int gsplit  = GSPLIT;             // 1563
  const int g16     = NN / 16;            // 3125 (l2out)
  const int gspmm = (NN / 16) * 8;        // 25000
  const int gpre = NSL * 4;

  // FUSE1: edge histograms + weight prepack (independent)
  fuse1_kernel<<<256 + PKB, b256, 0, stream>>>(
      (const int4*)dst, (const int4*)src, pd, ps,
      w_in, agg_w, attn_w1, gc_w, out_w, pk);

  // FUSE2: GEMM#1 (h0 -> T0) + degree reduce/scan
  fuse2_kernel<<<GSPLIT + GN, b256, 0, stream>>>(
      features, win_f, b_in, T0,
      pd, ps, row_ptr, bsum, inv_mean, inv_in, inv_out);

  // cursor init (absorbs bsum scan) -> cur0 + nodeinfo
  cursor_init2_kernel<<<GN, b256, 0, stream>>>(
      row_ptr, bsum, pd, cur0, inv_mean, inv_in, nodeinfo);
  // CSR fill
  fill_partial_kernel<<<gpre, b256, 0, stream>>>((const int4*)dst, (const int4*)src, cur0, col);

  // spmm1: neigh = mean-agg(h0) -> T1 (pd/ps dead now)
  spmm32p_kernel<<<gspmm, b256, 0, stream>>>(nodeinfo, col, T0, 0, T1);
  // #2: agg = relu([h0|neigh] @ agg_w + agg_b) -> T2 (cur0 dead now)
  mgemm_kernel<8, 4, 8, EPI_RELU, H16_NONE, 1, 1, 1, 0><<<gsplit, b256, 0, stream>>>(
      T0, 0, T1, agg_f, agg_b,
      nullptr, nullptr, nullptr, nullptr, nullptr,
      nullptr, T2, HF, HF, nullptr, nullptr);
  // #3 (fused attn): needs full row per wave -> NT=8, no col-split
  mgemm_kernel<8, 8, 8, EPI_ATTN, H16_NONE, 1, 1, 0, 0><<<gblocks, b256, 0, stream>>>(
      T0, 0, T2, at1_f, attn_b1,
      attn_w2, attn_b2, nullptr, nullptr, nullptr,
      nullptr, nullptr, HF, HF, X16, inv_out);

  // layer 0: spmm(X16) -> T1 ; rst0 = relu(BN(T1@gc0+b0)) -> T2 (+X16)
  spmm32p_kernel<<<gspmm, b256, 0, stream>>>(nodeinfo, col, X16, 1, T1);
  mgemm_kernel<4, 4, 8, EPI_BN, H16_SCALED, 1, 1, 1, 1><<<gsplit, b256, 0, stream>>>(
      T1, 0, nullptr, gcf0, gc_b,
      bn_gamma, bn_beta, bn_mean, bn_var, nullptr,
      nullptr, T2, HF, HF, X16, inv_out);
  // layer 1: spmm(X16) -> T1 ; rst1 = relu(BN(T1@gc1+b1)) + rst0 -> T0 (+X16)
  spmm32p_kernel<<<gspmm, b256, 0, stream>>>(nodeinfo, col, X16, 1, T1);
  mgemm_kernel<4, 4, 8, EPI_BN_RES, H16_SCALED, 1, 1, 1, 1><<<gsplit, b256, 0, stream>>>(
      T1, 0, nullptr, gcf1, gc_b + HF,
      bn_gamma + HF, bn_beta + HF, bn_mean + HF, bn_var + HF, T2,
      nullptr, T0, HF, HF, X16, inv_out);
  // layer 2: spmm(X16) -> T1 ; fused rst2(+res T0) @ out_w -> d_out (rst2 in LDS only)
  spmm32p_kernel<<<gspmm, b256, 0, stream>>>(nodeinfo, col, X16, 1, T1);
  l2out_kernel<<<g16, b256, 0, stream>>>(
      T1, gcf2, gc_b + 2 * HF,
      bn_gamma + 2 * HF, bn_beta + 2 * HF, bn_mean + 2 * HF, bn_var + 2 * HF,
      T0, ow_f, out_b, out);
}

// Round 24
// 291.495 us; speedup vs baseline: 1.2179x; 1.0313x over previous
//
#include <hip/hip_runtime.h>
#include <hip/hip_fp16.h>
#include <math.h>

constexpr int NN  = 50000;   // nodes
constexpr int EE  = 800000;  // edges
constexpr int INF_ = 256;    // input feat
constexpr int HF  = 128;     // hidden
constexpr int CC  = 50;      // classes
constexpr long NH = (long)NN * HF;
constexpr int NSL = 32;          // edge slices (preprocessing)
constexpr int ESL = EE / NSL;    // 25000 edges per slice
constexpr int CHK = 12500;       // nodes per chunk (4 chunks), 50KB LDS
#define EPSV 1e-5f

enum { EPI_RELU = 0, EPI_NONE = 1, EPI_BN = 2, EPI_BN_RES = 3 };
enum { H16_NONE = 0, H16_SCALED = 2 };

typedef __attribute__((ext_vector_type(4))) float f32x4;
typedef __attribute__((ext_vector_type(8))) _Float16 f16x8;

constexpr int SZ256 = 8 * 8 * 512;   // K=256, NTP=8
constexpr int SZ128 = 4 * 8 * 512;   // K=128, NTP=8
constexpr int SZOUT = 4 * 4 * 512;   // K=128, NTP=4
constexpr int PK_TOTAL = 3 * SZ256 + 3 * SZ128 + SZOUT;
constexpr int PKB = (PK_TOTAL + 255) / 256;   // prepack blocks (608)

// ---------------- FUSE1: edge histograms (256 blocks) + weight prepack (PKB blocks) ----------------

__global__ __launch_bounds__(256) void fuse1_kernel(
    const int4* __restrict__ dst4, const int4* __restrict__ src4,
    unsigned* __restrict__ pd, unsigned* __restrict__ ps,
    const float* __restrict__ w_in, const float* __restrict__ agg_w,
    const float* __restrict__ at1, const float* __restrict__ gc_w,
    const float* __restrict__ out_w, ushort* __restrict__ outbase) {
  __shared__ unsigned cnt[CHK];
  if (blockIdx.x < 256) {
    int bb = blockIdx.x;
    const int which = bb >> 7;
    bb &= 127;
    const int4* keys4 = which ? src4 : dst4;
    unsigned* partials = which ? ps : pd;
    const int chunk = bb & 3;
    const int sl = bb >> 2;
    for (int i = threadIdx.x; i < CHK; i += 256) cnt[i] = 0;
    __syncthreads();
    const int base4 = sl * (ESL / 4);
    const int lo = chunk * CHK;
    for (int i = threadIdx.x; i < ESL / 4; i += 256) {
      int4 k = keys4[base4 + i];
      int a;
      a = k.x - lo; if ((unsigned)a < (unsigned)CHK) atomicAdd(&cnt[a], 1u);
      a = k.y - lo; if ((unsigned)a < (unsigned)CHK) atomicAdd(&cnt[a], 1u);
      a = k.z - lo; if ((unsigned)a < (unsigned)CHK) atomicAdd(&cnt[a], 1u);
      a = k.w - lo; if ((unsigned)a < (unsigned)CHK) atomicAdd(&cnt[a], 1u);
    }
    __syncthreads();
    unsigned* p = partials + (long)sl * NN + lo;
    for (int i = threadIdx.x; i < CHK; i += 256) p[i] = cnt[i];
    return;
  }
  // prepack branch
  int idx = (blockIdx.x - 256) * 256 + threadIdx.x;
  if (idx >= PK_TOTAL) return;
  const float* W; int N, ldw, NTpad, local; ushort* outp;
  if (idx < 3 * SZ256) {
    int s = idx / SZ256; local = idx - s * SZ256;
    W = (s == 0) ? w_in : ((s == 1) ? agg_w : at1);
    N = HF; ldw = HF; NTpad = 8;
    outp = outbase + s * SZ256;
  } else if (idx < 3 * SZ256 + 3 * SZ128) {
    int r = idx - 3 * SZ256; int s = r / SZ128; local = r - s * SZ128;
    W = gc_w + (long)s * HF * HF; N = HF; ldw = HF; NTpad = 8;
    outp = outbase + 3 * SZ256 + s * SZ128;
  } else {
    local = idx - 3 * SZ256 - 3 * SZ128;
    W = out_w; N = CC; ldw = CC; NTpad = 4;
    outp = outbase + 3 * SZ256 + 3 * SZ128;
  }
  int j    = local & 7;
  int lane = (local >> 3) & 63;
  int rest = local >> 9;
  int nt = rest % NTpad;
  int kc = rest / NTpad;
  int k = kc * 32 + (lane >> 4) * 8 + j;
  int n = nt * 16 + (lane & 15);
  float w = (n < N) ? W[(long)k * ldw + n] : 0.f;
  outp[local] = __half_as_ushort(__float2half(w));
}

// ---------------- FUSE2: GEMM#1 (gsplit blocks) + degree reduce/scan (gN blocks) ----------------

constexpr int GSPLIT = (NN + 31) / 32;   // 1563
constexpr int GN = (NN + 255) / 256;     // 196

__global__ __launch_bounds__(256) void fuse2_kernel(
    const float* __restrict__ features, const ushort* __restrict__ Bf,
    const float* __restrict__ bias, __half* __restrict__ outh,
    const unsigned* __restrict__ pd, const unsigned* __restrict__ ps,
    int* __restrict__ row_ptr, int* __restrict__ bsum,
    float* __restrict__ inv_mean, float* __restrict__ inv_in,
    float* __restrict__ inv_out) {
  __shared__ int sh[256];
  if (blockIdx.x >= GSPLIT) {
    int n = (blockIdx.x - GSPLIT) * 256 + threadIdx.x;
    unsigned di = 0, dz = 0;
    if (n < NN) {
      #pragma unroll 8
      for (int sl = 0; sl < NSL; ++sl) {
        di += pd[(long)sl * NN + n];
        dz += ps[(long)sl * NN + n];
      }
      float fdi = fmaxf((float)di, 1.f), fdz = fmaxf((float)dz, 1.f);
      inv_mean[n] = 1.f / fdi;
      inv_in[n]  = rsqrtf(fdi);
      inv_out[n] = rsqrtf(fdz);
    }
    int v = (n < NN) ? (int)di : 0;
    sh[threadIdx.x] = v;
    __syncthreads();
    #pragma unroll
    for (int off = 1; off < 256; off <<= 1) {
      int tv = (threadIdx.x >= off) ? sh[threadIdx.x - off] : 0;
      __syncthreads();
      sh[threadIdx.x] += tv;
      __syncthreads();
    }
    if (n < NN) row_ptr[n] = sh[threadIdx.x] - v;
    if (threadIdx.x == 255) bsum[blockIdx.x - GSPLIT] = sh[255];
    return;
  }
  // GEMM#1 branch (KC=8, NT=4, NTP=8, fp32 A, col-split)
  const int t = threadIdx.x;
  const int lane = t & 63;
  const int wid = t >> 6;
  const int rowbase = blockIdx.x * 32 + (wid >> 1) * 16;
  const int colbase = (wid & 1) * 64;
  const int arow = rowbase + (lane & 15);
  const int kgrp = (lane >> 4) * 8;
  const bool rowok = arow < NN;

  f32x4 acc[4];
  #pragma unroll
  for (int n = 0; n < 4; ++n) acc[n] = (f32x4){0.f, 0.f, 0.f, 0.f};
  const f32x4 z4 = {0.f, 0.f, 0.f, 0.f};
  f32x4 fra[8], frb[8];
  #pragma unroll
  for (int kc = 0; kc < 8; ++kc) {
    const float* p = features + (long)arow * INF_ + kc * 32 + kgrp;
    fra[kc] = rowok ? *(const f32x4*)p : z4;
    frb[kc] = rowok ? *(const f32x4*)(p + 4) : z4;
  }
  #pragma unroll
  for (int kc = 0; kc < 8; ++kc) {
    f16x8 av;
    #pragma unroll
    for (int j = 0; j < 4; ++j) {
      av[j]     = (_Float16)fra[kc][j];
      av[j + 4] = (_Float16)frb[kc][j];
    }
    const ushort* bp = Bf + ((long)kc * 8 * 64 + lane) * 8 + (long)colbase * 32;
    #pragma unroll
    for (int nt = 0; nt < 4; ++nt) {
      union { uint4 u; f16x8 v; } bv;
      bv.u = *(const uint4*)(bp + (long)nt * 512);
      acc[nt] = __builtin_amdgcn_mfma_f32_16x16x32_f16(av, bv.v, acc[nt], 0, 0, 0);
    }
  }
  const int colg = lane & 15;
  const int rsub = (lane >> 4) * 4;
  #pragma unroll
  for (int nt = 0; nt < 4; ++nt) {
    int c = colbase + nt * 16 + colg;
    float bb = bias[c];
    #pragma unroll
    for (int i = 0; i < 4; ++i) {
      int r = rowbase + rsub + i;
      if (r >= NN) continue;
      long sidx = ((long)(c >> 5) * NN + r) * 32 + (c & 31);
      outh[sidx] = __float2half(fmaxf(acc[nt][i] + bb, 0.f));
    }
  }
}

// ---------------- cursor_init (absorbs the bsum scan) ----------------

__global__ __launch_bounds__(256) void cursor_init2_kernel(
    const int* __restrict__ row_ptr, const int* __restrict__ bsum,
    const unsigned* __restrict__ pd, unsigned* __restrict__ cur0,
    const float* __restrict__ inv_mean, const float* __restrict__ inv_in,
    int4* __restrict__ nodeinfo) {
  __shared__ int sh[256];
  int part = 0;
  for (int j = threadIdx.x; j < (int)blockIdx.x; j += 256) part += bsum[j];
  sh[threadIdx.x] = part;
  __syncthreads();
  #pragma unroll
  for (int off = 128; off >= 1; off >>= 1) {
    if (threadIdx.x < off) sh[threadIdx.x] += sh[threadIdx.x + off];
    __syncthreads();
  }
  const int boff = sh[0];
  int n = blockIdx.x * 256 + threadIdx.x;
  if (n >= NN) return;
  unsigned start = (unsigned)(row_ptr[n] + boff);
  unsigned run = start;
  #pragma unroll 8
  for (int sl = 0; sl < NSL; ++sl) {
    cur0[(long)sl * NN + n] = run;
    run += pd[(long)sl * NN + n];
  }
  nodeinfo[n] = make_int4((int)start, (int)run,
                          __float_as_int(inv_mean[n]), __float_as_int(inv_in[n]));
}

__global__ __launch_bounds__(256) void fill_partial_kernel(
    const int4* __restrict__ dst4, const int4* __restrict__ src4,
    const unsigned* __restrict__ cur0, int* __restrict__ col) {
  __shared__ unsigned cur[CHK];
  const int chunk = blockIdx.x & 3;
  const int sl = blockIdx.x >> 2;
  const int lo = chunk * CHK;
  const unsigned* c0 = cur0 + (long)sl * NN + lo;
  for (int i = threadIdx.x; i < CHK; i += 256) cur[i] = c0[i];
  __syncthreads();
  const int base4 = sl * (ESL / 4);
  for (int i = threadIdx.x; i < ESL / 4; i += 256) {
    int4 d = dst4[base4 + i];
    int4 s = src4[base4 + i];
    int a;
    a = d.x - lo; if ((unsigned)a < (unsigned)CHK) col[atomicAdd(&cur[a], 1u)] = s.x;
    a = d.y - lo; if ((unsigned)a < (unsigned)CHK) col[atomicAdd(&cur[a], 1u)] = s.y;
    a = d.z - lo; if ((unsigned)a < (unsigned)CHK) col[atomicAdd(&cur[a], 1u)] = s.z;
    a = d.w - lo; if ((unsigned)a < (unsigned)CHK) col[atomicAdd(&cur[a], 1u)] = s.w;
  }
}

// ---------------- SpMM: 4 slices x 32 feats (L2-resident), 2 nodes per wave ----------------

__global__ __launch_bounds__(256) void spmm32p_kernel(
    const int4* __restrict__ nodeinfo, const int* __restrict__ cols,
    const __half* __restrict__ xs, int useW,
    __half* __restrict__ outh) {
  const int t = threadIdx.x;
  const int lane = t & 63;
  const int wv = t >> 6;
  const int b = blockIdx.x;
  const int xcd = b & 7;
  const int slice = xcd >> 1;
  const int sub = xcd & 1;
  const int npair = lane >> 5;
  const int node = (b >> 3) * 16 + sub * 8 + wv * 2 + npair;  // NN = 3125*16
  const int e8 = (lane >> 2) & 7;
  const int q4 = lane & 3;
  const __half* xb = xs + (long)slice * NN * 32 + q4 * 8;
  int4 ni = nodeinfo[node];
  const int e0 = ni.x, end = ni.y;
  const float d = __int_as_float(useW ? ni.w : ni.z);
  const int deg = end - e0;
  int dmax = deg > 0 ? deg : 0;
  {
    int od = __shfl_xor(dmax, 32, 64);
    dmax = dmax > od ? dmax : od;
  }
  const int kmax = (dmax + 7) >> 3;
  const int ecl = (end - 1) > 0 ? (end - 1) : 0;
  const __half2 z2 = __float2half2_rn(0.f);
  __half2 A0 = z2, A1 = z2, A2 = z2, A3 = z2;
  __half2 B0 = z2, B1 = z2, B2 = z2, B3 = z2;
  int k = 0;
  for (; k + 2 <= kmax; k += 2) {
    int ee0 = e0 + k * 8 + e8;
    int ee1 = ee0 + 8;
    bool m0 = ee0 < end, m1 = ee1 < end;
    int s0 = cols[m0 ? ee0 : ecl];
    int s1 = cols[m1 ? ee1 : ecl];
    f32x4 v0 = *(const f32x4*)(xb + (unsigned)s0 * 32u);
    f32x4 v1 = *(const f32x4*)(xb + (unsigned)s1 * 32u);
    const __half2* h0 = (const __half2*)&v0;
    const __half2* h1 = (const __half2*)&v1;
    A0 = __hadd2(A0, m0 ? h0[0] : z2); A1 = __hadd2(A1, m0 ? h0[1] : z2);
    A2 = __hadd2(A2, m0 ? h0[2] : z2); A3 = __hadd2(A3, m0 ? h0[3] : z2);
    B0 = __hadd2(B0, m1 ? h1[0] : z2); B1 = __hadd2(B1, m1 ? h1[1] : z2);
    B2 = __hadd2(B2, m1 ? h1[2] : z2); B3 = __hadd2(B3, m1 ? h1[3] : z2);
  }
  if (k < kmax) {
    int ee = e0 + k * 8 + e8;
    bool m = ee < end;
    int s = cols[m ? ee : ecl];
    f32x4 v = *(const f32x4*)(xb + (unsigned)s * 32u);
    const __half2* h = (const __half2*)&v;
    A0 = __hadd2(A0, m ? h[0] : z2); A1 = __hadd2(A1, m ? h[1] : z2);
    A2 = __hadd2(A2, m ? h[2] : z2); A3 = __hadd2(A3, m ? h[3] : z2);
  }
  A0 = __hadd2(A0, B0); A1 = __hadd2(A1, B1);
  A2 = __hadd2(A2, B2); A3 = __hadd2(A3, B3);
  float2 p0 = __half22float2(A0), p1 = __half22float2(A1);
  float2 p2 = __half22float2(A2), p3 = __half22float2(A3);
  float f0 = p0.x, f1 = p0.y, f2 = p1.x, f3 = p1.y;
  float f4 = p2.x, f5 = p2.y, f6 = p3.x, f7 = p3.y;
  {
    bool hi = (lane & 4) != 0;
    float t0 = hi ? f0 : f4, t1 = hi ? f1 : f5, t2 = hi ? f2 : f6, t3 = hi ? f3 : f7;
    t0 = __shfl_xor(t0, 4, 64); t1 = __shfl_xor(t1, 4, 64);
    t2 = __shfl_xor(t2, 4, 64); t3 = __shfl_xor(t3, 4, 64);
    f0 = (hi ? f4 : f0) + t0; f1 = (hi ? f5 : f1) + t1;
    f2 = (hi ? f6 : f2) + t2; f3 = (hi ? f7 : f3) + t3;
  }
  {
    bool hi = (lane & 8) != 0;
    float t0 = hi ? f0 : f2, t1 = hi ? f1 : f3;
    t0 = __shfl_xor(t0, 8, 64); t1 = __shfl_xor(t1, 8, 64);
    f0 = (hi ? f2 : f0) + t0; f1 = (hi ? f3 : f1) + t1;
  }
  float fin;
  {
    bool hi = (lane & 16) != 0;
    float t0 = hi ? f0 : f1;
    t0 = __shfl_xor(t0, 16, 64);
    fin = (hi ? f1 : f0) + t0;
  }
  int foff = q4 * 8 + ((lane >> 2) & 1) * 4 + ((lane >> 3) & 1) * 2 + ((lane >> 4) & 1);
  outh[((long)slice * NN + node) * 32 + foff] = __float2half(fin * d);
}

// ---------------- fp16 MFMA GEMM: out = epi( [A1|A2] @ W + bias ) ----------------

template<int KC, int NT, int NTP, int EPI, int H16, int ASRC, int OUTM, int COLSPLIT, int BHOIST>
__global__ __launch_bounds__(256) void mgemm_kernel(
    const void* __restrict__ A1, int lda1,
    const void* __restrict__ A2,
    const ushort* __restrict__ Bf,
    const float* __restrict__ bias,
    const float* __restrict__ g, const float* __restrict__ be,
    const float* __restrict__ mu, const float* __restrict__ va,
    const __half* __restrict__ resp,
    float* __restrict__ outf, __half* __restrict__ outh, int ldc, int Ncols,
    __half* __restrict__ x16, const float* __restrict__ rowscale) {
  const int t = threadIdx.x;
  const int lane = t & 63;
  const int wid = t >> 6;
  const int rowbase = COLSPLIT ? (blockIdx.x * 32 + (wid >> 1) * 16)
                               : (blockIdx.x * 64 + wid * 16);
  const int colbase = COLSPLIT ? ((wid & 1) * NT * 16) : 0;
  const int arow = rowbase + (lane & 15);
  const int kgrp = (lane >> 4) * 8;
  const bool rowok = arow < NN;

  f32x4 acc[NT];
  #pragma unroll
  for (int n = 0; n < NT; ++n) acc[n] = (f32x4){0.f, 0.f, 0.f, 0.f};

  const f32x4 z4 = {0.f, 0.f, 0.f, 0.f};
  f32x4 fra[ASRC == 0 ? KC : 1], frb[ASRC == 0 ? KC : 1];
  uint4 areg[ASRC == 1 ? KC : 1];
  if (ASRC == 0) {
    #pragma unroll
    for (int kc = 0; kc < KC; ++kc) {
      const float* p = (const float*)A1 + (long)arow * lda1 + kc * 32 + kgrp;
      fra[kc] = rowok ? *(const f32x4*)p : z4;
      frb[kc] = rowok ? *(const f32x4*)(p + 4) : z4;
    }
  } else {
    #pragma unroll
    for (int kc = 0; kc < KC; ++kc) {
      const bool second = (KC == 8) && (kc >= 4);
      const ushort* At = (const ushort*)(second ? A2 : A1);
      int k0 = (second ? (kc - 4) : kc) * 32 + kgrp;
      const ushort* p = At + ((long)(k0 >> 5) * NN + arow) * 32 + (k0 & 31);
      areg[kc] = rowok ? *(const uint4*)p : make_uint4(0, 0, 0, 0);
    }
  }

  if (BHOIST) {
    uint4 breg[KC * NT];
    #pragma unroll
    for (int kc = 0; kc < KC; ++kc) {
      const ushort* bp = Bf + ((long)kc * NTP * 64 + lane) * 8 + (long)colbase * 32;
      #pragma unroll
      for (int nt = 0; nt < NT; ++nt)
        breg[kc * NT + nt] = *(const uint4*)(bp + (long)nt * 512);
    }
    #pragma unroll
    for (int kc = 0; kc < KC; ++kc) {
      union { uint4 u; f16x8 v; } cv;
      cv.u = areg[kc];
      #pragma unroll
      for (int nt = 0; nt < NT; ++nt) {
        union { uint4 u; f16x8 v; } bv;
        bv.u = breg[kc * NT + nt];
        acc[nt] = __builtin_amdgcn_mfma_f32_16x16x32_f16(cv.v, bv.v, acc[nt], 0, 0, 0);
      }
    }
  } else {
    #pragma unroll
    for (int kc = 0; kc < KC; ++kc) {
      f16x8 av;
      if (ASRC == 0) {
        #pragma unroll
        for (int j = 0; j < 4; ++j) {
          av[j]     = (_Float16)fra[kc][j];
          av[j + 4] = (_Float16)frb[kc][j];
        }
      } else {
        union { uint4 u; f16x8 v; } cv;
        cv.u = areg[kc];
        av = cv.v;
      }
      const ushort* bp = Bf + ((long)kc * NTP * 64 + lane) * 8 + (long)colbase * 32;
      #pragma unroll
      for (int nt = 0; nt < NT; ++nt) {
        union { uint4 u; f16x8 v; } bv;
        bv.u = *(const uint4*)(bp + (long)nt * 512);
        acc[nt] = __builtin_amdgcn_mfma_f32_16x16x32_f16(av, bv.v, acc[nt], 0, 0, 0);
      }
    }
  }

  const int colg = lane & 15;
  const int rsub = (lane >> 4) * 4;

  #pragma unroll
  for (int nt = 0; nt < NT; ++nt) {
    int c = colbase + nt * 16 + colg;
    if (c >= Ncols) continue;
    float bb = bias ? bias[c] : 0.f;
    float scale = 1.f, shift = 0.f;
    if (EPI == EPI_BN || EPI == EPI_BN_RES) {
      scale = g[c] * rsqrtf(va[c] + EPSV);
      shift = be[c] - mu[c] * scale;
    }
    #pragma unroll
    for (int i = 0; i < 4; ++i) {
      int r = rowbase + rsub + i;
      if (r >= NN) continue;
      long sidx = ((long)(c >> 5) * NN + r) * 32 + (c & 31);
      float v = acc[nt][i] + bb;
      if (EPI == EPI_RELU) {
        v = fmaxf(v, 0.f);
      } else if (EPI == EPI_BN || EPI == EPI_BN_RES) {
        v = fmaxf(v * scale + shift, 0.f);
        if (EPI == EPI_BN_RES) v += __half2float(resp[sidx]);
      }
      if (OUTM == 0) {
        outf[(long)r * ldc + c] = v;
      } else {
        outh[sidx] = __float2half(v);
        if (H16 == H16_SCALED) x16[sidx] = __float2half(v * rowscale[r]);
      }
    }
  }
}

// ---------------- col-split attention GEMM (block = 32 rows, 4 waves = 2r x 2c) ----------------
// Phase 1: a = relu([h0|agg]@w1+b1) partial dot over 64-col half -> LDS pdot[2][32].
// Phase 2: s = sigmoid(dot + b2); X16 = (h0 + agg*s) * inv_out (each wave its col-half).

__global__ __launch_bounds__(256) void attn_kernel(
    const __half* __restrict__ h0t, const __half* __restrict__ aggt,
    const ushort* __restrict__ Bf,       // at1_f, NTP=8
    const float* __restrict__ b1,
    const float* __restrict__ w2, const float* __restrict__ b2,
    __half* __restrict__ x16, const float* __restrict__ inv_out) {
  __shared__ float pdot[2][32];
  const int t = threadIdx.x;
  const int lane = t & 63;
  const int wid = t >> 6;
  const int rowg = wid >> 1;           // 0/1
  const int colh = wid & 1;            // 0/1
  const int rowbase = blockIdx.x * 32 + rowg * 16;   // NN = 1562.5*32 -> guard
  const int colbase = colh * 64;
  const int arow = rowbase + (lane & 15);
  const int kgrp = (lane >> 4) * 8;
  const bool rowok = arow < NN;

  f32x4 acc[4];
  #pragma unroll
  for (int n = 0; n < 4; ++n) acc[n] = (f32x4){0.f, 0.f, 0.f, 0.f};
  uint4 areg[8];
  #pragma unroll
  for (int kc = 0; kc < 8; ++kc) {
    const bool second = kc >= 4;
    const __half* At = second ? aggt : h0t;
    int k0 = (second ? (kc - 4) : kc) * 32 + kgrp;
    areg[kc] = rowok ? *(const uint4*)(At + ((long)(k0 >> 5) * NN + arow) * 32 + (k0 & 31))
                     : make_uint4(0, 0, 0, 0);
  }
  #pragma unroll
  for (int kc = 0; kc < 8; ++kc) {
    union { uint4 u; f16x8 v; } cv;
    cv.u = areg[kc];
    const ushort* bp = Bf + ((long)kc * 8 * 64 + lane) * 8 + (long)colbase * 32;
    #pragma unroll
    for (int nt = 0; nt < 4; ++nt) {
      union { uint4 u; f16x8 v; } bv;
      bv.u = *(const uint4*)(bp + (long)nt * 512);
      acc[nt] = __builtin_amdgcn_mfma_f32_16x16x32_f16(cv.v, bv.v, acc[nt], 0, 0, 0);
    }
  }

  const int colg = lane & 15;
  const int rsub = (lane >> 4) * 4;
  float part0 = 0.f, part1 = 0.f, part2 = 0.f, part3 = 0.f;
  #pragma unroll
  for (int nt = 0; nt < 4; ++nt) {
    int c = colbase + nt * 16 + colg;
    float w2v = w2[c];
    float bb = b1[c];
    part0 = fmaf(fmaxf(acc[nt][0] + bb, 0.f), w2v, part0);
    part1 = fmaf(fmaxf(acc[nt][1] + bb, 0.f), w2v, part1);
    part2 = fmaf(fmaxf(acc[nt][2] + bb, 0.f), w2v, part2);
    part3 = fmaf(fmaxf(acc[nt][3] + bb, 0.f), w2v, part3);
  }
  #pragma unroll
  for (int m = 1; m <= 8; m <<= 1) {
    part0 += __shfl_xor(part0, m, 64);
    part1 += __shfl_xor(part1, m, 64);
    part2 += __shfl_xor(part2, m, 64);
    part3 += __shfl_xor(part3, m, 64);
  }
  if (colg == 0) {
    int rib = rowg * 16 + rsub;
    pdot[colh][rib + 0] = part0;
    pdot[colh][rib + 1] = part1;
    pdot[colh][rib + 2] = part2;
    pdot[colh][rib + 3] = part3;
  }
  __syncthreads();
  const float b2v = b2[0];
  float sden[4];
  #pragma unroll
  for (int i = 0; i < 4; ++i) {
    int rib = rowg * 16 + rsub + i;
    float dot = pdot[0][rib] + pdot[1][rib] + b2v;
    sden[i] = 1.f / (1.f + __expf(-dot));
  }
  #pragma unroll
  for (int nt = 0; nt < 4; ++nt) {
    int c = colbase + nt * 16 + colg;
    #pragma unroll
    for (int i = 0; i < 4; ++i) {
      int r = rowbase + rsub + i;
      if (r >= NN) continue;
      long sidx = ((long)(c >> 5) * NN + r) * 32 + (c & 31);
      float h = __half2float(h0t[sidx]) + __half2float(aggt[sidx]) * sden[i];
      x16[sidx] = __float2half(h * inv_out[r]);
    }
  }
}

// ---------------- fused layer-2 GEMM + out GEMM (rst2 lives only in LDS) ----------------

__global__ __launch_bounds__(256) void l2out_kernel(
    const __half* __restrict__ A1,      // T1 (z, sliced)
    const ushort* __restrict__ Bf,      // gcf2
    const float* __restrict__ bias,     // gc_b + 2*HF
    const float* __restrict__ g, const float* __restrict__ be,
    const float* __restrict__ mu, const float* __restrict__ va,
    const __half* __restrict__ resp,    // T0 (rst1)
    const ushort* __restrict__ OwF,     // ow_f
    const float* __restrict__ out_b,
    float* __restrict__ outf) {
  __shared__ __half sh[16][HF + 8];
  const int t = threadIdx.x;
  const int lane = t & 63;
  const int wid = t >> 6;
  const int rowbase = blockIdx.x * 16;  // NN = 3125*16, exact
  const int colbase = wid * 32;
  const int arow = rowbase + (lane & 15);
  const int kgrp = (lane >> 4) * 8;

  f32x4 acc[2];
  acc[0] = (f32x4){0.f, 0.f, 0.f, 0.f};
  acc[1] = (f32x4){0.f, 0.f, 0.f, 0.f};
  uint4 areg[4];
  #pragma unroll
  for (int kc = 0; kc < 4; ++kc) {
    int k0 = kc * 32 + kgrp;
    areg[kc] = *(const uint4*)(A1 + ((long)(k0 >> 5) * NN + arow) * 32 + (k0 & 31));
  }
  #pragma unroll
  for (int kc = 0; kc < 4; ++kc) {
    union { uint4 u; f16x8 v; } cv;
    cv.u = areg[kc];
    const ushort* bp = Bf + ((long)kc * 8 * 64 + lane) * 8 + (long)colbase * 32;
    #pragma unroll
    for (int nt = 0; nt < 2; ++nt) {
      union { uint4 u; f16x8 v; } bv;
      bv.u = *(const uint4*)(bp + (long)nt * 512);
      acc[nt] = __builtin_amdgcn_mfma_f32_16x16x32_f16(cv.v, bv.v, acc[nt], 0, 0, 0);
    }
  }
  const int colg = lane & 15;
  const int rsub = (lane >> 4) * 4;
  #pragma unroll
  for (int nt = 0; nt < 2; ++nt) {
    int c = colbase + nt * 16 + colg;
    float bb = bias[c];
    float scale = g[c] * rsqrtf(va[c] + EPSV);
    float shift = be[c] - mu[c] * scale;
    #pragma unroll
    for (int i = 0; i < 4; ++i) {
      int r = rowbase + rsub + i;
      long sidx = ((long)(c >> 5) * NN + r) * 32 + (c & 31);
      float v = fmaxf((acc[nt][i] + bb) * scale + shift, 0.f) + __half2float(resp[sidx]);
      sh[rsub + i][c] = __float2half(v);
    }
  }
  __syncthreads();
  f32x4 acc2 = (f32x4){0.f, 0.f, 0.f, 0.f};
  #pragma unroll
  for (int kc = 0; kc < 4; ++kc) {
    union { uint4 u; f16x8 v; } av;
    av.v = *(const f16x8*)&sh[lane & 15][kc * 32 + kgrp];
    union { uint4 u; f16x8 v; } bv;
    bv.u = *(const uint4*)(OwF + ((long)kc * 4 * 64 + lane) * 8 + (long)wid * 512);
    acc2 = __builtin_amdgcn_mfma_f32_16x16x32_f16(av.v, bv.v, acc2, 0, 0, 0);
  }
  int c = wid * 16 + colg;
  if (c < CC) {
    float bb = out_b[c];
    #pragma unroll
    for (int i = 0; i < 4; ++i) {
      int r = rowbase + rsub + i;
      outf[(long)r * CC + c] = acc2[i] + bb;
    }
  }
}

// ---------------- launch ----------------

extern "C" void kernel_launch(void* const* d_in, const int* in_sizes, int n_in,
                              void* d_out, int out_size, void* d_ws, size_t ws_size,
                              hipStream_t stream) {
  const float* features = (const float*)d_in[0];
  const int*   src      = (const int*)d_in[1];
  const int*   dst      = (const int*)d_in[2];
  const float* w_in     = (const float*)d_in[3];
  const float* b_in     = (const float*)d_in[4];
  const float* gc_w     = (const float*)d_in[5];
  const float* gc_b     = (const float*)d_in[6];
  const float* bn_gamma = (const float*)d_in[7];
  const float* bn_beta  = (const float*)d_in[8];
  const float* bn_mean  = (const float*)d_in[9];
  const float* bn_var   = (const float*)d_in[10];
  const float* attn_w1  = (const float*)d_in[11];
  const float* attn_b1  = (const float*)d_in[12];
  const float* attn_w2  = (const float*)d_in[13];
  const float* attn_b2  = (const float*)d_in[14];
  const float* agg_w    = (const float*)d_in[15];
  const float* agg_b    = (const float*)d_in[16];
  const float* out_w    = (const float*)d_in[17];
  const float* out_b    = (const float*)d_in[18];
  float* out = (float*)d_out;

  float* fbase = (float*)d_ws;
  float* inv_mean = fbase;
  float* inv_in   = inv_mean + NN;
  float* inv_out  = inv_in + NN;
  int* row_ptr = (int*)(inv_out + NN);   // NN+16
  int* bsum    = row_ptr + NN + 16;      // 256
  int* col     = bsum + 256;             // EE
  int4* nodeinfo = (int4*)(col + EE);    // NN

  // packed fp16 weights (contiguous: win, agg, at1, gc0..2, ow)
  ushort* pk = (ushort*)(nodeinfo + NN);
  ushort* win_f = pk;
  ushort* agg_f = pk + SZ256;
  ushort* at1_f = pk + 2 * SZ256;
  ushort* gcf0  = pk + 3 * SZ256;
  ushort* gcf1  = gcf0 + SZ128;
  ushort* gcf2  = gcf1 + SZ128;
  ushort* ow_f  = gcf2 + SZ128;

  // fp16 activation pools, sliced [4][NN][32]
  __half* T0 = (__half*)(ow_f + SZOUT);  // h0 -> rst1
  __half* T1 = T0 + NH;                  // neigh / spmm rst
  __half* T2 = T1 + NH;                  // agg -> rst0
  __half* X16 = T2 + NH;                 // h_att -> (layer gather table)

  // preprocessing scratch aliased into T1/T2 (dead until spmm1/GEMM#2)
  unsigned* pd   = (unsigned*)T1;              // 6.4MB
  unsigned* ps   = pd + (long)NSL * NN;        // 6.4MB (pd+ps = T1 exactly)
  unsigned* cur0 = (unsigned*)T2;              // 6.4MB (T2 first written by GEMM#2)

  dim3 b256(256);
  const int gsplit  = GSPLIT;             // 1563
  const int g16     = NN / 16;            // 3125 (l2out)
  const int gspmm = (NN / 16) * 8;        // 25000
  const int gpre = NSL * 4;

  // FUSE1: edge histograms + weight prepack (independent)
  fuse1_kernel<<<256 + PKB, b256, 0, stream>>>(
      (const int4*)dst, (const int4*)src, pd, ps,
      w_in, agg_w, attn_w1, gc_w, out_w, pk);

  // FUSE2: GEMM#1 (h0 -> T0) + degree reduce/scan
  fuse2_kernel<<<GSPLIT + GN, b256, 0, stream>>>(
      features, win_f, b_in, T0,
      pd, ps, row_ptr, bsum, inv_mean, inv_in, inv_out);

  // cursor init (absorbs bsum scan) -> cur0 + nodeinfo
  cursor_init2_kernel<<<GN, b256, 0, stream>>>(
      row_ptr, bsum, pd, cur0, inv_mean, inv_in, nodeinfo);
  // CSR fill
  fill_partial_kernel<<<gpre, b256, 0, stream>>>((const int4*)dst, (const int4*)src, cur0, col);

  // spmm1: neigh = mean-agg(h0) -> T1 (pd/ps dead now)
  spmm32p_kernel<<<gspmm, b256, 0, stream>>>(nodeinfo, col, T0, 0, T1);
  // #2: agg = relu([h0|neigh] @ agg_w + agg_b) -> T2 (cur0 dead now)
  mgemm_kernel<8, 4, 8, EPI_RELU, H16_NONE, 1, 1, 1, 0><<<gsplit, b256, 0, stream>>>(
      T0, 0, T1, agg_f, agg_b,
      nullptr, nullptr, nullptr, nullptr, nullptr,
      nullptr, T2, HF, HF, nullptr, nullptr);
  // #3 attention (col-split with LDS dot combine): X16 = (h0 + agg*s) * inv_out
  attn_kernel<<<gsplit, b256, 0, stream>>>(
      T0, T2, at1_f, attn_b1, attn_w2, attn_b2, X16, inv_out);

  // layer 0: spmm(X16) -> T1 ; rst0 = relu(BN(T1@gc0+b0)) -> T2 (+X16)
  spmm32p_kernel<<<gspmm, b256, 0, stream>>>(nodeinfo, col, X16, 1, T1);
  mgemm_kernel<4, 4, 8, EPI_BN, H16_SCALED, 1, 1, 1, 1><<<gsplit, b256, 0, stream>>>(
      T1, 0, nullptr, gcf0, gc_b,
      bn_gamma, bn_beta, bn_mean, bn_var, nullptr,
      nullptr, T2, HF, HF, X16, inv_out);
  // layer 1: spmm(X16) -> T1 ; rst1 = relu(BN(T1@gc1+b1)) + rst0 -> T0 (+X16)
  spmm32p_kernel<<<gspmm, b256, 0, stream>>>(nodeinfo, col, X16, 1, T1);
  mgemm_kernel<4, 4, 8, EPI_BN_RES, H16_SCALED, 1, 1, 1, 1><<<gsplit, b256, 0, stream>>>(
      T1, 0, nullptr, gcf1, gc_b + HF,
      bn_gamma + HF, bn_beta + HF, bn_mean + HF, bn_var + HF, T2,
      nullptr, T0, HF, HF, X16, inv_out);
  // layer 2: spmm(X16) -> T1 ; fused rst2(+res T0) @ out_w -> d_out
  spmm32p_kernel<<<gspmm, b256, 0, stream>>>(nodeinfo, col, X16, 1, T1);
  l2out_kernel<<<g16, b256, 0, stream>>>(
      T1, gcf2, gc_b + 2 * HF,
      bn_gamma + 2 * HF, bn_beta + 2 * HF, bn_mean + 2 * HF, bn_var + 2 * HF,
      T0, ow_f, out_b, out);
}

// Round 25
// 281.152 us; speedup vs baseline: 1.2627x; 1.0368x over previous
//
#include <hip/hip_runtime.h>
#include <hip/hip_fp16.h>
#include <math.h>

constexpr int NN  = 50000;   // nodes
constexpr int EE  = 800000;  // edges
constexpr int INF_ = 256;    // input feat
constexpr int HF  = 128;     // hidden
constexpr int CC  = 50;      // classes
constexpr long NH = (long)NN * HF;
constexpr int NSL = 32;          // edge slices (preprocessing)
constexpr int ESL = EE / NSL;    // 25000 edges per slice
constexpr int CHK = 12500;       // nodes per chunk (4 chunks), 50KB LDS
#define EPSV 1e-5f

enum { EPI_RELU = 0, EPI_NONE = 1, EPI_BN = 2, EPI_BN_RES = 3 };
enum { H16_NONE = 0, H16_SCALED = 2 };

typedef __attribute__((ext_vector_type(4))) float f32x4;
typedef __attribute__((ext_vector_type(8))) _Float16 f16x8;

constexpr int SZ256 = 8 * 8 * 512;   // K=256, NTP=8
constexpr int SZ128 = 4 * 8 * 512;   // K=128, NTP=8
constexpr int SZOUT = 4 * 4 * 512;   // K=128, NTP=4
constexpr int PK_TOTAL = 3 * SZ256 + 3 * SZ128 + SZOUT;
constexpr int PKB = (PK_TOTAL + 255) / 256;   // prepack blocks (608)

// ---------------- FUSE1: edge histograms (256 blocks) + weight prepack (PKB blocks) ----------------

__global__ __launch_bounds__(256) void fuse1_kernel(
    const int4* __restrict__ dst4, const int4* __restrict__ src4,
    unsigned* __restrict__ pd, unsigned* __restrict__ ps,
    const float* __restrict__ w_in, const float* __restrict__ agg_w,
    const float* __restrict__ at1, const float* __restrict__ gc_w,
    const float* __restrict__ out_w, ushort* __restrict__ outbase) {
  __shared__ unsigned cnt[CHK];
  if (blockIdx.x < 256) {
    int bb = blockIdx.x;
    const int which = bb >> 7;
    bb &= 127;
    const int4* keys4 = which ? src4 : dst4;
    unsigned* partials = which ? ps : pd;
    const int chunk = bb & 3;
    const int sl = bb >> 2;
    for (int i = threadIdx.x; i < CHK; i += 256) cnt[i] = 0;
    __syncthreads();
    const int base4 = sl * (ESL / 4);
    const int lo = chunk * CHK;
    for (int i = threadIdx.x; i < ESL / 4; i += 256) {
      int4 k = keys4[base4 + i];
      int a;
      a = k.x - lo; if ((unsigned)a < (unsigned)CHK) atomicAdd(&cnt[a], 1u);
      a = k.y - lo; if ((unsigned)a < (unsigned)CHK) atomicAdd(&cnt[a], 1u);
      a = k.z - lo; if ((unsigned)a < (unsigned)CHK) atomicAdd(&cnt[a], 1u);
      a = k.w - lo; if ((unsigned)a < (unsigned)CHK) atomicAdd(&cnt[a], 1u);
    }
    __syncthreads();
    unsigned* p = partials + (long)sl * NN + lo;
    for (int i = threadIdx.x; i < CHK; i += 256) p[i] = cnt[i];
    return;
  }
  // prepack branch
  int idx = (blockIdx.x - 256) * 256 + threadIdx.x;
  if (idx >= PK_TOTAL) return;
  const float* W; int N, ldw, NTpad, local; ushort* outp;
  if (idx < 3 * SZ256) {
    int s = idx / SZ256; local = idx - s * SZ256;
    W = (s == 0) ? w_in : ((s == 1) ? agg_w : at1);
    N = HF; ldw = HF; NTpad = 8;
    outp = outbase + s * SZ256;
  } else if (idx < 3 * SZ256 + 3 * SZ128) {
    int r = idx - 3 * SZ256; int s = r / SZ128; local = r - s * SZ128;
    W = gc_w + (long)s * HF * HF; N = HF; ldw = HF; NTpad = 8;
    outp = outbase + 3 * SZ256 + s * SZ128;
  } else {
    local = idx - 3 * SZ256 - 3 * SZ128;
    W = out_w; N = CC; ldw = CC; NTpad = 4;
    outp = outbase + 3 * SZ256 + 3 * SZ128;
  }
  int j    = local & 7;
  int lane = (local >> 3) & 63;
  int rest = local >> 9;
  int nt = rest % NTpad;
  int kc = rest / NTpad;
  int k = kc * 32 + (lane >> 4) * 8 + j;
  int n = nt * 16 + (lane & 15);
  float w = (n < N) ? W[(long)k * ldw + n] : 0.f;
  outp[local] = __half_as_ushort(__float2half(w));
}

// ---------------- FUSE2: GEMM#1 (gsplit blocks) + degree reduce/scan (gN blocks) ----------------

constexpr int GSPLIT = (NN + 31) / 32;   // 1563
constexpr int GN = (NN + 255) / 256;     // 196

__global__ __launch_bounds__(256) void fuse2_kernel(
    const float* __restrict__ features, const ushort* __restrict__ Bf,
    const float* __restrict__ bias, __half* __restrict__ outh,
    const unsigned* __restrict__ pd, const unsigned* __restrict__ ps,
    int* __restrict__ row_ptr, int* __restrict__ bsum,
    float* __restrict__ inv_mean, float* __restrict__ inv_in,
    float* __restrict__ inv_out) {
  __shared__ int sh[256];
  if (blockIdx.x >= GSPLIT) {
    int n = (blockIdx.x - GSPLIT) * 256 + threadIdx.x;
    unsigned di = 0, dz = 0;
    if (n < NN) {
      #pragma unroll 8
      for (int sl = 0; sl < NSL; ++sl) {
        di += pd[(long)sl * NN + n];
        dz += ps[(long)sl * NN + n];
      }
      float fdi = fmaxf((float)di, 1.f), fdz = fmaxf((float)dz, 1.f);
      inv_mean[n] = 1.f / fdi;
      inv_in[n]  = rsqrtf(fdi);
      inv_out[n] = rsqrtf(fdz);
    }
    int v = (n < NN) ? (int)di : 0;
    sh[threadIdx.x] = v;
    __syncthreads();
    #pragma unroll
    for (int off = 1; off < 256; off <<= 1) {
      int tv = (threadIdx.x >= off) ? sh[threadIdx.x - off] : 0;
      __syncthreads();
      sh[threadIdx.x] += tv;
      __syncthreads();
    }
    if (n < NN) row_ptr[n] = sh[threadIdx.x] - v;
    if (threadIdx.x == 255) bsum[blockIdx.x - GSPLIT] = sh[255];
    return;
  }
  // GEMM#1 branch (KC=8, NT=4, NTP=8, fp32 A, col-split)
  const int t = threadIdx.x;
  const int lane = t & 63;
  const int wid = t >> 6;
  const int rowbase = blockIdx.x * 32 + (wid >> 1) * 16;
  const int colbase = (wid & 1) * 64;
  const int arow = rowbase + (lane & 15);
  const int kgrp = (lane >> 4) * 8;
  const bool rowok = arow < NN;

  f32x4 acc[4];
  #pragma unroll
  for (int n = 0; n < 4; ++n) acc[n] = (f32x4){0.f, 0.f, 0.f, 0.f};
  const f32x4 z4 = {0.f, 0.f, 0.f, 0.f};
  f32x4 fra[8], frb[8];
  #pragma unroll
  for (int kc = 0; kc < 8; ++kc) {
    const float* p = features + (long)arow * INF_ + kc * 32 + kgrp;
    fra[kc] = rowok ? *(const f32x4*)p : z4;
    frb[kc] = rowok ? *(const f32x4*)(p + 4) : z4;
  }
  #pragma unroll
  for (int kc = 0; kc < 8; ++kc) {
    f16x8 av;
    #pragma unroll
    for (int j = 0; j < 4; ++j) {
      av[j]     = (_Float16)fra[kc][j];
      av[j + 4] = (_Float16)frb[kc][j];
    }
    const ushort* bp = Bf + ((long)kc * 8 * 64 + lane) * 8 + (long)colbase * 32;
    #pragma unroll
    for (int nt = 0; nt < 4; ++nt) {
      union { uint4 u; f16x8 v; } bv;
      bv.u = *(const uint4*)(bp + (long)nt * 512);
      acc[nt] = __builtin_amdgcn_mfma_f32_16x16x32_f16(av, bv.v, acc[nt], 0, 0, 0);
    }
  }
  const int colg = lane & 15;
  const int rsub = (lane >> 4) * 4;
  #pragma unroll
  for (int nt = 0; nt < 4; ++nt) {
    int c = colbase + nt * 16 + colg;
    float bb = bias[c];
    #pragma unroll
    for (int i = 0; i < 4; ++i) {
      int r = rowbase + rsub + i;
      if (r >= NN) continue;
      long sidx = ((long)(c >> 5) * NN + r) * 32 + (c & 31);
      outh[sidx] = __float2half(fmaxf(acc[nt][i] + bb, 0.f));
    }
  }
}

// ---------------- cursor_init (absorbs the bsum scan) ----------------

__global__ __launch_bounds__(256) void cursor_init2_kernel(
    const int* __restrict__ row_ptr, const int* __restrict__ bsum,
    const unsigned* __restrict__ pd, unsigned* __restrict__ cur0,
    const float* __restrict__ inv_mean, const float* __restrict__ inv_in,
    int4* __restrict__ nodeinfo) {
  __shared__ int sh[256];
  int part = 0;
  for (int j = threadIdx.x; j < (int)blockIdx.x; j += 256) part += bsum[j];
  sh[threadIdx.x] = part;
  __syncthreads();
  #pragma unroll
  for (int off = 128; off >= 1; off >>= 1) {
    if (threadIdx.x < off) sh[threadIdx.x] += sh[threadIdx.x + off];
    __syncthreads();
  }
  const int boff = sh[0];
  int n = blockIdx.x * 256 + threadIdx.x;
  if (n >= NN) return;
  unsigned start = (unsigned)(row_ptr[n] + boff);
  unsigned run = start;
  #pragma unroll 8
  for (int sl = 0; sl < NSL; ++sl) {
    cur0[(long)sl * NN + n] = run;
    run += pd[(long)sl * NN + n];
  }
  nodeinfo[n] = make_int4((int)start, (int)run,
                          __float_as_int(inv_mean[n]), __float_as_int(inv_in[n]));
}

__global__ __launch_bounds__(256) void fill_partial_kernel(
    const int4* __restrict__ dst4, const int4* __restrict__ src4,
    const unsigned* __restrict__ cur0, int* __restrict__ col) {
  __shared__ unsigned cur[CHK];
  const int chunk = blockIdx.x & 3;
  const int sl = blockIdx.x >> 2;
  const int lo = chunk * CHK;
  const unsigned* c0 = cur0 + (long)sl * NN + lo;
  for (int i = threadIdx.x; i < CHK; i += 256) cur[i] = c0[i];
  __syncthreads();
  const int base4 = sl * (ESL / 4);
  for (int i = threadIdx.x; i < ESL / 4; i += 256) {
    int4 d = dst4[base4 + i];
    int4 s = src4[base4 + i];
    int a;
    a = d.x - lo; if ((unsigned)a < (unsigned)CHK) col[atomicAdd(&cur[a], 1u)] = s.x;
    a = d.y - lo; if ((unsigned)a < (unsigned)CHK) col[atomicAdd(&cur[a], 1u)] = s.y;
    a = d.z - lo; if ((unsigned)a < (unsigned)CHK) col[atomicAdd(&cur[a], 1u)] = s.z;
    a = d.w - lo; if ((unsigned)a < (unsigned)CHK) col[atomicAdd(&cur[a], 1u)] = s.w;
  }
}

// ---------------- SpMM: 4 slices x 32 feats (L2-resident), 2 nodes per wave ----------------

__global__ __launch_bounds__(256) void spmm32p_kernel(
    const int4* __restrict__ nodeinfo, const int* __restrict__ cols,
    const __half* __restrict__ xs, int useW,
    __half* __restrict__ outh) {
  const int t = threadIdx.x;
  const int lane = t & 63;
  const int wv = t >> 6;
  const int b = blockIdx.x;
  const int xcd = b & 7;
  const int slice = xcd >> 1;
  const int sub = xcd & 1;
  const int npair = lane >> 5;
  const int node = (b >> 3) * 16 + sub * 8 + wv * 2 + npair;  // NN = 3125*16
  const int e8 = (lane >> 2) & 7;
  const int q4 = lane & 3;
  const __half* xb = xs + (long)slice * NN * 32 + q4 * 8;
  int4 ni = nodeinfo[node];
  const int e0 = ni.x, end = ni.y;
  const float d = __int_as_float(useW ? ni.w : ni.z);
  const int deg = end - e0;
  int dmax = deg > 0 ? deg : 0;
  {
    int od = __shfl_xor(dmax, 32, 64);
    dmax = dmax > od ? dmax : od;
  }
  const int kmax = (dmax + 7) >> 3;
  const int ecl = (end - 1) > 0 ? (end - 1) : 0;
  const __half2 z2 = __float2half2_rn(0.f);
  __half2 A0 = z2, A1 = z2, A2 = z2, A3 = z2;
  __half2 B0 = z2, B1 = z2, B2 = z2, B3 = z2;
  int k = 0;
  for (; k + 2 <= kmax; k += 2) {
    int ee0 = e0 + k * 8 + e8;
    int ee1 = ee0 + 8;
    bool m0 = ee0 < end, m1 = ee1 < end;
    int s0 = cols[m0 ? ee0 : ecl];
    int s1 = cols[m1 ? ee1 : ecl];
    f32x4 v0 = *(const f32x4*)(xb + (unsigned)s0 * 32u);
    f32x4 v1 = *(const f32x4*)(xb + (unsigned)s1 * 32u);
    const __half2* h0 = (const __half2*)&v0;
    const __half2* h1 = (const __half2*)&v1;
    A0 = __hadd2(A0, m0 ? h0[0] : z2); A1 = __hadd2(A1, m0 ? h0[1] : z2);
    A2 = __hadd2(A2, m0 ? h0[2] : z2); A3 = __hadd2(A3, m0 ? h0[3] : z2);
    B0 = __hadd2(B0, m1 ? h1[0] : z2); B1 = __hadd2(B1, m1 ? h1[1] : z2);
    B2 = __hadd2(B2, m1 ? h1[2] : z2); B3 = __hadd2(B3, m1 ? h1[3] : z2);
  }
  if (k < kmax) {
    int ee = e0 + k * 8 + e8;
    bool m = ee < end;
    int s = cols[m ? ee : ecl];
    f32x4 v = *(const f32x4*)(xb + (unsigned)s * 32u);
    const __half2* h = (const __half2*)&v;
    A0 = __hadd2(A0, m ? h[0] : z2); A1 = __hadd2(A1, m ? h[1] : z2);
    A2 = __hadd2(A2, m ? h[2] : z2); A3 = __hadd2(A3, m ? h[3] : z2);
  }
  A0 = __hadd2(A0, B0); A1 = __hadd2(A1, B1);
  A2 = __hadd2(A2, B2); A3 = __hadd2(A3, B3);
  float2 p0 = __half22float2(A0), p1 = __half22float2(A1);
  float2 p2 = __half22float2(A2), p3 = __half22float2(A3);
  float f0 = p0.x, f1 = p0.y, f2 = p1.x, f3 = p1.y;
  float f4 = p2.x, f5 = p2.y, f6 = p3.x, f7 = p3.y;
  {
    bool hi = (lane & 4) != 0;
    float t0 = hi ? f0 : f4, t1 = hi ? f1 : f5, t2 = hi ? f2 : f6, t3 = hi ? f3 : f7;
    t0 = __shfl_xor(t0, 4, 64); t1 = __shfl_xor(t1, 4, 64);
    t2 = __shfl_xor(t2, 4, 64); t3 = __shfl_xor(t3, 4, 64);
    f0 = (hi ? f4 : f0) + t0; f1 = (hi ? f5 : f1) + t1;
    f2 = (hi ? f6 : f2) + t2; f3 = (hi ? f7 : f3) + t3;
  }
  {
    bool hi = (lane & 8) != 0;
    float t0 = hi ? f0 : f2, t1 = hi ? f1 : f3;
    t0 = __shfl_xor(t0, 8, 64); t1 = __shfl_xor(t1, 8, 64);
    f0 = (hi ? f2 : f0) + t0; f1 = (hi ? f3 : f1) + t1;
  }
  float fin;
  {
    bool hi = (lane & 16) != 0;
    float t0 = hi ? f0 : f1;
    t0 = __shfl_xor(t0, 16, 64);
    fin = (hi ? f1 : f0) + t0;
  }
  int foff = q4 * 8 + ((lane >> 2) & 1) * 4 + ((lane >> 3) & 1) * 2 + ((lane >> 4) & 1);
  outh[((long)slice * NN + node) * 32 + foff] = __float2half(fin * d);
}

// ---------------- fp16 MFMA GEMM: out = epi( [A1|A2] @ W + bias ) ----------------

template<int KC, int NT, int NTP, int EPI, int H16, int ASRC, int OUTM, int COLSPLIT, int BHOIST>
__global__ __launch_bounds__(256) void mgemm_kernel(
    const void* __restrict__ A1, int lda1,
    const void* __restrict__ A2,
    const ushort* __restrict__ Bf,
    const float* __restrict__ bias,
    const float* __restrict__ g, const float* __restrict__ be,
    const float* __restrict__ mu, const float* __restrict__ va,
    const __half* __restrict__ resp,
    float* __restrict__ outf, __half* __restrict__ outh, int ldc, int Ncols,
    __half* __restrict__ x16, const float* __restrict__ rowscale) {
  const int t = threadIdx.x;
  const int lane = t & 63;
  const int wid = t >> 6;
  const int rowbase = COLSPLIT ? (blockIdx.x * 32 + (wid >> 1) * 16)
                               : (blockIdx.x * 64 + wid * 16);
  const int colbase = COLSPLIT ? ((wid & 1) * NT * 16) : 0;
  const int arow = rowbase + (lane & 15);
  const int kgrp = (lane >> 4) * 8;
  const bool rowok = arow < NN;

  f32x4 acc[NT];
  #pragma unroll
  for (int n = 0; n < NT; ++n) acc[n] = (f32x4){0.f, 0.f, 0.f, 0.f};

  const f32x4 z4 = {0.f, 0.f, 0.f, 0.f};
  f32x4 fra[ASRC == 0 ? KC : 1], frb[ASRC == 0 ? KC : 1];
  uint4 areg[ASRC == 1 ? KC : 1];
  if (ASRC == 0) {
    #pragma unroll
    for (int kc = 0; kc < KC; ++kc) {
      const float* p = (const float*)A1 + (long)arow * lda1 + kc * 32 + kgrp;
      fra[kc] = rowok ? *(const f32x4*)p : z4;
      frb[kc] = rowok ? *(const f32x4*)(p + 4) : z4;
    }
  } else {
    #pragma unroll
    for (int kc = 0; kc < KC; ++kc) {
      const bool second = (KC == 8) && (kc >= 4);
      const ushort* At = (const ushort*)(second ? A2 : A1);
      int k0 = (second ? (kc - 4) : kc) * 32 + kgrp;
      const ushort* p = At + ((long)(k0 >> 5) * NN + arow) * 32 + (k0 & 31);
      areg[kc] = rowok ? *(const uint4*)p : make_uint4(0, 0, 0, 0);
    }
  }

  if (BHOIST) {
    uint4 breg[KC * NT];
    #pragma unroll
    for (int kc = 0; kc < KC; ++kc) {
      const ushort* bp = Bf + ((long)kc * NTP * 64 + lane) * 8 + (long)colbase * 32;
      #pragma unroll
      for (int nt = 0; nt < NT; ++nt)
        breg[kc * NT + nt] = *(const uint4*)(bp + (long)nt * 512);
    }
    #pragma unroll
    for (int kc = 0; kc < KC; ++kc) {
      union { uint4 u; f16x8 v; } cv;
      cv.u = areg[kc];
      #pragma unroll
      for (int nt = 0; nt < NT; ++nt) {
        union { uint4 u; f16x8 v; } bv;
        bv.u = breg[kc * NT + nt];
        acc[nt] = __builtin_amdgcn_mfma_f32_16x16x32_f16(cv.v, bv.v, acc[nt], 0, 0, 0);
      }
    }
  } else {
    #pragma unroll
    for (int kc = 0; kc < KC; ++kc) {
      f16x8 av;
      if (ASRC == 0) {
        #pragma unroll
        for (int j = 0; j < 4; ++j) {
          av[j]     = (_Float16)fra[kc][j];
          av[j + 4] = (_Float16)frb[kc][j];
        }
      } else {
        union { uint4 u; f16x8 v; } cv;
        cv.u = areg[kc];
        av = cv.v;
      }
      const ushort* bp = Bf + ((long)kc * NTP * 64 + lane) * 8 + (long)colbase * 32;
      #pragma unroll
      for (int nt = 0; nt < NT; ++nt) {
        union { uint4 u; f16x8 v; } bv;
        bv.u = *(const uint4*)(bp + (long)nt * 512);
        acc[nt] = __builtin_amdgcn_mfma_f32_16x16x32_f16(av, bv.v, acc[nt], 0, 0, 0);
      }
    }
  }

  const int colg = lane & 15;
  const int rsub = (lane >> 4) * 4;

  #pragma unroll
  for (int nt = 0; nt < NT; ++nt) {
    int c = colbase + nt * 16 + colg;
    if (c >= Ncols) continue;
    float bb = bias ? bias[c] : 0.f;
    float scale = 1.f, shift = 0.f;
    if (EPI == EPI_BN || EPI == EPI_BN_RES) {
      scale = g[c] * rsqrtf(va[c] + EPSV);
      shift = be[c] - mu[c] * scale;
    }
    #pragma unroll
    for (int i = 0; i < 4; ++i) {
      int r = rowbase + rsub + i;
      if (r >= NN) continue;
      long sidx = ((long)(c >> 5) * NN + r) * 32 + (c & 31);
      float v = acc[nt][i] + bb;
      if (EPI == EPI_RELU) {
        v = fmaxf(v, 0.f);
      } else if (EPI == EPI_BN || EPI == EPI_BN_RES) {
        v = fmaxf(v * scale + shift, 0.f);
        if (EPI == EPI_BN_RES) v += __half2float(resp[sidx]);
      }
      if (OUTM == 0) {
        outf[(long)r * ldc + c] = v;
      } else {
        outh[sidx] = __float2half(v);
        if (H16 == H16_SCALED) x16[sidx] = __float2half(v * rowscale[r]);
      }
    }
  }
}

// ---------------- fused agg-GEMM + attention (agg lives only in LDS) ----------------
// Block = 32 rows, 4 waves = 2 row-groups x 2 col-halves.
// Phase 1: agg = relu([h0|neigh]@agg_w+agg_b) -> LDS aggsh[32][136].
// Phase 2: attn GEMM (h0 global, agg LDS), partial dots -> pdot, sigmoid,
//          X16 = (h0 + agg*s) * inv_out.

__global__ __launch_bounds__(256) void agg_attn_kernel(
    const __half* __restrict__ h0t, const __half* __restrict__ neigh,
    const ushort* __restrict__ AggF, const float* __restrict__ agg_b,
    const ushort* __restrict__ At1F, const float* __restrict__ b1,
    const float* __restrict__ w2, const float* __restrict__ b2,
    __half* __restrict__ x16, const float* __restrict__ inv_out) {
  __shared__ __half aggsh[32][HF + 8];
  __shared__ float pdot[2][32];
  const int t = threadIdx.x;
  const int lane = t & 63;
  const int wid = t >> 6;
  const int rowg = wid >> 1;
  const int colh = wid & 1;
  const int rowbase = blockIdx.x * 32 + rowg * 16;
  const int colbase = colh * 64;
  const int arow = rowbase + (lane & 15);
  const int kgrp = (lane >> 4) * 8;
  const bool rowok = arow < NN;
  const int colg = lane & 15;
  const int rsub = (lane >> 4) * 4;

  // ---- phase 1: agg tile -> LDS ----
  {
    f32x4 acc[4];
    #pragma unroll
    for (int n = 0; n < 4; ++n) acc[n] = (f32x4){0.f, 0.f, 0.f, 0.f};
    uint4 areg[8];
    #pragma unroll
    for (int kc = 0; kc < 8; ++kc) {
      const bool second = kc >= 4;
      const __half* At = second ? neigh : h0t;
      int k0 = (second ? (kc - 4) : kc) * 32 + kgrp;
      areg[kc] = rowok ? *(const uint4*)(At + ((long)(k0 >> 5) * NN + arow) * 32 + (k0 & 31))
                       : make_uint4(0, 0, 0, 0);
    }
    #pragma unroll
    for (int kc = 0; kc < 8; ++kc) {
      union { uint4 u; f16x8 v; } cv;
      cv.u = areg[kc];
      const ushort* bp = AggF + ((long)kc * 8 * 64 + lane) * 8 + (long)colbase * 32;
      #pragma unroll
      for (int nt = 0; nt < 4; ++nt) {
        union { uint4 u; f16x8 v; } bv;
        bv.u = *(const uint4*)(bp + (long)nt * 512);
        acc[nt] = __builtin_amdgcn_mfma_f32_16x16x32_f16(cv.v, bv.v, acc[nt], 0, 0, 0);
      }
    }
    #pragma unroll
    for (int nt = 0; nt < 4; ++nt) {
      int c = colbase + nt * 16 + colg;
      float bb = agg_b[c];
      #pragma unroll
      for (int i = 0; i < 4; ++i) {
        aggsh[rowg * 16 + rsub + i][c] = __float2half(fmaxf(acc[nt][i] + bb, 0.f));
      }
    }
  }
  __syncthreads();

  // ---- phase 2: attention ----
  f32x4 acc[4];
  #pragma unroll
  for (int n = 0; n < 4; ++n) acc[n] = (f32x4){0.f, 0.f, 0.f, 0.f};
  #pragma unroll
  for (int kc = 0; kc < 8; ++kc) {
    union { uint4 u; f16x8 v; } cv;
    if (kc < 4) {
      int k0 = kc * 32 + kgrp;
      cv.u = rowok ? *(const uint4*)(h0t + ((long)(k0 >> 5) * NN + arow) * 32 + (k0 & 31))
                   : make_uint4(0, 0, 0, 0);
    } else {
      int k0 = (kc - 4) * 32 + kgrp;
      cv.v = *(const f16x8*)&aggsh[rowg * 16 + (lane & 15)][k0];
    }
    const ushort* bp = At1F + ((long)kc * 8 * 64 + lane) * 8 + (long)colbase * 32;
    #pragma unroll
    for (int nt = 0; nt < 4; ++nt) {
      union { uint4 u; f16x8 v; } bv;
      bv.u = *(const uint4*)(bp + (long)nt * 512);
      acc[nt] = __builtin_amdgcn_mfma_f32_16x16x32_f16(cv.v, bv.v, acc[nt], 0, 0, 0);
    }
  }

  float part0 = 0.f, part1 = 0.f, part2 = 0.f, part3 = 0.f;
  #pragma unroll
  for (int nt = 0; nt < 4; ++nt) {
    int c = colbase + nt * 16 + colg;
    float w2v = w2[c];
    float bb = b1[c];
    part0 = fmaf(fmaxf(acc[nt][0] + bb, 0.f), w2v, part0);
    part1 = fmaf(fmaxf(acc[nt][1] + bb, 0.f), w2v, part1);
    part2 = fmaf(fmaxf(acc[nt][2] + bb, 0.f), w2v, part2);
    part3 = fmaf(fmaxf(acc[nt][3] + bb, 0.f), w2v, part3);
  }
  #pragma unroll
  for (int m = 1; m <= 8; m <<= 1) {
    part0 += __shfl_xor(part0, m, 64);
    part1 += __shfl_xor(part1, m, 64);
    part2 += __shfl_xor(part2, m, 64);
    part3 += __shfl_xor(part3, m, 64);
  }
  if (colg == 0) {
    int rib = rowg * 16 + rsub;
    pdot[colh][rib + 0] = part0;
    pdot[colh][rib + 1] = part1;
    pdot[colh][rib + 2] = part2;
    pdot[colh][rib + 3] = part3;
  }
  __syncthreads();
  const float b2v = b2[0];
  float sden[4];
  #pragma unroll
  for (int i = 0; i < 4; ++i) {
    int rib = rowg * 16 + rsub + i;
    float dot = pdot[0][rib] + pdot[1][rib] + b2v;
    sden[i] = 1.f / (1.f + __expf(-dot));
  }
  #pragma unroll
  for (int nt = 0; nt < 4; ++nt) {
    int c = colbase + nt * 16 + colg;
    #pragma unroll
    for (int i = 0; i < 4; ++i) {
      int r = rowbase + rsub + i;
      if (r >= NN) continue;
      long sidx = ((long)(c >> 5) * NN + r) * 32 + (c & 31);
      float ag = __half2float(aggsh[rowg * 16 + rsub + i][c]);
      float h = __half2float(h0t[sidx]) + ag * sden[i];
      x16[sidx] = __float2half(h * inv_out[r]);
    }
  }
}

// ---------------- fused layer-2 GEMM + out GEMM (rst2 lives only in LDS) ----------------

__global__ __launch_bounds__(256) void l2out_kernel(
    const __half* __restrict__ A1,      // T1 (z, sliced)
    const ushort* __restrict__ Bf,      // gcf2
    const float* __restrict__ bias,     // gc_b + 2*HF
    const float* __restrict__ g, const float* __restrict__ be,
    const float* __restrict__ mu, const float* __restrict__ va,
    const __half* __restrict__ resp,    // T0 (rst1)
    const ushort* __restrict__ OwF,     // ow_f
    const float* __restrict__ out_b,
    float* __restrict__ outf) {
  __shared__ __half sh[16][HF + 8];
  const int t = threadIdx.x;
  const int lane = t & 63;
  const int wid = t >> 6;
  const int rowbase = blockIdx.x * 16;  // NN = 3125*16, exact
  const int colbase = wid * 32;
  const int arow = rowbase + (lane & 15);
  const int kgrp = (lane >> 4) * 8;

  f32x4 acc[2];
  acc[0] = (f32x4){0.f, 0.f, 0.f, 0.f};
  acc[1] = (f32x4){0.f, 0.f, 0.f, 0.f};
  uint4 areg[4];
  #pragma unroll
  for (int kc = 0; kc < 4; ++kc) {
    int k0 = kc * 32 + kgrp;
    areg[kc] = *(const uint4*)(A1 + ((long)(k0 >> 5) * NN + arow) * 32 + (k0 & 31));
  }
  #pragma unroll
  for (int kc = 0; kc < 4; ++kc) {
    union { uint4 u; f16x8 v; } cv;
    cv.u = areg[kc];
    const ushort* bp = Bf + ((long)kc * 8 * 64 + lane) * 8 + (long)colbase * 32;
    #pragma unroll
    for (int nt = 0; nt < 2; ++nt) {
      union { uint4 u; f16x8 v; } bv;
      bv.u = *(const uint4*)(bp + (long)nt * 512);
      acc[nt] = __builtin_amdgcn_mfma_f32_16x16x32_f16(cv.v, bv.v, acc[nt], 0, 0, 0);
    }
  }
  const int colg = lane & 15;
  const int rsub = (lane >> 4) * 4;
  #pragma unroll
  for (int nt = 0; nt < 2; ++nt) {
    int c = colbase + nt * 16 + colg;
    float bb = bias[c];
    float scale = g[c] * rsqrtf(va[c] + EPSV);
    float shift = be[c] - mu[c] * scale;
    #pragma unroll
    for (int i = 0; i < 4; ++i) {
      int r = rowbase + rsub + i;
      long sidx = ((long)(c >> 5) * NN + r) * 32 + (c & 31);
      float v = fmaxf((acc[nt][i] + bb) * scale + shift, 0.f) + __half2float(resp[sidx]);
      sh[rsub + i][c] = __float2half(v);
    }
  }
  __syncthreads();
  f32x4 acc2 = (f32x4){0.f, 0.f, 0.f, 0.f};
  #pragma unroll
  for (int kc = 0; kc < 4; ++kc) {
    union { uint4 u; f16x8 v; } av;
    av.v = *(const f16x8*)&sh[lane & 15][kc * 32 + kgrp];
    union { uint4 u; f16x8 v; } bv;
    bv.u = *(const uint4*)(OwF + ((long)kc * 4 * 64 + lane) * 8 + (long)wid * 512);
    acc2 = __builtin_amdgcn_mfma_f32_16x16x32_f16(av.v, bv.v, acc2, 0, 0, 0);
  }
  int c = wid * 16 + colg;
  if (c < CC) {
    float bb = out_b[c];
    #pragma unroll
    for (int i = 0; i < 4; ++i) {
      int r = rowbase + rsub + i;
      outf[(long)r * CC + c] = acc2[i] + bb;
    }
  }
}

// ---------------- launch ----------------

extern "C" void kernel_launch(void* const* d_in, const int* in_sizes, int n_in,
                              void* d_out, int out_size, void* d_ws, size_t ws_size,
                              hipStream_t stream) {
  const float* features = (const float*)d_in[0];
  const int*   src      = (const int*)d_in[1];
  const int*   dst      = (const int*)d_in[2];
  const float* w_in     = (const float*)d_in[3];
  const float* b_in     = (const float*)d_in[4];
  const float* gc_w     = (const float*)d_in[5];
  const float* gc_b     = (const float*)d_in[6];
  const float* bn_gamma = (const float*)d_in[7];
  const float* bn_beta  = (const float*)d_in[8];
  const float* bn_mean  = (const float*)d_in[9];
  const float* bn_var   = (const float*)d_in[10];
  const float* attn_w1  = (const float*)d_in[11];
  const float* attn_b1  = (const float*)d_in[12];
  const float* attn_w2  = (const float*)d_in[13];
  const float* attn_b2  = (const float*)d_in[14];
  const float* agg_w    = (const float*)d_in[15];
  const float* agg_b    = (const float*)d_in[16];
  const float* out_w    = (const float*)d_in[17];
  const float* out_b    = (const float*)d_in[18];
  float* out = (float*)d_out;

  float* fbase = (float*)d_ws;
  float* inv_mean = fbase;
  float* inv_in   = inv_mean + NN;
  float* inv_out  = inv_in + NN;
  int* row_ptr = (int*)(inv_out + NN);   // NN+16
  int* bsum    = row_ptr + NN + 16;      // 256
  int* col     = bsum + 256;             // EE
  int4* nodeinfo = (int4*)(col + EE);    // NN

  // packed fp16 weights (contiguous: win, agg, at1, gc0..2, ow)
  ushort* pk = (ushort*)(nodeinfo + NN);
  ushort* win_f = pk;
  ushort* agg_f = pk + SZ256;
  ushort* at1_f = pk + 2 * SZ256;
  ushort* gcf0  = pk + 3 * SZ256;
  ushort* gcf1  = gcf0 + SZ128;
  ushort* gcf2  = gcf1 + SZ128;
  ushort* ow_f  = gcf2 + SZ128;

  // fp16 activation pools, sliced [4][NN][32]
  __half* T0 = (__half*)(ow_f + SZOUT);  // h0 -> rst1
  __half* T1 = T0 + NH;                  // neigh / spmm rst
  __half* T2 = T1 + NH;                  // rst0
  __half* X16 = T2 + NH;                 // h_att -> (layer gather table)

  // preprocessing scratch aliased into T1/T2 (dead until spmm1 / GEMM L0)
  unsigned* pd   = (unsigned*)T1;              // 6.4MB
  unsigned* ps   = pd + (long)NSL * NN;        // 6.4MB (pd+ps = T1 exactly)
  unsigned* cur0 = (unsigned*)T2;              // 6.4MB (T2 first written by GEMM L0)

  dim3 b256(256);
  const int gsplit  = GSPLIT;             // 1563
  const int g16     = NN / 16;            // 3125 (l2out)
  const int gspmm = (NN / 16) * 8;        // 25000
  const int gpre = NSL * 4;

  // FUSE1: edge histograms + weight prepack (independent)
  fuse1_kernel<<<256 + PKB, b256, 0, stream>>>(
      (const int4*)dst, (const int4*)src, pd, ps,
      w_in, agg_w, attn_w1, gc_w, out_w, pk);

  // FUSE2: GEMM#1 (h0 -> T0) + degree reduce/scan
  fuse2_kernel<<<GSPLIT + GN, b256, 0, stream>>>(
      features, win_f, b_in, T0,
      pd, ps, row_ptr, bsum, inv_mean, inv_in, inv_out);

  // cursor init (absorbs bsum scan) -> cur0 + nodeinfo
  cursor_init2_kernel<<<GN, b256, 0, stream>>>(
      row_ptr, bsum, pd, cur0, inv_mean, inv_in, nodeinfo);
  // CSR fill
  fill_partial_kernel<<<gpre, b256, 0, stream>>>((const int4*)dst, (const int4*)src, cur0, col);

  // spmm1: neigh = mean-agg(h0) -> T1 (pd/ps dead now)
  spmm32p_kernel<<<gspmm, b256, 0, stream>>>(nodeinfo, col, T0, 0, T1);
  // fused agg-GEMM + attention: X16 = (h0 + agg*s) * inv_out  (agg LDS-only)
  agg_attn_kernel<<<gsplit, b256, 0, stream>>>(
      T0, T1, agg_f, agg_b, at1_f, attn_b1, attn_w2, attn_b2, X16, inv_out);

  // layer 0: spmm(X16) -> T1 ; rst0 = relu(BN(T1@gc0+b0)) -> T2 (+X16)
  spmm32p_kernel<<<gspmm, b256, 0, stream>>>(nodeinfo, col, X16, 1, T1);
  mgemm_kernel<4, 4, 8, EPI_BN, H16_SCALED, 1, 1, 1, 1><<<gsplit, b256, 0, stream>>>(
      T1, 0, nullptr, gcf0, gc_b,
      bn_gamma, bn_beta, bn_mean, bn_var, nullptr,
      nullptr, T2, HF, HF, X16, inv_out);
  // layer 1: spmm(X16) -> T1 ; rst1 = relu(BN(T1@gc1+b1)) + rst0 -> T0 (+X16)
  spmm32p_kernel<<<gspmm, b256, 0, stream>>>(nodeinfo, col, X16, 1, T1);
  mgemm_kernel<4, 4, 8, EPI_BN_RES, H16_SCALED, 1, 1, 1, 1><<<gsplit, b256, 0, stream>>>(
      T1, 0, nullptr, gcf1, gc_b + HF,
      bn_gamma + HF, bn_beta + HF, bn_mean + HF, bn_var + HF, T2,
      nullptr, T0, HF, HF, X16, inv_out);
  // layer 2: spmm(X16) -> T1 ; fused rst2(+res T0) @ out_w -> d_out
  spmm32p_kernel<<<gspmm, b256, 0, stream>>>(nodeinfo, col, X16, 1, T1);
  l2out_kernel<<<g16, b256, 0, stream>>>(
      T1, gcf2, gc_b + 2 * HF,
      bn_gamma + 2 * HF, bn_beta + 2 * HF, bn_mean + 2 * HF, bn_var + 2 * HF,
      T0, ow_f, out_b, out);
}